// Round 10
// baseline (4312.474 us; speedup 1.0000x reference)
//
#include <hip/hip_runtime.h>

// ---------------- types / constants ----------------
typedef short short8 __attribute__((ext_vector_type(8)));
typedef float f32x4 __attribute__((ext_vector_type(4)));

#define DMODEL 1024
#define HKDIM 1024
#define MDIM 4096
#define NROW 4096   // S*B = 1024*4
#define VOCAB 32000
#define NLAYER 6

#define GLOAD_LDS16(g, l)                                                      \
  __builtin_amdgcn_global_load_lds(                                            \
      (const __attribute__((address_space(1))) void*)(g),                      \
      (__attribute__((address_space(3))) void*)(l), 16, 0, 0)

__device__ __forceinline__ unsigned short f2bf(float f) {
  unsigned u = __float_as_uint(f);
  u += 0x7fffu + ((u >> 16) & 1u);
  return (unsigned short)(u >> 16);
}
__device__ __forceinline__ float bf2f(unsigned short h) {
  return __uint_as_float(((unsigned)h) << 16);
}
__device__ __forceinline__ float wave_sum(float v) {
  for (int o = 32; o; o >>= 1) v += __shfl_xor(v, o);
  return v;
}
__device__ __forceinline__ float wave_max(float v) {
  for (int o = 32; o; o >>= 1) v = fmaxf(v, __shfl_xor(v, o));
  return v;
}

// ---------------- embedding ----------------
__global__ __launch_bounds__(256) void k_embed(const int* __restrict__ x,
    const float* __restrict__ wemb, const float* __restrict__ pemb,
    float* __restrict__ z) {
  int r = blockIdx.x;           // r = s*4 + b
  int s = r >> 2;
  int tok = x[r];
  float4 a = ((const float4*)(wemb + (long)tok * DMODEL))[threadIdx.x];
  float4 p = ((const float4*)(pemb + (long)s * DMODEL))[threadIdx.x];
  float4 o;
  o.x = fmaxf(a.x * 32.0f + p.x, 0.0f);
  o.y = fmaxf(a.y * 32.0f + p.y, 0.0f);
  o.z = fmaxf(a.z * 32.0f + p.z, 0.0f);
  o.w = fmaxf(a.w * 32.0f + p.w, 0.0f);
  ((float4*)(z + (long)r * DMODEL))[threadIdx.x] = o;
}

// ---------------- permute rows: x = swapaxes(z,0,1), bf16 out only ----------------
__global__ __launch_bounds__(256) void k_permute(const float* __restrict__ zin,
    unsigned short* __restrict__ xb, int A0, int A1) {
  int r = blockIdx.x;
  int a1 = r / A0, a0 = r - a1 * A0;
  float4 v = ((const float4*)(zin + (long)(a0 * A1 + a1) * DMODEL))[threadIdx.x];
  ushort4 o = make_ushort4(f2bf(v.x), f2bf(v.y), f2bf(v.z), f2bf(v.w));
  ((ushort4*)(xb + (long)r * DMODEL))[threadIdx.x] = o;
}

// ---------------- f32 -> bf16 ----------------
__global__ __launch_bounds__(256) void k_cvt(const float* __restrict__ in,
    unsigned short* __restrict__ out, int n4) {
  int i = blockIdx.x * 256 + threadIdx.x;
  int stride = gridDim.x * 256;
  for (; i < n4; i += stride) {
    float4 v = ((const float4*)in)[i];
    ((ushort4*)out)[i] = make_ushort4(f2bf(v.x), f2bf(v.y), f2bf(v.z), f2bf(v.w));
  }
}

// ---------------- 128x128 bf16 GEMM (m97 structure + T2 + XCD swizzle) ------------
__global__ __launch_bounds__(256) void k_gemm_bt(
    const unsigned short* __restrict__ A, const unsigned short* __restrict__ B,
    float* __restrict__ Cf, unsigned short* __restrict__ Cb,
    const float* __restrict__ bias, const unsigned short* __restrict__ resb,
    int M, int N, int K, int lda, int ldb, int ldc,
    long aB, long bB, long cB, float scale) {
  __shared__ unsigned short As[128 * 64];
  __shared__ unsigned short Bs[128 * 64];
  const int tid = threadIdx.x;
  const int gx = gridDim.x, gy = gridDim.y;

  int nwg = gx * gy * gridDim.z;
  int flat = blockIdx.x + gx * (blockIdx.y + gy * blockIdx.z);
  int q8 = nwg >> 3, r8 = nwg & 7;
  int xcd = flat & 7, inner = flat >> 3;
  int wg = (xcd < r8 ? xcd * (q8 + 1) : r8 * (q8 + 1) + (xcd - r8) * q8) + inner;
  int ty = wg % gy;         // y-fastest: co-XCD consecutive blocks share B-panel
  int rest = wg / gy;
  int tx = rest % gx;
  int tz = rest / gx;

  const unsigned short* Ab = A + (long)tz * aB;
  const unsigned short* Bb = B + (long)tz * bB;
  const int row0 = ty * 128, col0 = tx * 128;
  const int lane = tid & 63, w = tid >> 6;
  const int wm = w >> 1, wn = w & 1;
  const int fr = lane & 15, fg = lane >> 4, fr7 = fr & 7;
  const int lrow = lane >> 3;
  const int lcol = ((lane & 7) ^ lrow) * 8;  // T2: pre-swizzled global source chunk

  const unsigned short* aSrc = Ab + (long)(row0 + w * 32 + lrow) * lda + lcol;
  const unsigned short* bSrc = Bb + (long)(col0 + w * 32 + lrow) * ldb + lcol;
  unsigned short* aDst = As + w * 32 * 64;  // linear wave-uniform LDS dest
  unsigned short* bDst = Bs + w * 32 * 64;

  f32x4 acc[4][4];
#pragma unroll
  for (int i = 0; i < 4; ++i)
#pragma unroll
    for (int j = 0; j < 4; ++j)
#pragma unroll
      for (int qq = 0; qq < 4; ++qq) acc[i][j][qq] = 0.0f;

  for (int k0 = 0; k0 < K; k0 += 64) {
#pragma unroll
    for (int i = 0; i < 4; ++i) {
      GLOAD_LDS16(aSrc + (long)i * 8 * lda + k0, aDst + i * 512);
      GLOAD_LDS16(bSrc + (long)i * 8 * ldb + k0, bDst + i * 512);
    }
    __syncthreads();
#pragma unroll
    for (int kk = 0; kk < 64; kk += 32) {
      short8 af[4], bfr[4];
#pragma unroll
      for (int i = 0; i < 4; ++i) {
        af[i] = *(const short8*)(As + (wm * 64 + i * 16 + fr) * 64 +
                                 (((kk >> 3) + fg) ^ fr7) * 8);
        bfr[i] = *(const short8*)(Bs + (wn * 64 + i * 16 + fr) * 64 +
                                  (((kk >> 3) + fg) ^ fr7) * 8);
      }
#pragma unroll
      for (int i = 0; i < 4; ++i)
#pragma unroll
        for (int j = 0; j < 4; ++j)
          acc[i][j] = __builtin_amdgcn_mfma_f32_16x16x32_bf16(af[i], bfr[j], acc[i][j], 0, 0, 0);
    }
    __syncthreads();
  }

#pragma unroll
  for (int j = 0; j < 4; ++j) {
    int col = col0 + wn * 64 + j * 16 + fr;
    float bv = bias ? bias[col] : 0.0f;
#pragma unroll
    for (int i = 0; i < 4; ++i) {
#pragma unroll
      for (int qq = 0; qq < 4; ++qq) {
        int row = row0 + wm * 64 + i * 16 + fg * 4 + qq;
        long off = cB * tz + (long)row * ldc + col;
        float v = acc[i][j][qq] * scale + bv;
        if (resb) v += bf2f(resb[off]);
        if (Cf) Cf[off] = v;
        if (Cb) Cb[off] = f2bf(v);
      }
    }
  }
}

// ---------------- 64x128 bf16 GEMM variant for N=1024 shapes ----------------
__global__ __launch_bounds__(256) void k_gemm64(
    const unsigned short* __restrict__ A, const unsigned short* __restrict__ B,
    float* __restrict__ Cf, unsigned short* __restrict__ Cb,
    const float* __restrict__ bias, const unsigned short* __restrict__ resb,
    int M, int N, int K, int lda, int ldb, int ldc,
    long aB, long bB, long cB, float scale) {
  __shared__ unsigned short As[64 * 64];
  __shared__ unsigned short Bs[128 * 64];
  const int tid = threadIdx.x;
  const int gx = gridDim.x, gy = gridDim.y;

  int nwg = gx * gy * gridDim.z;
  int flat = blockIdx.x + gx * (blockIdx.y + gy * blockIdx.z);
  int q8 = nwg >> 3, r8 = nwg & 7;
  int xcd = flat & 7, inner = flat >> 3;
  int wg = (xcd < r8 ? xcd * (q8 + 1) : r8 * (q8 + 1) + (xcd - r8) * q8) + inner;
  int ty = wg % gy;
  int rest = wg / gy;
  int tx = rest % gx;
  int tz = rest / gx;

  const unsigned short* Ab = A + (long)tz * aB;
  const unsigned short* Bb = B + (long)tz * bB;
  const int row0 = ty * 64, col0 = tx * 128;
  const int lane = tid & 63, w = tid >> 6;
  const int wm = w >> 1, wn = w & 1;
  const int fr = lane & 15, fg = lane >> 4, fr7 = fr & 7;
  const int lrow = lane >> 3;
  const int lcol = ((lane & 7) ^ lrow) * 8;

  const unsigned short* aSrc = Ab + (long)(row0 + w * 16 + lrow) * lda + lcol;
  const unsigned short* bSrc = Bb + (long)(col0 + w * 32 + lrow) * ldb + lcol;
  unsigned short* aDst = As + w * 16 * 64;
  unsigned short* bDst = Bs + w * 32 * 64;

  f32x4 acc[2][4];
#pragma unroll
  for (int i = 0; i < 2; ++i)
#pragma unroll
    for (int j = 0; j < 4; ++j)
#pragma unroll
      for (int qq = 0; qq < 4; ++qq) acc[i][j][qq] = 0.0f;

  for (int k0 = 0; k0 < K; k0 += 64) {
#pragma unroll
    for (int i = 0; i < 2; ++i)
      GLOAD_LDS16(aSrc + (long)i * 8 * lda + k0, aDst + i * 512);
#pragma unroll
    for (int i = 0; i < 4; ++i)
      GLOAD_LDS16(bSrc + (long)i * 8 * ldb + k0, bDst + i * 512);
    __syncthreads();
#pragma unroll
    for (int kk = 0; kk < 64; kk += 32) {
      short8 af[2], bfr[4];
#pragma unroll
      for (int i = 0; i < 2; ++i)
        af[i] = *(const short8*)(As + (wm * 32 + i * 16 + fr) * 64 +
                                 (((kk >> 3) + fg) ^ fr7) * 8);
#pragma unroll
      for (int j = 0; j < 4; ++j)
        bfr[j] = *(const short8*)(Bs + (wn * 64 + j * 16 + fr) * 64 +
                                  (((kk >> 3) + fg) ^ fr7) * 8);
#pragma unroll
      for (int i = 0; i < 2; ++i)
#pragma unroll
        for (int j = 0; j < 4; ++j)
          acc[i][j] = __builtin_amdgcn_mfma_f32_16x16x32_bf16(af[i], bfr[j], acc[i][j], 0, 0, 0);
    }
    __syncthreads();
  }

#pragma unroll
  for (int j = 0; j < 4; ++j) {
    int col = col0 + wn * 64 + j * 16 + fr;
    float bv = bias ? bias[col] : 0.0f;
#pragma unroll
    for (int i = 0; i < 2; ++i) {
#pragma unroll
      for (int qq = 0; qq < 4; ++qq) {
        int row = row0 + wm * 32 + i * 16 + fg * 4 + qq;
        long off = cB * tz + (long)row * ldc + col;
        float v = acc[i][j][qq] * scale + bv;
        if (resb) v += bf2f(resb[off]);
        if (Cf) Cf[off] = v;
        if (Cb) Cb[off] = f2bf(v);
      }
    }
  }
}

// ---------------- 256x256 single-buffered 2-barrier bf16 GEMM (decoder) ----------
// 64KB LDS -> 2 blocks/CU (16 waves/CU): cross-block overlap absorbs the barrier
// drain (m97 mechanism at 256^2 traffic). 512 threads = 8 waves (2M x 4N).
__global__ __launch_bounds__(512, 4) void k_gemm8s(
    const unsigned short* __restrict__ A, const unsigned short* __restrict__ B,
    float* __restrict__ Cf, unsigned short* __restrict__ Cb,
    const float* __restrict__ bias, int M, int N, int K,
    int lda, int ldb, int ldc) {
  __shared__ unsigned short As[256 * 64];
  __shared__ unsigned short Bs[256 * 64];
  const int tid = threadIdx.x;
  const int gx = gridDim.x, gy = gridDim.y;
  int nwg = gx * gy;
  int flat = blockIdx.x + gx * blockIdx.y;
  int q8 = nwg >> 3, r8 = nwg & 7;
  int xcd = flat & 7, inner = flat >> 3;
  int wg = (xcd < r8 ? xcd * (q8 + 1) : r8 * (q8 + 1) + (xcd - r8) * q8) + inner;
  int ty = wg % gy, tx = wg / gy;

  const int row0 = ty * 256, col0 = tx * 256;
  const int lane = tid & 63, w = tid >> 6;
  const int wm = w >> 2, wn = w & 3;
  const int fr = lane & 15, fg = lane >> 4, fr7 = fr & 7;
  const int srow = lane >> 3;
  const int scol = ((lane & 7) ^ srow) * 8;   // T2 pre-swizzled source chunk

  const unsigned short* pA = A + (size_t)(row0 + w * 32 + srow) * lda + scol;
  const unsigned short* pB = B + (size_t)(col0 + w * 32 + srow) * ldb + scol;
  unsigned short* aD = As + w * 32 * 64;
  unsigned short* bD = Bs + w * 32 * 64;

  auto rdA = [&](int i, int kq) -> short8 {
    return *(const short8*)(As + (wm * 128 + i * 16 + fr) * 64 +
                            (((kq << 2) + fg) ^ fr7) * 8);
  };
  auto rdB = [&](int j, int kq) -> short8 {
    return *(const short8*)(Bs + (wn * 64 + j * 16 + fr) * 64 +
                            (((kq << 2) + fg) ^ fr7) * 8);
  };

  f32x4 acc[8][4];
#pragma unroll
  for (int i = 0; i < 8; ++i)
#pragma unroll
    for (int j = 0; j < 4; ++j)
#pragma unroll
      for (int qq = 0; qq < 4; ++qq) acc[i][j][qq] = 0.0f;

  const int NT = K >> 6;

  for (int t = 0; t < NT; ++t) {
#pragma unroll
    for (int i = 0; i < 4; ++i) {
      GLOAD_LDS16(pA + (size_t)i * 8 * lda + (size_t)t * 64, aD + i * 512);
      GLOAD_LDS16(pB + (size_t)i * 8 * ldb + (size_t)t * 64, bD + i * 512);
    }
    __syncthreads();
#pragma unroll
    for (int kq = 0; kq < 2; ++kq) {
      short8 a8[8], b8[4];
#pragma unroll
      for (int i = 0; i < 8; ++i) a8[i] = rdA(i, kq);
#pragma unroll
      for (int j = 0; j < 4; ++j) b8[j] = rdB(j, kq);
#pragma unroll
      for (int i = 0; i < 8; ++i)
#pragma unroll
        for (int j = 0; j < 4; ++j)
          acc[i][j] = __builtin_amdgcn_mfma_f32_16x16x32_bf16(a8[i], b8[j], acc[i][j], 0, 0, 0);
    }
    __syncthreads();
  }

#pragma unroll
  for (int j = 0; j < 4; ++j) {
    int col = col0 + wn * 64 + j * 16 + fr;
    float bv = bias ? bias[col] : 0.0f;
#pragma unroll
    for (int i = 0; i < 8; ++i) {
#pragma unroll
      for (int qq = 0; qq < 4; ++qq) {
        int row = row0 + wm * 128 + i * 16 + fg * 4 + qq;
        size_t off = (size_t)row * ldc + col;
        float v = acc[i][j][qq] + bv;
        if (Cf) Cf[off] = v;
        if (Cb) Cb[off] = f2bf(v);
      }
    }
  }
}

// ---------------- layernorm: X f32 (+ optional bf16 X2) -> f32/bf16 out -------------
__global__ __launch_bounds__(256) void k_ln(const float* __restrict__ X,
    const unsigned short* __restrict__ X2b, const float* __restrict__ g,
    const float* __restrict__ b, float* __restrict__ outF,
    unsigned short* __restrict__ outB) {
  __shared__ float sm[4];
  int row = blockIdx.x, t = threadIdx.x;
  float4 v = ((const float4*)(X + (long)row * DMODEL))[t];
  if (X2b) {
    ushort4 u = ((const ushort4*)(X2b + (long)row * DMODEL))[t];
    v.x += bf2f(u.x); v.y += bf2f(u.y); v.z += bf2f(u.z); v.w += bf2f(u.w);
  }
  float s = wave_sum(v.x + v.y + v.z + v.w);
  if ((t & 63) == 0) sm[t >> 6] = s;
  __syncthreads();
  float mean = (sm[0] + sm[1] + sm[2] + sm[3]) * (1.0f / DMODEL);
  __syncthreads();
  float4 c;
  c.x = v.x - mean; c.y = v.y - mean; c.z = v.z - mean; c.w = v.w - mean;
  float ss = wave_sum(c.x * c.x + c.y * c.y + c.z * c.z + c.w * c.w);
  if ((t & 63) == 0) sm[t >> 6] = ss;
  __syncthreads();
  float var = (sm[0] + sm[1] + sm[2] + sm[3]) * (1.0f / DMODEL);
  float rs = rsqrtf(var + 1e-5f);
  float4 gv = ((const float4*)g)[t], bv = ((const float4*)b)[t];
  float4 o;
  o.x = c.x * rs * gv.x + bv.x;
  o.y = c.y * rs * gv.y + bv.y;
  o.z = c.z * rs * gv.z + bv.z;
  o.w = c.w * rs * gv.w + bv.w;
  if (outF) ((float4*)(outF + (long)row * DMODEL))[t] = o;
  if (outB)
    ((ushort4*)(outB + (long)row * DMODEL))[t] =
        make_ushort4(f2bf(o.x), f2bf(o.y), f2bf(o.z), f2bf(o.w));
}

// ---------------- softmax (rows of 1024) ----------------
__global__ __launch_bounds__(256) void k_softmax(const float* __restrict__ S,
    unsigned short* __restrict__ A) {
  __shared__ float sm[4];
  int row = blockIdx.x, t = threadIdx.x;
  float4 v = ((const float4*)(S + (long)row * 1024))[t];
  float m = wave_max(fmaxf(fmaxf(v.x, v.y), fmaxf(v.z, v.w)));
  if ((t & 63) == 0) sm[t >> 6] = m;
  __syncthreads();
  m = fmaxf(fmaxf(sm[0], sm[1]), fmaxf(sm[2], sm[3]));
  __syncthreads();
  float4 e;
  e.x = __expf(v.x - m); e.y = __expf(v.y - m);
  e.z = __expf(v.z - m); e.w = __expf(v.w - m);
  float s = wave_sum(e.x + e.y + e.z + e.w);
  if ((t & 63) == 0) sm[t >> 6] = s;
  __syncthreads();
  float inv = 1.0f / (sm[0] + sm[1] + sm[2] + sm[3]);
  ((ushort4*)(A + (long)row * 1024))[t] =
      make_ushort4(f2bf(e.x * inv), f2bf(e.y * inv), f2bf(e.z * inv), f2bf(e.w * inv));
}

// ---------------- odd layers: seq-4 attention (QKV packed, stride 3072) -------------
__global__ __launch_bounds__(256) void k_attn4(const unsigned short* __restrict__ QKV,
    unsigned short* __restrict__ C) {
  int bp = blockIdx.x;
  int w = threadIdx.x >> 6, lane = threadIdx.x & 63;
  const unsigned short* q = QKV + (long)(bp * 4 + w) * 3072;
  float s[4];
  for (int j = 0; j < 4; ++j) {
    const unsigned short* kj = QKV + (long)(bp * 4 + j) * 3072 + 1024;
    float a = 0.0f;
    for (int e = lane; e < 1024; e += 64) a += bf2f(q[e]) * bf2f(kj[e]);
    s[j] = wave_sum(a) * (1.0f / 32.0f);
  }
  float m = fmaxf(fmaxf(s[0], s[1]), fmaxf(s[2], s[3]));
  float e0 = __expf(s[0] - m), e1 = __expf(s[1] - m);
  float e2 = __expf(s[2] - m), e3 = __expf(s[3] - m);
  float inv = 1.0f / (e0 + e1 + e2 + e3);
  float a0 = e0 * inv, a1 = e1 * inv, a2 = e2 * inv, a3 = e3 * inv;
  unsigned short* c = C + (long)(bp * 4 + w) * 1024;
  const unsigned short* v0 = QKV + (long)(bp * 4 + 0) * 3072 + 2048;
  const unsigned short* v1 = QKV + (long)(bp * 4 + 1) * 3072 + 2048;
  const unsigned short* v2 = QKV + (long)(bp * 4 + 2) * 3072 + 2048;
  const unsigned short* v3 = QKV + (long)(bp * 4 + 3) * 3072 + 2048;
  for (int e = lane; e < 1024; e += 64) {
    float v = a0 * bf2f(v0[e]) + a1 * bf2f(v1[e]) + a2 * bf2f(v2[e]) + a3 * bf2f(v3[e]);
    c[e] = f2bf(v);
  }
}

// ---------------- bf16 batched transpose with strides ----------------
__global__ __launch_bounds__(256) void k_transpose(const unsigned short* __restrict__ in,
    unsigned short* __restrict__ out, int rows, int cols, int ld_in, int ld_out,
    long inB, long outB) {
  __shared__ unsigned short tile[32][33];
  long ibase = (long)blockIdx.z * inB;
  long obase = (long)blockIdx.z * outB;
  int r0 = blockIdx.y * 32, c0 = blockIdx.x * 32;
  int tx = threadIdx.x, ty = threadIdx.y;
  for (int i = ty; i < 32; i += 8)
    tile[i][tx] = in[ibase + (long)(r0 + i) * ld_in + c0 + tx];
  __syncthreads();
  for (int i = ty; i < 32; i += 8)
    out[obase + (long)(c0 + i) * ld_out + r0 + tx] = tile[tx][i];
}

// ---------------- log-softmax: bf16 logits in, f32 out ----------------
__global__ __launch_bounds__(320) void k_logsoftmax_b(
    const unsigned short* __restrict__ Lb, float* __restrict__ out) {
  __shared__ float sm[5];
  int row = blockIdx.x, t = threadIdx.x;
  const unsigned long long* xr =
      (const unsigned long long*)(Lb + (long)row * VOCAB);
  float* yr = out + (long)row * VOCAB;
  float4 v[25];
  float m = -1e30f;
#pragma unroll
  for (int i = 0; i < 25; ++i) {
    unsigned long long u = __builtin_nontemporal_load(&xr[t + i * 320]);
    v[i].x = bf2f((unsigned short)(u & 0xffffu));
    v[i].y = bf2f((unsigned short)((u >> 16) & 0xffffu));
    v[i].z = bf2f((unsigned short)((u >> 32) & 0xffffu));
    v[i].w = bf2f((unsigned short)(u >> 48));
    m = fmaxf(m, fmaxf(fmaxf(v[i].x, v[i].y), fmaxf(v[i].z, v[i].w)));
  }
  m = wave_max(m);
  if ((t & 63) == 0) sm[t >> 6] = m;
  __syncthreads();
  m = fmaxf(fmaxf(fmaxf(sm[0], sm[1]), fmaxf(sm[2], sm[3])), sm[4]);
  __syncthreads();
  float s = 0.0f;
#pragma unroll
  for (int i = 0; i < 25; ++i)
    s += __expf(v[i].x - m) + __expf(v[i].y - m) + __expf(v[i].z - m) + __expf(v[i].w - m);
  s = wave_sum(s);
  if ((t & 63) == 0) sm[t >> 6] = s;
  __syncthreads();
  float l = m + __logf(sm[0] + sm[1] + sm[2] + sm[3] + sm[4]);
#pragma unroll
  for (int i = 0; i < 25; ++i) {
    float4 o = v[i];
    o.x -= l; o.y -= l; o.z -= l; o.w -= l;
    ((float4*)yr)[t + i * 320] = o;
  }
}

// ---------------- log-softmax fallback: in-place f32 ----------------
__global__ __launch_bounds__(320) void k_logsoftmax(float* __restrict__ L) {
  __shared__ float sm[5];
  int row = blockIdx.x, t = threadIdx.x;
  float* x = L + (long)row * VOCAB;
  float4 v[25];
  float m = -1e30f;
#pragma unroll
  for (int i = 0; i < 25; ++i) {
    v[i] = ((const float4*)x)[t + i * 320];
    m = fmaxf(m, fmaxf(fmaxf(v[i].x, v[i].y), fmaxf(v[i].z, v[i].w)));
  }
  m = wave_max(m);
  if ((t & 63) == 0) sm[t >> 6] = m;
  __syncthreads();
  m = fmaxf(fmaxf(fmaxf(sm[0], sm[1]), fmaxf(sm[2], sm[3])), sm[4]);
  __syncthreads();
  float s = 0.0f;
#pragma unroll
  for (int i = 0; i < 25; ++i)
    s += __expf(v[i].x - m) + __expf(v[i].y - m) + __expf(v[i].z - m) + __expf(v[i].w - m);
  s = wave_sum(s);
  if ((t & 63) == 0) sm[t >> 6] = s;
  __syncthreads();
  float l = m + __logf(sm[0] + sm[1] + sm[2] + sm[3] + sm[4]);
#pragma unroll
  for (int i = 0; i < 25; ++i) {
    float4 o = v[i];
    o.x -= l; o.y -= l; o.z -= l; o.w -= l;
    ((float4*)x)[t + i * 320] = o;
  }
}

__global__ __launch_bounds__(256) void k_addbias(const float* __restrict__ a,
    const float* __restrict__ b, float* __restrict__ o, int n) {
  int i = blockIdx.x * 256 + threadIdx.x;
  if (i < n) o[i] = a[i] + b[i];
}

// ---------------- host ----------------
extern "C" void kernel_launch(void* const* d_in, const int* in_sizes, int n_in,
                              void* d_out, int out_size, void* d_ws, size_t ws_size,
                              hipStream_t stream) {
  const int* x = (const int*)d_in[0];
  const float* wemb = (const float*)d_in[1];
  const float* pemb = (const float*)d_in[2];
  const float* wq = (const float*)d_in[3];
  const float* wk = (const float*)d_in[4];
  const float* wv = (const float*)d_in[5];
  const float* wc = (const float*)d_in[6];
  const float* ln1g = (const float*)d_in[7];
  const float* ln1b = (const float*)d_in[8];
  const float* w1 = (const float*)d_in[9];
  const float* b1 = (const float*)d_in[10];
  const float* w2 = (const float*)d_in[11];
  const float* b2 = (const float*)d_in[12];
  const float* ln2g = (const float*)d_in[13];
  const float* ln2b = (const float*)d_in[14];
  const float* decw = (const float*)d_in[15];
  const float* decb = (const float*)d_in[16];
  const float* obias = (const float*)d_in[17];
  float* out = (float*)d_out;

  char* ws = (char*)d_ws;
  size_t off = 0;
  auto alloc = [&](size_t bytes) -> char* {
    char* p = ws + off;
    off += (bytes + 255) & ~(size_t)255;
    return p;
  };
  float* z = (float*)alloc((size_t)NROW * DMODEL * 4);
  unsigned short* xb = (unsigned short*)alloc((size_t)NROW * DMODEL * 2);
  unsigned short* qkv = (unsigned short*)alloc((size_t)NROW * 3072 * 2);
  unsigned short* vt = (unsigned short*)alloc((size_t)NROW * HKDIM * 2);
  unsigned short* wbuf = (unsigned short*)alloc((size_t)MDIM * DMODEL * 2);
  float* tmp16 = (float*)alloc((size_t)NROW * 1024 * 4);
  unsigned short* am = (unsigned short*)alloc((size_t)NROW * 1024 * 2);
  unsigned short* ctx = (unsigned short*)alloc((size_t)NROW * HKDIM * 2);
  unsigned short* hb = (unsigned short*)alloc((size_t)NROW * DMODEL * 2);
  unsigned short* f = (unsigned short*)alloc((size_t)NROW * MDIM * 2);
  unsigned short* dwb = (unsigned short*)alloc((size_t)VOCAB * DMODEL * 2);
  unsigned short* zb = (unsigned short*)alloc((size_t)NROW * DMODEL * 2);
  float* biasD = (float*)alloc((size_t)VOCAB * 4);
  unsigned short* logits = (unsigned short*)alloc((size_t)NROW * VOCAB * 2);
  const bool bfLogits = (off <= ws_size);  // deterministic: ws_size fixed per deploy
  (void)in_sizes; (void)n_in; (void)out_size;

  auto gemm = [&](const unsigned short* A, const unsigned short* B, float* Cf,
                  unsigned short* Cb, const float* bias, const unsigned short* resb,
                  int M, int N, int K, int lda, int ldb, int ldc, int batch,
                  long aB, long bB, long cB, float scale) {
    dim3 g(N / 128, M / 128, batch);
    k_gemm_bt<<<g, dim3(256), 0, stream>>>(A, B, Cf, Cb, bias, resb, M, N, K,
                                           lda, ldb, ldc, aB, bB, cB, scale);
  };
  auto gemm64 = [&](const unsigned short* A, const unsigned short* B, float* Cf,
                    unsigned short* Cb, const float* bias, const unsigned short* resb,
                    int M, int N, int K, int lda, int ldb, int ldc, int batch,
                    long aB, long bB, long cB, float scale) {
    dim3 g(N / 128, M / 64, batch);
    k_gemm64<<<g, dim3(256), 0, stream>>>(A, B, Cf, Cb, bias, resb, M, N, K,
                                          lda, ldb, ldc, aB, bB, cB, scale);
  };
  auto gemm8s = [&](const unsigned short* A, const unsigned short* B, float* Cf,
                    unsigned short* Cb, const float* bias, int M, int N, int K,
                    int lda, int ldb, int ldc) {
    k_gemm8s<<<dim3(N / 256, M / 256, 1), dim3(512), 0, stream>>>(
        A, B, Cf, Cb, bias, M, N, K, lda, ldb, ldc);
  };
  auto cvt = [&](const float* in, unsigned short* o, long n) {
    int n4 = (int)(n / 4);
    int grid = (n4 + 255) / 256;
    if (grid > 2048) grid = 2048;
    k_cvt<<<dim3(grid), dim3(256), 0, stream>>>(in, o, n4);
  };

  k_embed<<<NROW, 256, 0, stream>>>(x, wemb, pemb, z);

  for (int i = 0; i < NLAYER; ++i) {
    int A0 = (i % 2 == 0) ? 1024 : 4;
    int A1 = 4096 / A0;
    k_permute<<<NROW, 256, 0, stream>>>(z, xb, A0, A1);

    // merged QKV: weights stacked [3072,1024] (768 blocks, 3/CU)
    cvt(wq + (long)i * HKDIM * DMODEL, wbuf, (long)HKDIM * DMODEL);
    cvt(wk + (long)i * HKDIM * DMODEL, wbuf + (size_t)1024 * DMODEL, (long)HKDIM * DMODEL);
    cvt(wv + (long)i * HKDIM * DMODEL, wbuf + (size_t)2048 * DMODEL, (long)HKDIM * DMODEL);
    gemm(xb, wbuf, nullptr, qkv, nullptr, nullptr, NROW, 3072, DMODEL,
         DMODEL, DMODEL, 3072, 1, 0, 0, 0, 1.0f);

    if (A0 == 1024) {  // even: full attention over S=1024, 4 batches
      gemm64(qkv, qkv + 1024, tmp16, nullptr, nullptr, nullptr, 1024, 1024, 1024,
             3072, 3072, 1024, 4, (long)1024 * 3072, (long)1024 * 3072, 1 << 20,
             1.0f / 32.0f);
      k_softmax<<<NROW, 256, 0, stream>>>(tmp16, am);
      k_transpose<<<dim3(32, 32, 4), dim3(32, 8), 0, stream>>>(
          qkv + 2048, vt, 1024, 1024, 3072, 1024, (long)1024 * 3072, 1 << 20);
      gemm64(am, vt, nullptr, ctx, nullptr, nullptr, 1024, 1024, 1024,
             1024, 1024, 1024, 4, 1 << 20, 1 << 20, 1 << 20, 1.0f);
    } else {  // odd: seq length 4
      k_attn4<<<1024, 256, 0, stream>>>(qkv, ctx);
    }

    // proj + bf16 residual  (N=1024: 64-row tiles -> 512 blocks, 2/CU)
    cvt(wc + (long)i * DMODEL * HKDIM, wbuf, (long)DMODEL * HKDIM);
    gemm64(ctx, wbuf, tmp16, nullptr, nullptr, xb, NROW, DMODEL, HKDIM,
           HKDIM, HKDIM, DMODEL, 1, 0, 0, 0, 1.0f);
    k_ln<<<NROW, 256, 0, stream>>>(tmp16, nullptr, ln1g + (long)i * DMODEL,
                                   ln1b + (long)i * DMODEL, nullptr, hb);
    cvt(w1 + (long)i * MDIM * DMODEL, wbuf, (long)MDIM * DMODEL);
    gemm(hb, wbuf, nullptr, f, b1 + (long)i * MDIM, nullptr, NROW, MDIM, DMODEL,
         DMODEL, DMODEL, MDIM, 1, 0, 0, 0, 1.0f);
    cvt(w2 + (long)i * DMODEL * MDIM, wbuf, (long)DMODEL * MDIM);
    gemm64(f, wbuf, tmp16, nullptr, b2 + (long)i * DMODEL, nullptr, NROW, DMODEL, MDIM,
           MDIM, MDIM, DMODEL, 1, 0, 0, 0, 1.0f);
    // final layer: LN2 writes bf16 zb directly (skips f32 z + cvt)
    if (i == NLAYER - 1)
      k_ln<<<NROW, 256, 0, stream>>>(tmp16, hb, ln2g + (long)i * DMODEL,
                                     ln2b + (long)i * DMODEL, nullptr, zb);
    else
      k_ln<<<NROW, 256, 0, stream>>>(tmp16, hb, ln2g + (long)i * DMODEL,
                                     ln2b + (long)i * DMODEL, z, nullptr);
  }

  // decoder: single-buffered 256^2 (2 blocks/CU), bf16 logits when ws allows
  cvt(decw, dwb, (long)VOCAB * DMODEL);
  k_addbias<<<(VOCAB + 255) / 256, 256, 0, stream>>>(decb, obias, biasD, VOCAB);
  if (bfLogits) {
    gemm8s(zb, dwb, nullptr, logits, biasD, NROW, VOCAB, DMODEL, DMODEL, DMODEL, VOCAB);
    k_logsoftmax_b<<<NROW, 320, 0, stream>>>(logits, out);
  } else {
    gemm8s(zb, dwb, out, nullptr, biasD, NROW, VOCAB, DMODEL, DMODEL, DMODEL, VOCAB);
    k_logsoftmax<<<NROW, 320, 0, stream>>>(out);
  }
}

// Round 11
// 2309.327 us; speedup vs baseline: 1.8674x; 1.8674x over previous
//
#include <hip/hip_runtime.h>

// ---------------- types / constants ----------------
typedef short short8 __attribute__((ext_vector_type(8)));
typedef float f32x4 __attribute__((ext_vector_type(4)));

#define DMODEL 1024
#define HKDIM 1024
#define MDIM 4096
#define NROW 4096   // S*B = 1024*4
#define VOCAB 32000
#define NLAYER 6

#define GLOAD_LDS16(g, l)                                                      \
  __builtin_amdgcn_global_load_lds(                                            \
      (const __attribute__((address_space(1))) void*)(g),                      \
      (__attribute__((address_space(3))) void*)(l), 16, 0, 0)

__device__ __forceinline__ unsigned short f2bf(float f) {
  unsigned u = __float_as_uint(f);
  u += 0x7fffu + ((u >> 16) & 1u);
  return (unsigned short)(u >> 16);
}
__device__ __forceinline__ float bf2f(unsigned short h) {
  return __uint_as_float(((unsigned)h) << 16);
}
__device__ __forceinline__ float wave_sum(float v) {
  for (int o = 32; o; o >>= 1) v += __shfl_xor(v, o);
  return v;
}
__device__ __forceinline__ float wave_max(float v) {
  for (int o = 32; o; o >>= 1) v = fmaxf(v, __shfl_xor(v, o));
  return v;
}

// ---------------- embedding ----------------
__global__ __launch_bounds__(256) void k_embed(const int* __restrict__ x,
    const float* __restrict__ wemb, const float* __restrict__ pemb,
    float* __restrict__ z) {
  int r = blockIdx.x;           // r = s*4 + b
  int s = r >> 2;
  int tok = x[r];
  float4 a = ((const float4*)(wemb + (long)tok * DMODEL))[threadIdx.x];
  float4 p = ((const float4*)(pemb + (long)s * DMODEL))[threadIdx.x];
  float4 o;
  o.x = fmaxf(a.x * 32.0f + p.x, 0.0f);
  o.y = fmaxf(a.y * 32.0f + p.y, 0.0f);
  o.z = fmaxf(a.z * 32.0f + p.z, 0.0f);
  o.w = fmaxf(a.w * 32.0f + p.w, 0.0f);
  ((float4*)(z + (long)r * DMODEL))[threadIdx.x] = o;
}

// ---------------- permute rows: x = swapaxes(z,0,1), bf16 out only ----------------
__global__ __launch_bounds__(256) void k_permute(const float* __restrict__ zin,
    unsigned short* __restrict__ xb, int A0, int A1) {
  int r = blockIdx.x;
  int a1 = r / A0, a0 = r - a1 * A0;
  float4 v = ((const float4*)(zin + (long)(a0 * A1 + a1) * DMODEL))[threadIdx.x];
  ushort4 o = make_ushort4(f2bf(v.x), f2bf(v.y), f2bf(v.z), f2bf(v.w));
  ((ushort4*)(xb + (long)r * DMODEL))[threadIdx.x] = o;
}

// ---------------- f32 -> bf16 ----------------
__global__ __launch_bounds__(256) void k_cvt(const float* __restrict__ in,
    unsigned short* __restrict__ out, int n4) {
  int i = blockIdx.x * 256 + threadIdx.x;
  int stride = gridDim.x * 256;
  for (; i < n4; i += stride) {
    float4 v = ((const float4*)in)[i];
    ((ushort4*)out)[i] = make_ushort4(f2bf(v.x), f2bf(v.y), f2bf(v.z), f2bf(v.w));
  }
}

// ---------------- 128x128 bf16 GEMM (m97 structure + T2 + XCD swizzle) ------------
__global__ __launch_bounds__(256) void k_gemm_bt(
    const unsigned short* __restrict__ A, const unsigned short* __restrict__ B,
    float* __restrict__ Cf, unsigned short* __restrict__ Cb,
    const float* __restrict__ bias, const unsigned short* __restrict__ resb,
    int M, int N, int K, int lda, int ldb, int ldc,
    long aB, long bB, long cB, float scale) {
  __shared__ unsigned short As[128 * 64];
  __shared__ unsigned short Bs[128 * 64];
  const int tid = threadIdx.x;
  const int gx = gridDim.x, gy = gridDim.y;

  int nwg = gx * gy * gridDim.z;
  int flat = blockIdx.x + gx * (blockIdx.y + gy * blockIdx.z);
  int q8 = nwg >> 3, r8 = nwg & 7;
  int xcd = flat & 7, inner = flat >> 3;
  int wg = (xcd < r8 ? xcd * (q8 + 1) : r8 * (q8 + 1) + (xcd - r8) * q8) + inner;
  int ty = wg % gy;         // y-fastest: co-XCD consecutive blocks share B-panel
  int rest = wg / gy;
  int tx = rest % gx;
  int tz = rest / gx;

  const unsigned short* Ab = A + (long)tz * aB;
  const unsigned short* Bb = B + (long)tz * bB;
  const int row0 = ty * 128, col0 = tx * 128;
  const int lane = tid & 63, w = tid >> 6;
  const int wm = w >> 1, wn = w & 1;
  const int fr = lane & 15, fg = lane >> 4, fr7 = fr & 7;
  const int lrow = lane >> 3;
  const int lcol = ((lane & 7) ^ lrow) * 8;  // T2: pre-swizzled global source chunk

  const unsigned short* aSrc = Ab + (long)(row0 + w * 32 + lrow) * lda + lcol;
  const unsigned short* bSrc = Bb + (long)(col0 + w * 32 + lrow) * ldb + lcol;
  unsigned short* aDst = As + w * 32 * 64;  // linear wave-uniform LDS dest
  unsigned short* bDst = Bs + w * 32 * 64;

  f32x4 acc[4][4];
#pragma unroll
  for (int i = 0; i < 4; ++i)
#pragma unroll
    for (int j = 0; j < 4; ++j)
#pragma unroll
      for (int qq = 0; qq < 4; ++qq) acc[i][j][qq] = 0.0f;

  for (int k0 = 0; k0 < K; k0 += 64) {
#pragma unroll
    for (int i = 0; i < 4; ++i) {
      GLOAD_LDS16(aSrc + (long)i * 8 * lda + k0, aDst + i * 512);
      GLOAD_LDS16(bSrc + (long)i * 8 * ldb + k0, bDst + i * 512);
    }
    __syncthreads();
#pragma unroll
    for (int kk = 0; kk < 64; kk += 32) {
      short8 af[4], bfr[4];
#pragma unroll
      for (int i = 0; i < 4; ++i) {
        af[i] = *(const short8*)(As + (wm * 64 + i * 16 + fr) * 64 +
                                 (((kk >> 3) + fg) ^ fr7) * 8);
        bfr[i] = *(const short8*)(Bs + (wn * 64 + i * 16 + fr) * 64 +
                                  (((kk >> 3) + fg) ^ fr7) * 8);
      }
#pragma unroll
      for (int i = 0; i < 4; ++i)
#pragma unroll
        for (int j = 0; j < 4; ++j)
          acc[i][j] = __builtin_amdgcn_mfma_f32_16x16x32_bf16(af[i], bfr[j], acc[i][j], 0, 0, 0);
    }
    __syncthreads();
  }

#pragma unroll
  for (int j = 0; j < 4; ++j) {
    int col = col0 + wn * 64 + j * 16 + fr;
    float bv = bias ? bias[col] : 0.0f;
#pragma unroll
    for (int i = 0; i < 4; ++i) {
#pragma unroll
      for (int qq = 0; qq < 4; ++qq) {
        int row = row0 + wm * 64 + i * 16 + fg * 4 + qq;
        long off = cB * tz + (long)row * ldc + col;
        float v = acc[i][j][qq] * scale + bv;
        if (resb) v += bf2f(resb[off]);
        if (Cf) Cf[off] = v;
        if (Cb) Cb[off] = f2bf(v);
      }
    }
  }
}

// ---------------- 64x128 bf16 GEMM variant for N=1024 shapes ----------------
__global__ __launch_bounds__(256) void k_gemm64(
    const unsigned short* __restrict__ A, const unsigned short* __restrict__ B,
    float* __restrict__ Cf, unsigned short* __restrict__ Cb,
    const float* __restrict__ bias, const unsigned short* __restrict__ resb,
    int M, int N, int K, int lda, int ldb, int ldc,
    long aB, long bB, long cB, float scale) {
  __shared__ unsigned short As[64 * 64];
  __shared__ unsigned short Bs[128 * 64];
  const int tid = threadIdx.x;
  const int gx = gridDim.x, gy = gridDim.y;

  int nwg = gx * gy * gridDim.z;
  int flat = blockIdx.x + gx * (blockIdx.y + gy * blockIdx.z);
  int q8 = nwg >> 3, r8 = nwg & 7;
  int xcd = flat & 7, inner = flat >> 3;
  int wg = (xcd < r8 ? xcd * (q8 + 1) : r8 * (q8 + 1) + (xcd - r8) * q8) + inner;
  int ty = wg % gy;
  int rest = wg / gy;
  int tx = rest % gx;
  int tz = rest / gx;

  const unsigned short* Ab = A + (long)tz * aB;
  const unsigned short* Bb = B + (long)tz * bB;
  const int row0 = ty * 64, col0 = tx * 128;
  const int lane = tid & 63, w = tid >> 6;
  const int wm = w >> 1, wn = w & 1;
  const int fr = lane & 15, fg = lane >> 4, fr7 = fr & 7;
  const int lrow = lane >> 3;
  const int lcol = ((lane & 7) ^ lrow) * 8;

  const unsigned short* aSrc = Ab + (long)(row0 + w * 16 + lrow) * lda + lcol;
  const unsigned short* bSrc = Bb + (long)(col0 + w * 32 + lrow) * ldb + lcol;
  unsigned short* aDst = As + w * 16 * 64;
  unsigned short* bDst = Bs + w * 32 * 64;

  f32x4 acc[2][4];
#pragma unroll
  for (int i = 0; i < 2; ++i)
#pragma unroll
    for (int j = 0; j < 4; ++j)
#pragma unroll
      for (int qq = 0; qq < 4; ++qq) acc[i][j][qq] = 0.0f;

  for (int k0 = 0; k0 < K; k0 += 64) {
#pragma unroll
    for (int i = 0; i < 2; ++i)
      GLOAD_LDS16(aSrc + (long)i * 8 * lda + k0, aDst + i * 512);
#pragma unroll
    for (int i = 0; i < 4; ++i)
      GLOAD_LDS16(bSrc + (long)i * 8 * ldb + k0, bDst + i * 512);
    __syncthreads();
#pragma unroll
    for (int kk = 0; kk < 64; kk += 32) {
      short8 af[2], bfr[4];
#pragma unroll
      for (int i = 0; i < 2; ++i)
        af[i] = *(const short8*)(As + (wm * 32 + i * 16 + fr) * 64 +
                                 (((kk >> 3) + fg) ^ fr7) * 8);
#pragma unroll
      for (int j = 0; j < 4; ++j)
        bfr[j] = *(const short8*)(Bs + (wn * 64 + j * 16 + fr) * 64 +
                                  (((kk >> 3) + fg) ^ fr7) * 8);
#pragma unroll
      for (int i = 0; i < 2; ++i)
#pragma unroll
        for (int j = 0; j < 4; ++j)
          acc[i][j] = __builtin_amdgcn_mfma_f32_16x16x32_bf16(af[i], bfr[j], acc[i][j], 0, 0, 0);
    }
    __syncthreads();
  }

#pragma unroll
  for (int j = 0; j < 4; ++j) {
    int col = col0 + wn * 64 + j * 16 + fr;
    float bv = bias ? bias[col] : 0.0f;
#pragma unroll
    for (int i = 0; i < 2; ++i) {
#pragma unroll
      for (int qq = 0; qq < 4; ++qq) {
        int row = row0 + wm * 32 + i * 16 + fg * 4 + qq;
        long off = cB * tz + (long)row * ldc + col;
        float v = acc[i][j][qq] * scale + bv;
        if (resb) v += bf2f(resb[off]);
        if (Cf) Cf[off] = v;
        if (Cb) Cb[off] = f2bf(v);
      }
    }
  }
}

// ---------------- 256x256 single-buffered 2-barrier bf16 GEMM (decoder) ----------
// 64KB LDS -> 2 blocks/CU; VGPR ~116 -> 4 waves/SIMD: cross-block overlap absorbs
// the barrier drain (m97 mechanism at 256^2 traffic). launch_bounds min-waves=2
// so the allocator does NOT cap VGPRs below the 128-reg accumulator (r10 bug).
__global__ __launch_bounds__(512, 2) void k_gemm8s(
    const unsigned short* __restrict__ A, const unsigned short* __restrict__ B,
    float* __restrict__ Cf, unsigned short* __restrict__ Cb,
    const float* __restrict__ bias, int M, int N, int K,
    int lda, int ldb, int ldc) {
  __shared__ unsigned short As[256 * 64];
  __shared__ unsigned short Bs[256 * 64];
  const int tid = threadIdx.x;
  const int gx = gridDim.x, gy = gridDim.y;
  int nwg = gx * gy;
  int flat = blockIdx.x + gx * blockIdx.y;
  int q8 = nwg >> 3, r8 = nwg & 7;
  int xcd = flat & 7, inner = flat >> 3;
  int wg = (xcd < r8 ? xcd * (q8 + 1) : r8 * (q8 + 1) + (xcd - r8) * q8) + inner;
  int ty = wg % gy, tx = wg / gy;

  const int row0 = ty * 256, col0 = tx * 256;
  const int lane = tid & 63, w = tid >> 6;
  const int wm = w >> 2, wn = w & 3;
  const int fr = lane & 15, fg = lane >> 4, fr7 = fr & 7;
  const int srow = lane >> 3;
  const int scol = ((lane & 7) ^ srow) * 8;   // T2 pre-swizzled source chunk

  const unsigned short* pA = A + (size_t)(row0 + w * 32 + srow) * lda + scol;
  const unsigned short* pB = B + (size_t)(col0 + w * 32 + srow) * ldb + scol;
  unsigned short* aD = As + w * 32 * 64;
  unsigned short* bD = Bs + w * 32 * 64;

  auto rdA = [&](int i, int kq) -> short8 {
    return *(const short8*)(As + (wm * 128 + i * 16 + fr) * 64 +
                            (((kq << 2) + fg) ^ fr7) * 8);
  };
  auto rdB = [&](int j, int kq) -> short8 {
    return *(const short8*)(Bs + (wn * 64 + j * 16 + fr) * 64 +
                            (((kq << 2) + fg) ^ fr7) * 8);
  };

  f32x4 acc[8][4];
#pragma unroll
  for (int i = 0; i < 8; ++i)
#pragma unroll
    for (int j = 0; j < 4; ++j)
#pragma unroll
      for (int qq = 0; qq < 4; ++qq) acc[i][j][qq] = 0.0f;

  const int NT = K >> 6;

  for (int t = 0; t < NT; ++t) {
#pragma unroll
    for (int i = 0; i < 4; ++i) {
      GLOAD_LDS16(pA + (size_t)i * 8 * lda + (size_t)t * 64, aD + i * 512);
      GLOAD_LDS16(pB + (size_t)i * 8 * ldb + (size_t)t * 64, bD + i * 512);
    }
    __syncthreads();
#pragma unroll
    for (int kq = 0; kq < 2; ++kq) {
      short8 a8[8], b8[4];
#pragma unroll
      for (int i = 0; i < 8; ++i) a8[i] = rdA(i, kq);
#pragma unroll
      for (int j = 0; j < 4; ++j) b8[j] = rdB(j, kq);
#pragma unroll
      for (int i = 0; i < 8; ++i)
#pragma unroll
        for (int j = 0; j < 4; ++j)
          acc[i][j] = __builtin_amdgcn_mfma_f32_16x16x32_bf16(a8[i], b8[j], acc[i][j], 0, 0, 0);
    }
    __syncthreads();
  }

#pragma unroll
  for (int j = 0; j < 4; ++j) {
    int col = col0 + wn * 64 + j * 16 + fr;
    float bv = bias ? bias[col] : 0.0f;
#pragma unroll
    for (int i = 0; i < 8; ++i) {
#pragma unroll
      for (int qq = 0; qq < 4; ++qq) {
        int row = row0 + wm * 128 + i * 16 + fg * 4 + qq;
        size_t off = (size_t)row * ldc + col;
        float v = acc[i][j][qq] + bv;
        if (Cf) Cf[off] = v;
        if (Cb) Cb[off] = f2bf(v);
      }
    }
  }
}

// ---------------- layernorm: X f32 (+ optional bf16 X2) -> f32/bf16 out -------------
__global__ __launch_bounds__(256) void k_ln(const float* __restrict__ X,
    const unsigned short* __restrict__ X2b, const float* __restrict__ g,
    const float* __restrict__ b, float* __restrict__ outF,
    unsigned short* __restrict__ outB) {
  __shared__ float sm[4];
  int row = blockIdx.x, t = threadIdx.x;
  float4 v = ((const float4*)(X + (long)row * DMODEL))[t];
  if (X2b) {
    ushort4 u = ((const ushort4*)(X2b + (long)row * DMODEL))[t];
    v.x += bf2f(u.x); v.y += bf2f(u.y); v.z += bf2f(u.z); v.w += bf2f(u.w);
  }
  float s = wave_sum(v.x + v.y + v.z + v.w);
  if ((t & 63) == 0) sm[t >> 6] = s;
  __syncthreads();
  float mean = (sm[0] + sm[1] + sm[2] + sm[3]) * (1.0f / DMODEL);
  __syncthreads();
  float4 c;
  c.x = v.x - mean; c.y = v.y - mean; c.z = v.z - mean; c.w = v.w - mean;
  float ss = wave_sum(c.x * c.x + c.y * c.y + c.z * c.z + c.w * c.w);
  if ((t & 63) == 0) sm[t >> 6] = ss;
  __syncthreads();
  float var = (sm[0] + sm[1] + sm[2] + sm[3]) * (1.0f / DMODEL);
  float rs = rsqrtf(var + 1e-5f);
  float4 gv = ((const float4*)g)[t], bv = ((const float4*)b)[t];
  float4 o;
  o.x = c.x * rs * gv.x + bv.x;
  o.y = c.y * rs * gv.y + bv.y;
  o.z = c.z * rs * gv.z + bv.z;
  o.w = c.w * rs * gv.w + bv.w;
  if (outF) ((float4*)(outF + (long)row * DMODEL))[t] = o;
  if (outB)
    ((ushort4*)(outB + (long)row * DMODEL))[t] =
        make_ushort4(f2bf(o.x), f2bf(o.y), f2bf(o.z), f2bf(o.w));
}

// ---------------- softmax (rows of 1024) ----------------
__global__ __launch_bounds__(256) void k_softmax(const float* __restrict__ S,
    unsigned short* __restrict__ A) {
  __shared__ float sm[4];
  int row = blockIdx.x, t = threadIdx.x;
  float4 v = ((const float4*)(S + (long)row * 1024))[t];
  float m = wave_max(fmaxf(fmaxf(v.x, v.y), fmaxf(v.z, v.w)));
  if ((t & 63) == 0) sm[t >> 6] = m;
  __syncthreads();
  m = fmaxf(fmaxf(sm[0], sm[1]), fmaxf(sm[2], sm[3]));
  __syncthreads();
  float4 e;
  e.x = __expf(v.x - m); e.y = __expf(v.y - m);
  e.z = __expf(v.z - m); e.w = __expf(v.w - m);
  float s = wave_sum(e.x + e.y + e.z + e.w);
  if ((t & 63) == 0) sm[t >> 6] = s;
  __syncthreads();
  float inv = 1.0f / (sm[0] + sm[1] + sm[2] + sm[3]);
  ((ushort4*)(A + (long)row * 1024))[t] =
      make_ushort4(f2bf(e.x * inv), f2bf(e.y * inv), f2bf(e.z * inv), f2bf(e.w * inv));
}

// ---------------- odd layers: seq-4 attention (QKV packed, stride 3072) -------------
__global__ __launch_bounds__(256) void k_attn4(const unsigned short* __restrict__ QKV,
    unsigned short* __restrict__ C) {
  int bp = blockIdx.x;
  int w = threadIdx.x >> 6, lane = threadIdx.x & 63;
  const unsigned short* q = QKV + (long)(bp * 4 + w) * 3072;
  float s[4];
  for (int j = 0; j < 4; ++j) {
    const unsigned short* kj = QKV + (long)(bp * 4 + j) * 3072 + 1024;
    float a = 0.0f;
    for (int e = lane; e < 1024; e += 64) a += bf2f(q[e]) * bf2f(kj[e]);
    s[j] = wave_sum(a) * (1.0f / 32.0f);
  }
  float m = fmaxf(fmaxf(s[0], s[1]), fmaxf(s[2], s[3]));
  float e0 = __expf(s[0] - m), e1 = __expf(s[1] - m);
  float e2 = __expf(s[2] - m), e3 = __expf(s[3] - m);
  float inv = 1.0f / (e0 + e1 + e2 + e3);
  float a0 = e0 * inv, a1 = e1 * inv, a2 = e2 * inv, a3 = e3 * inv;
  unsigned short* c = C + (long)(bp * 4 + w) * 1024;
  const unsigned short* v0 = QKV + (long)(bp * 4 + 0) * 3072 + 2048;
  const unsigned short* v1 = QKV + (long)(bp * 4 + 1) * 3072 + 2048;
  const unsigned short* v2 = QKV + (long)(bp * 4 + 2) * 3072 + 2048;
  const unsigned short* v3 = QKV + (long)(bp * 4 + 3) * 3072 + 2048;
  for (int e = lane; e < 1024; e += 64) {
    float v = a0 * bf2f(v0[e]) + a1 * bf2f(v1[e]) + a2 * bf2f(v2[e]) + a3 * bf2f(v3[e]);
    c[e] = f2bf(v);
  }
}

// ---------------- bf16 batched transpose with strides ----------------
__global__ __launch_bounds__(256) void k_transpose(const unsigned short* __restrict__ in,
    unsigned short* __restrict__ out, int rows, int cols, int ld_in, int ld_out,
    long inB, long outB) {
  __shared__ unsigned short tile[32][33];
  long ibase = (long)blockIdx.z * inB;
  long obase = (long)blockIdx.z * outB;
  int r0 = blockIdx.y * 32, c0 = blockIdx.x * 32;
  int tx = threadIdx.x, ty = threadIdx.y;
  for (int i = ty; i < 32; i += 8)
    tile[i][tx] = in[ibase + (long)(r0 + i) * ld_in + c0 + tx];
  __syncthreads();
  for (int i = ty; i < 32; i += 8)
    out[obase + (long)(c0 + i) * ld_out + r0 + tx] = tile[tx][i];
}

// ---------------- log-softmax: bf16 logits in, f32 out ----------------
__global__ __launch_bounds__(320) void k_logsoftmax_b(
    const unsigned short* __restrict__ Lb, float* __restrict__ out) {
  __shared__ float sm[5];
  int row = blockIdx.x, t = threadIdx.x;
  const unsigned long long* xr =
      (const unsigned long long*)(Lb + (long)row * VOCAB);
  float* yr = out + (long)row * VOCAB;
  float4 v[25];
  float m = -1e30f;
#pragma unroll
  for (int i = 0; i < 25; ++i) {
    unsigned long long u = __builtin_nontemporal_load(&xr[t + i * 320]);
    v[i].x = bf2f((unsigned short)(u & 0xffffu));
    v[i].y = bf2f((unsigned short)((u >> 16) & 0xffffu));
    v[i].z = bf2f((unsigned short)((u >> 32) & 0xffffu));
    v[i].w = bf2f((unsigned short)(u >> 48));
    m = fmaxf(m, fmaxf(fmaxf(v[i].x, v[i].y), fmaxf(v[i].z, v[i].w)));
  }
  m = wave_max(m);
  if ((t & 63) == 0) sm[t >> 6] = m;
  __syncthreads();
  m = fmaxf(fmaxf(fmaxf(sm[0], sm[1]), fmaxf(sm[2], sm[3])), sm[4]);
  __syncthreads();
  float s = 0.0f;
#pragma unroll
  for (int i = 0; i < 25; ++i)
    s += __expf(v[i].x - m) + __expf(v[i].y - m) + __expf(v[i].z - m) + __expf(v[i].w - m);
  s = wave_sum(s);
  if ((t & 63) == 0) sm[t >> 6] = s;
  __syncthreads();
  float l = m + __logf(sm[0] + sm[1] + sm[2] + sm[3] + sm[4]);
#pragma unroll
  for (int i = 0; i < 25; ++i) {
    float4 o = v[i];
    o.x -= l; o.y -= l; o.z -= l; o.w -= l;
    ((float4*)yr)[t + i * 320] = o;
  }
}

// ---------------- log-softmax fallback: in-place f32 ----------------
__global__ __launch_bounds__(320) void k_logsoftmax(float* __restrict__ L) {
  __shared__ float sm[5];
  int row = blockIdx.x, t = threadIdx.x;
  float* x = L + (long)row * VOCAB;
  float4 v[25];
  float m = -1e30f;
#pragma unroll
  for (int i = 0; i < 25; ++i) {
    v[i] = ((const float4*)x)[t + i * 320];
    m = fmaxf(m, fmaxf(fmaxf(v[i].x, v[i].y), fmaxf(v[i].z, v[i].w)));
  }
  m = wave_max(m);
  if ((t & 63) == 0) sm[t >> 6] = m;
  __syncthreads();
  m = fmaxf(fmaxf(fmaxf(sm[0], sm[1]), fmaxf(sm[2], sm[3])), sm[4]);
  __syncthreads();
  float s = 0.0f;
#pragma unroll
  for (int i = 0; i < 25; ++i)
    s += __expf(v[i].x - m) + __expf(v[i].y - m) + __expf(v[i].z - m) + __expf(v[i].w - m);
  s = wave_sum(s);
  if ((t & 63) == 0) sm[t >> 6] = s;
  __syncthreads();
  float l = m + __logf(sm[0] + sm[1] + sm[2] + sm[3] + sm[4]);
#pragma unroll
  for (int i = 0; i < 25; ++i) {
    float4 o = v[i];
    o.x -= l; o.y -= l; o.z -= l; o.w -= l;
    ((float4*)x)[t + i * 320] = o;
  }
}

__global__ __launch_bounds__(256) void k_addbias(const float* __restrict__ a,
    const float* __restrict__ b, float* __restrict__ o, int n) {
  int i = blockIdx.x * 256 + threadIdx.x;
  if (i < n) o[i] = a[i] + b[i];
}

// ---------------- host ----------------
extern "C" void kernel_launch(void* const* d_in, const int* in_sizes, int n_in,
                              void* d_out, int out_size, void* d_ws, size_t ws_size,
                              hipStream_t stream) {
  const int* x = (const int*)d_in[0];
  const float* wemb = (const float*)d_in[1];
  const float* pemb = (const float*)d_in[2];
  const float* wq = (const float*)d_in[3];
  const float* wk = (const float*)d_in[4];
  const float* wv = (const float*)d_in[5];
  const float* wc = (const float*)d_in[6];
  const float* ln1g = (const float*)d_in[7];
  const float* ln1b = (const float*)d_in[8];
  const float* w1 = (const float*)d_in[9];
  const float* b1 = (const float*)d_in[10];
  const float* w2 = (const float*)d_in[11];
  const float* b2 = (const float*)d_in[12];
  const float* ln2g = (const float*)d_in[13];
  const float* ln2b = (const float*)d_in[14];
  const float* decw = (const float*)d_in[15];
  const float* decb = (const float*)d_in[16];
  const float* obias = (const float*)d_in[17];
  float* out = (float*)d_out;

  char* ws = (char*)d_ws;
  size_t off = 0;
  auto alloc = [&](size_t bytes) -> char* {
    char* p = ws + off;
    off += (bytes + 255) & ~(size_t)255;
    return p;
  };
  float* z = (float*)alloc((size_t)NROW * DMODEL * 4);
  unsigned short* xb = (unsigned short*)alloc((size_t)NROW * DMODEL * 2);
  unsigned short* qkv = (unsigned short*)alloc((size_t)NROW * 3072 * 2);
  unsigned short* vt = (unsigned short*)alloc((size_t)NROW * HKDIM * 2);
  unsigned short* wbuf = (unsigned short*)alloc((size_t)MDIM * DMODEL * 2);
  float* tmp16 = (float*)alloc((size_t)NROW * 1024 * 4);
  unsigned short* am = (unsigned short*)alloc((size_t)NROW * 1024 * 2);
  unsigned short* ctx = (unsigned short*)alloc((size_t)NROW * HKDIM * 2);
  unsigned short* hb = (unsigned short*)alloc((size_t)NROW * DMODEL * 2);
  unsigned short* f = (unsigned short*)alloc((size_t)NROW * MDIM * 2);
  unsigned short* dwb = (unsigned short*)alloc((size_t)VOCAB * DMODEL * 2);
  unsigned short* zb = (unsigned short*)alloc((size_t)NROW * DMODEL * 2);
  float* biasD = (float*)alloc((size_t)VOCAB * 4);
  unsigned short* logits = (unsigned short*)alloc((size_t)NROW * VOCAB * 2);
  const bool bfLogits = (off <= ws_size);  // deterministic: ws_size fixed per deploy
  (void)in_sizes; (void)n_in; (void)out_size;

  auto gemm = [&](const unsigned short* A, const unsigned short* B, float* Cf,
                  unsigned short* Cb, const float* bias, const unsigned short* resb,
                  int M, int N, int K, int lda, int ldb, int ldc, int batch,
                  long aB, long bB, long cB, float scale) {
    dim3 g(N / 128, M / 128, batch);
    k_gemm_bt<<<g, dim3(256), 0, stream>>>(A, B, Cf, Cb, bias, resb, M, N, K,
                                           lda, ldb, ldc, aB, bB, cB, scale);
  };
  auto gemm64 = [&](const unsigned short* A, const unsigned short* B, float* Cf,
                    unsigned short* Cb, const float* bias, const unsigned short* resb,
                    int M, int N, int K, int lda, int ldb, int ldc, int batch,
                    long aB, long bB, long cB, float scale) {
    dim3 g(N / 128, M / 64, batch);
    k_gemm64<<<g, dim3(256), 0, stream>>>(A, B, Cf, Cb, bias, resb, M, N, K,
                                          lda, ldb, ldc, aB, bB, cB, scale);
  };
  auto gemm8s = [&](const unsigned short* A, const unsigned short* B, float* Cf,
                    unsigned short* Cb, const float* bias, int M, int N, int K,
                    int lda, int ldb, int ldc) {
    k_gemm8s<<<dim3(N / 256, M / 256, 1), dim3(512), 0, stream>>>(
        A, B, Cf, Cb, bias, M, N, K, lda, ldb, ldc);
  };
  auto cvt = [&](const float* in, unsigned short* o, long n) {
    int n4 = (int)(n / 4);
    int grid = (n4 + 255) / 256;
    if (grid > 2048) grid = 2048;
    k_cvt<<<dim3(grid), dim3(256), 0, stream>>>(in, o, n4);
  };

  k_embed<<<NROW, 256, 0, stream>>>(x, wemb, pemb, z);

  for (int i = 0; i < NLAYER; ++i) {
    int A0 = (i % 2 == 0) ? 1024 : 4;
    int A1 = 4096 / A0;
    k_permute<<<NROW, 256, 0, stream>>>(z, xb, A0, A1);

    // merged QKV: weights stacked [3072,1024] (768 blocks, 3/CU)
    cvt(wq + (long)i * HKDIM * DMODEL, wbuf, (long)HKDIM * DMODEL);
    cvt(wk + (long)i * HKDIM * DMODEL, wbuf + (size_t)1024 * DMODEL, (long)HKDIM * DMODEL);
    cvt(wv + (long)i * HKDIM * DMODEL, wbuf + (size_t)2048 * DMODEL, (long)HKDIM * DMODEL);
    gemm(xb, wbuf, nullptr, qkv, nullptr, nullptr, NROW, 3072, DMODEL,
         DMODEL, DMODEL, 3072, 1, 0, 0, 0, 1.0f);

    if (A0 == 1024) {  // even: full attention over S=1024, 4 batches
      gemm64(qkv, qkv + 1024, tmp16, nullptr, nullptr, nullptr, 1024, 1024, 1024,
             3072, 3072, 1024, 4, (long)1024 * 3072, (long)1024 * 3072, 1 << 20,
             1.0f / 32.0f);
      k_softmax<<<NROW, 256, 0, stream>>>(tmp16, am);
      k_transpose<<<dim3(32, 32, 4), dim3(32, 8), 0, stream>>>(
          qkv + 2048, vt, 1024, 1024, 3072, 1024, (long)1024 * 3072, 1 << 20);
      gemm64(am, vt, nullptr, ctx, nullptr, nullptr, 1024, 1024, 1024,
             1024, 1024, 1024, 4, 1 << 20, 1 << 20, 1 << 20, 1.0f);
    } else {  // odd: seq length 4
      k_attn4<<<1024, 256, 0, stream>>>(qkv, ctx);
    }

    // proj + bf16 residual  (N=1024: 64-row tiles -> 512 blocks, 2/CU)
    cvt(wc + (long)i * DMODEL * HKDIM, wbuf, (long)DMODEL * HKDIM);
    gemm64(ctx, wbuf, tmp16, nullptr, nullptr, xb, NROW, DMODEL, HKDIM,
           HKDIM, HKDIM, DMODEL, 1, 0, 0, 0, 1.0f);
    k_ln<<<NROW, 256, 0, stream>>>(tmp16, nullptr, ln1g + (long)i * DMODEL,
                                   ln1b + (long)i * DMODEL, nullptr, hb);
    cvt(w1 + (long)i * MDIM * DMODEL, wbuf, (long)MDIM * DMODEL);
    gemm(hb, wbuf, nullptr, f, b1 + (long)i * MDIM, nullptr, NROW, MDIM, DMODEL,
         DMODEL, DMODEL, MDIM, 1, 0, 0, 0, 1.0f);
    cvt(w2 + (long)i * DMODEL * MDIM, wbuf, (long)DMODEL * MDIM);
    gemm64(f, wbuf, tmp16, nullptr, b2 + (long)i * DMODEL, nullptr, NROW, DMODEL, MDIM,
           MDIM, MDIM, DMODEL, 1, 0, 0, 0, 1.0f);
    // final layer: LN2 writes bf16 zb directly (skips f32 z + cvt)
    if (i == NLAYER - 1)
      k_ln<<<NROW, 256, 0, stream>>>(tmp16, hb, ln2g + (long)i * DMODEL,
                                     ln2b + (long)i * DMODEL, nullptr, zb);
    else
      k_ln<<<NROW, 256, 0, stream>>>(tmp16, hb, ln2g + (long)i * DMODEL,
                                     ln2b + (long)i * DMODEL, z, nullptr);
  }

  // decoder: single-buffered 256^2 (2 blocks/CU), bf16 logits when ws allows
  cvt(decw, dwb, (long)VOCAB * DMODEL);
  k_addbias<<<(VOCAB + 255) / 256, 256, 0, stream>>>(decb, obias, biasD, VOCAB);
  if (bfLogits) {
    gemm8s(zb, dwb, nullptr, logits, biasD, NROW, VOCAB, DMODEL, DMODEL, DMODEL, VOCAB);
    k_logsoftmax_b<<<NROW, 320, 0, stream>>>(logits, out);
  } else {
    gemm8s(zb, dwb, out, nullptr, biasD, NROW, VOCAB, DMODEL, DMODEL, DMODEL, VOCAB);
    k_logsoftmax<<<NROW, 320, 0, stream>>>(out);
  }
}

// Round 12
// 2197.018 us; speedup vs baseline: 1.9629x; 1.0511x over previous
//
#include <hip/hip_runtime.h>

// ---------------- types / constants ----------------
typedef short short8 __attribute__((ext_vector_type(8)));
typedef float f32x4 __attribute__((ext_vector_type(4)));

#define DMODEL 1024
#define HKDIM 1024
#define MDIM 4096
#define NROW 4096   // S*B = 1024*4
#define VOCAB 32000
#define NLAYER 6

#define GLOAD_LDS16(g, l)                                                      \
  __builtin_amdgcn_global_load_lds(                                            \
      (const __attribute__((address_space(1))) void*)(g),                      \
      (__attribute__((address_space(3))) void*)(l), 16, 0, 0)

__device__ __forceinline__ unsigned short f2bf(float f) {
  unsigned u = __float_as_uint(f);
  u += 0x7fffu + ((u >> 16) & 1u);
  return (unsigned short)(u >> 16);
}
__device__ __forceinline__ float bf2f(unsigned short h) {
  return __uint_as_float(((unsigned)h) << 16);
}
__device__ __forceinline__ float wave_sum(float v) {
  for (int o = 32; o; o >>= 1) v += __shfl_xor(v, o);
  return v;
}
__device__ __forceinline__ float wave_max(float v) {
  for (int o = 32; o; o >>= 1) v = fmaxf(v, __shfl_xor(v, o));
  return v;
}

// ---------------- embedding ----------------
__global__ __launch_bounds__(256) void k_embed(const int* __restrict__ x,
    const float* __restrict__ wemb, const float* __restrict__ pemb,
    float* __restrict__ z) {
  int r = blockIdx.x;           // r = s*4 + b
  int s = r >> 2;
  int tok = x[r];
  float4 a = ((const float4*)(wemb + (long)tok * DMODEL))[threadIdx.x];
  float4 p = ((const float4*)(pemb + (long)s * DMODEL))[threadIdx.x];
  float4 o;
  o.x = fmaxf(a.x * 32.0f + p.x, 0.0f);
  o.y = fmaxf(a.y * 32.0f + p.y, 0.0f);
  o.z = fmaxf(a.z * 32.0f + p.z, 0.0f);
  o.w = fmaxf(a.w * 32.0f + p.w, 0.0f);
  ((float4*)(z + (long)r * DMODEL))[threadIdx.x] = o;
}

// ---------------- permute rows: x = swapaxes(z,0,1), bf16 out only ----------------
__global__ __launch_bounds__(256) void k_permute(const float* __restrict__ zin,
    unsigned short* __restrict__ xb, int A0, int A1) {
  int r = blockIdx.x;
  int a1 = r / A0, a0 = r - a1 * A0;
  float4 v = ((const float4*)(zin + (long)(a0 * A1 + a1) * DMODEL))[threadIdx.x];
  ushort4 o = make_ushort4(f2bf(v.x), f2bf(v.y), f2bf(v.z), f2bf(v.w));
  ((ushort4*)(xb + (long)r * DMODEL))[threadIdx.x] = o;
}

// ---------------- f32 -> bf16 ----------------
__global__ __launch_bounds__(256) void k_cvt(const float* __restrict__ in,
    unsigned short* __restrict__ out, int n4) {
  int i = blockIdx.x * 256 + threadIdx.x;
  int stride = gridDim.x * 256;
  for (; i < n4; i += stride) {
    float4 v = ((const float4*)in)[i];
    ((ushort4*)out)[i] = make_ushort4(f2bf(v.x), f2bf(v.y), f2bf(v.z), f2bf(v.w));
  }
}

// ---------------- 128x128 bf16 GEMM (m97 structure + T2 + XCD swizzle) ------------
__global__ __launch_bounds__(256) void k_gemm_bt(
    const unsigned short* __restrict__ A, const unsigned short* __restrict__ B,
    float* __restrict__ Cf, unsigned short* __restrict__ Cb,
    const float* __restrict__ bias, const unsigned short* __restrict__ resb,
    int M, int N, int K, int lda, int ldb, int ldc,
    long aB, long bB, long cB, float scale) {
  __shared__ unsigned short As[128 * 64];
  __shared__ unsigned short Bs[128 * 64];
  const int tid = threadIdx.x;
  const int gx = gridDim.x, gy = gridDim.y;

  int nwg = gx * gy * gridDim.z;
  int flat = blockIdx.x + gx * (blockIdx.y + gy * blockIdx.z);
  int q8 = nwg >> 3, r8 = nwg & 7;
  int xcd = flat & 7, inner = flat >> 3;
  int wg = (xcd < r8 ? xcd * (q8 + 1) : r8 * (q8 + 1) + (xcd - r8) * q8) + inner;
  int ty = wg % gy;         // y-fastest: co-XCD consecutive blocks share B-panel
  int rest = wg / gy;
  int tx = rest % gx;
  int tz = rest / gx;

  const unsigned short* Ab = A + (long)tz * aB;
  const unsigned short* Bb = B + (long)tz * bB;
  const int row0 = ty * 128, col0 = tx * 128;
  const int lane = tid & 63, w = tid >> 6;
  const int wm = w >> 1, wn = w & 1;
  const int fr = lane & 15, fg = lane >> 4, fr7 = fr & 7;
  const int lrow = lane >> 3;
  const int lcol = ((lane & 7) ^ lrow) * 8;  // T2: pre-swizzled global source chunk

  const unsigned short* aSrc = Ab + (long)(row0 + w * 32 + lrow) * lda + lcol;
  const unsigned short* bSrc = Bb + (long)(col0 + w * 32 + lrow) * ldb + lcol;
  unsigned short* aDst = As + w * 32 * 64;  // linear wave-uniform LDS dest
  unsigned short* bDst = Bs + w * 32 * 64;

  f32x4 acc[4][4];
#pragma unroll
  for (int i = 0; i < 4; ++i)
#pragma unroll
    for (int j = 0; j < 4; ++j)
#pragma unroll
      for (int qq = 0; qq < 4; ++qq) acc[i][j][qq] = 0.0f;

  for (int k0 = 0; k0 < K; k0 += 64) {
#pragma unroll
    for (int i = 0; i < 4; ++i) {
      GLOAD_LDS16(aSrc + (long)i * 8 * lda + k0, aDst + i * 512);
      GLOAD_LDS16(bSrc + (long)i * 8 * ldb + k0, bDst + i * 512);
    }
    __syncthreads();
#pragma unroll
    for (int kk = 0; kk < 64; kk += 32) {
      short8 af[4], bfr[4];
#pragma unroll
      for (int i = 0; i < 4; ++i) {
        af[i] = *(const short8*)(As + (wm * 64 + i * 16 + fr) * 64 +
                                 (((kk >> 3) + fg) ^ fr7) * 8);
        bfr[i] = *(const short8*)(Bs + (wn * 64 + i * 16 + fr) * 64 +
                                  (((kk >> 3) + fg) ^ fr7) * 8);
      }
#pragma unroll
      for (int i = 0; i < 4; ++i)
#pragma unroll
        for (int j = 0; j < 4; ++j)
          acc[i][j] = __builtin_amdgcn_mfma_f32_16x16x32_bf16(af[i], bfr[j], acc[i][j], 0, 0, 0);
    }
    __syncthreads();
  }

#pragma unroll
  for (int i = 0; i < 4; ++i) {
#pragma unroll
    for (int qq = 0; qq < 4; ++qq) {
      int row = row0 + wm * 64 + i * 16 + fg * 4 + qq;
#pragma unroll
      for (int j = 0; j < 4; ++j) {
        int col = col0 + wn * 64 + j * 16 + fr;
        long off = cB * tz + (long)row * ldc + col;
        float v = acc[i][j][qq] * scale + (bias ? bias[col] : 0.0f);
        if (resb) v += bf2f(resb[off]);
        if (Cf) Cf[off] = v;
        if (Cb) Cb[off] = f2bf(v);
      }
    }
  }
}

// ---------------- 64x128 bf16 GEMM variant for N=1024 shapes ----------------
__global__ __launch_bounds__(256) void k_gemm64(
    const unsigned short* __restrict__ A, const unsigned short* __restrict__ B,
    float* __restrict__ Cf, unsigned short* __restrict__ Cb,
    const float* __restrict__ bias, const unsigned short* __restrict__ resb,
    int M, int N, int K, int lda, int ldb, int ldc,
    long aB, long bB, long cB, float scale) {
  __shared__ unsigned short As[64 * 64];
  __shared__ unsigned short Bs[128 * 64];
  const int tid = threadIdx.x;
  const int gx = gridDim.x, gy = gridDim.y;

  int nwg = gx * gy * gridDim.z;
  int flat = blockIdx.x + gx * (blockIdx.y + gy * blockIdx.z);
  int q8 = nwg >> 3, r8 = nwg & 7;
  int xcd = flat & 7, inner = flat >> 3;
  int wg = (xcd < r8 ? xcd * (q8 + 1) : r8 * (q8 + 1) + (xcd - r8) * q8) + inner;
  int ty = wg % gy;
  int rest = wg / gy;
  int tx = rest % gx;
  int tz = rest / gx;

  const unsigned short* Ab = A + (long)tz * aB;
  const unsigned short* Bb = B + (long)tz * bB;
  const int row0 = ty * 64, col0 = tx * 128;
  const int lane = tid & 63, w = tid >> 6;
  const int wm = w >> 1, wn = w & 1;
  const int fr = lane & 15, fg = lane >> 4, fr7 = fr & 7;
  const int lrow = lane >> 3;
  const int lcol = ((lane & 7) ^ lrow) * 8;

  const unsigned short* aSrc = Ab + (long)(row0 + w * 16 + lrow) * lda + lcol;
  const unsigned short* bSrc = Bb + (long)(col0 + w * 32 + lrow) * ldb + lcol;
  unsigned short* aDst = As + w * 16 * 64;
  unsigned short* bDst = Bs + w * 32 * 64;

  f32x4 acc[2][4];
#pragma unroll
  for (int i = 0; i < 2; ++i)
#pragma unroll
    for (int j = 0; j < 4; ++j)
#pragma unroll
      for (int qq = 0; qq < 4; ++qq) acc[i][j][qq] = 0.0f;

  for (int k0 = 0; k0 < K; k0 += 64) {
#pragma unroll
    for (int i = 0; i < 2; ++i)
      GLOAD_LDS16(aSrc + (long)i * 8 * lda + k0, aDst + i * 512);
#pragma unroll
    for (int i = 0; i < 4; ++i)
      GLOAD_LDS16(bSrc + (long)i * 8 * ldb + k0, bDst + i * 512);
    __syncthreads();
#pragma unroll
    for (int kk = 0; kk < 64; kk += 32) {
      short8 af[2], bfr[4];
#pragma unroll
      for (int i = 0; i < 2; ++i)
        af[i] = *(const short8*)(As + (wm * 32 + i * 16 + fr) * 64 +
                                 (((kk >> 3) + fg) ^ fr7) * 8);
#pragma unroll
      for (int j = 0; j < 4; ++j)
        bfr[j] = *(const short8*)(Bs + (wn * 64 + j * 16 + fr) * 64 +
                                  (((kk >> 3) + fg) ^ fr7) * 8);
#pragma unroll
      for (int i = 0; i < 2; ++i)
#pragma unroll
        for (int j = 0; j < 4; ++j)
          acc[i][j] = __builtin_amdgcn_mfma_f32_16x16x32_bf16(af[i], bfr[j], acc[i][j], 0, 0, 0);
    }
    __syncthreads();
  }

#pragma unroll
  for (int i = 0; i < 2; ++i) {
#pragma unroll
    for (int qq = 0; qq < 4; ++qq) {
      int row = row0 + wm * 32 + i * 16 + fg * 4 + qq;
#pragma unroll
      for (int j = 0; j < 4; ++j) {
        int col = col0 + wn * 64 + j * 16 + fr;
        long off = cB * tz + (long)row * ldc + col;
        float v = acc[i][j][qq] * scale + (bias ? bias[col] : 0.0f);
        if (resb) v += bf2f(resb[off]);
        if (Cf) Cf[off] = v;
        if (Cb) Cb[off] = f2bf(v);
      }
    }
  }
}

// ---------------- 256x256 2-phase bf16 GEMM (decoder; r9 best: 400us) ----------
// 512 threads = 8 waves (2M x 4N); BK=64, double-buffered LDS. Issue next tile's
// DMA first, then compute, then ONE __syncthreads() per K-tile.
__global__ __launch_bounds__(512, 2) void k_gemm8(
    const unsigned short* __restrict__ A, const unsigned short* __restrict__ B,
    float* __restrict__ Cf, unsigned short* __restrict__ Cb,
    const float* __restrict__ bias, int M, int N, int K,
    int lda, int ldb, int ldc) {
  __shared__ unsigned short As[2][256 * 64];
  __shared__ unsigned short Bs[2][256 * 64];
  const int tid = threadIdx.x;
  const int gx = gridDim.x, gy = gridDim.y;
  int nwg = gx * gy;
  int flat = blockIdx.x + gx * blockIdx.y;
  int q8 = nwg >> 3, r8 = nwg & 7;
  int xcd = flat & 7, inner = flat >> 3;
  int wg = (xcd < r8 ? xcd * (q8 + 1) : r8 * (q8 + 1) + (xcd - r8) * q8) + inner;
  int ty = wg % gy, tx = wg / gy;

  const int row0 = ty * 256, col0 = tx * 256;
  const int lane = tid & 63, w = tid >> 6;
  const int wm = w >> 2, wn = w & 3;
  const int fr = lane & 15, fg = lane >> 4, fr7 = fr & 7;
  const int srow = lane >> 3;
  const int scol = ((lane & 7) ^ srow) * 8;   // T2 pre-swizzled source chunk

  const unsigned short* pA = A + (size_t)(row0 + w * 32 + srow) * lda + scol;
  const unsigned short* pB = B + (size_t)(col0 + w * 32 + srow) * ldb + scol;
  unsigned short* aD0 = &As[0][w * 32 * 64];
  unsigned short* bD0 = &Bs[0][w * 32 * 64];
  unsigned short* aD1 = &As[1][w * 32 * 64];
  unsigned short* bD1 = &Bs[1][w * 32 * 64];

  auto stage = [&](int bf, int tk) {
    unsigned short* aD = bf ? aD1 : aD0;
    unsigned short* bD = bf ? bD1 : bD0;
#pragma unroll
    for (int i = 0; i < 4; ++i) {
      GLOAD_LDS16(pA + (size_t)i * 8 * lda + (size_t)tk * 64, aD + i * 512);
      GLOAD_LDS16(pB + (size_t)i * 8 * ldb + (size_t)tk * 64, bD + i * 512);
    }
  };
  auto rdA = [&](const unsigned short* lds, int i, int kq) -> short8 {
    return *(const short8*)(lds + (wm * 128 + i * 16 + fr) * 64 +
                            (((kq << 2) + fg) ^ fr7) * 8);
  };
  auto rdB = [&](const unsigned short* lds, int j, int kq) -> short8 {
    return *(const short8*)(lds + (wn * 64 + j * 16 + fr) * 64 +
                            (((kq << 2) + fg) ^ fr7) * 8);
  };

  f32x4 acc[8][4];
#pragma unroll
  for (int i = 0; i < 8; ++i)
#pragma unroll
    for (int j = 0; j < 4; ++j)
#pragma unroll
      for (int qq = 0; qq < 4; ++qq) acc[i][j][qq] = 0.0f;

  const int NT = K >> 6;

  stage(0, 0);
  __syncthreads();

  for (int t = 0; t < NT; ++t) {
    const unsigned short* aL = (t & 1) ? &As[1][0] : &As[0][0];
    const unsigned short* bL = (t & 1) ? &Bs[1][0] : &Bs[0][0];
    if (t + 1 < NT) stage((t & 1) ^ 1, t + 1);  // issue next-tile DMA first
#pragma unroll
    for (int kq = 0; kq < 2; ++kq) {
      short8 a8[8], b8[4];
#pragma unroll
      for (int i = 0; i < 8; ++i) a8[i] = rdA(aL, i, kq);
#pragma unroll
      for (int j = 0; j < 4; ++j) b8[j] = rdB(bL, j, kq);
#pragma unroll
      for (int i = 0; i < 8; ++i)
#pragma unroll
        for (int j = 0; j < 4; ++j)
          acc[i][j] = __builtin_amdgcn_mfma_f32_16x16x32_bf16(a8[i], b8[j], acc[i][j], 0, 0, 0);
    }
    __syncthreads();
  }

  // epilogue: j innermost so each row's 128B span is written by adjacent stores
#pragma unroll
  for (int i = 0; i < 8; ++i) {
#pragma unroll
    for (int qq = 0; qq < 4; ++qq) {
      int row = row0 + wm * 128 + i * 16 + fg * 4 + qq;
#pragma unroll
      for (int j = 0; j < 4; ++j) {
        int col = col0 + wn * 64 + j * 16 + fr;
        size_t off = (size_t)row * ldc + col;
        float v = acc[i][j][qq] + (bias ? bias[col] : 0.0f);
        if (Cf) Cf[off] = v;
        if (Cb) Cb[off] = f2bf(v);
      }
    }
  }
}

// ---------------- layernorm: X f32 (+ optional bf16 X2) -> f32/bf16 out -------------
// If pA1 > 0, outB is written at the PERMUTED destination row for the next layer:
// src row s -> dst (s % pA1) * pA0 + s / pA1  (fuses the inter-layer k_permute).
__global__ __launch_bounds__(256) void k_ln(const float* __restrict__ X,
    const unsigned short* __restrict__ X2b, const float* __restrict__ g,
    const float* __restrict__ b, float* __restrict__ outF,
    unsigned short* __restrict__ outB, int pA0, int pA1) {
  __shared__ float sm[4];
  int row = blockIdx.x, t = threadIdx.x;
  float4 v = ((const float4*)(X + (long)row * DMODEL))[t];
  if (X2b) {
    ushort4 u = ((const ushort4*)(X2b + (long)row * DMODEL))[t];
    v.x += bf2f(u.x); v.y += bf2f(u.y); v.z += bf2f(u.z); v.w += bf2f(u.w);
  }
  float s = wave_sum(v.x + v.y + v.z + v.w);
  if ((t & 63) == 0) sm[t >> 6] = s;
  __syncthreads();
  float mean = (sm[0] + sm[1] + sm[2] + sm[3]) * (1.0f / DMODEL);
  __syncthreads();
  float4 c;
  c.x = v.x - mean; c.y = v.y - mean; c.z = v.z - mean; c.w = v.w - mean;
  float ss = wave_sum(c.x * c.x + c.y * c.y + c.z * c.z + c.w * c.w);
  if ((t & 63) == 0) sm[t >> 6] = ss;
  __syncthreads();
  float var = (sm[0] + sm[1] + sm[2] + sm[3]) * (1.0f / DMODEL);
  float rs = rsqrtf(var + 1e-5f);
  float4 gv = ((const float4*)g)[t], bv = ((const float4*)b)[t];
  float4 o;
  o.x = c.x * rs * gv.x + bv.x;
  o.y = c.y * rs * gv.y + bv.y;
  o.z = c.z * rs * gv.z + bv.z;
  o.w = c.w * rs * gv.w + bv.w;
  if (outF) ((float4*)(outF + (long)row * DMODEL))[t] = o;
  if (outB) {
    int d = row;
    if (pA1 > 0) d = (row % pA1) * pA0 + row / pA1;
    ((ushort4*)(outB + (long)d * DMODEL))[t] =
        make_ushort4(f2bf(o.x), f2bf(o.y), f2bf(o.z), f2bf(o.w));
  }
}

// ---------------- softmax (rows of 1024) ----------------
__global__ __launch_bounds__(256) void k_softmax(const float* __restrict__ S,
    unsigned short* __restrict__ A) {
  __shared__ float sm[4];
  int row = blockIdx.x, t = threadIdx.x;
  float4 v = ((const float4*)(S + (long)row * 1024))[t];
  float m = wave_max(fmaxf(fmaxf(v.x, v.y), fmaxf(v.z, v.w)));
  if ((t & 63) == 0) sm[t >> 6] = m;
  __syncthreads();
  m = fmaxf(fmaxf(sm[0], sm[1]), fmaxf(sm[2], sm[3]));
  __syncthreads();
  float4 e;
  e.x = __expf(v.x - m); e.y = __expf(v.y - m);
  e.z = __expf(v.z - m); e.w = __expf(v.w - m);
  float s = wave_sum(e.x + e.y + e.z + e.w);
  if ((t & 63) == 0) sm[t >> 6] = s;
  __syncthreads();
  float inv = 1.0f / (sm[0] + sm[1] + sm[2] + sm[3]);
  ((ushort4*)(A + (long)row * 1024))[t] =
      make_ushort4(f2bf(e.x * inv), f2bf(e.y * inv), f2bf(e.z * inv), f2bf(e.w * inv));
}

// ---------------- odd layers: seq-4 attention (QKV packed, stride 3072) -------------
__global__ __launch_bounds__(256) void k_attn4(const unsigned short* __restrict__ QKV,
    unsigned short* __restrict__ C) {
  int bp = blockIdx.x;
  int w = threadIdx.x >> 6, lane = threadIdx.x & 63;
  const unsigned short* q = QKV + (long)(bp * 4 + w) * 3072;
  float s[4];
  for (int j = 0; j < 4; ++j) {
    const unsigned short* kj = QKV + (long)(bp * 4 + j) * 3072 + 1024;
    float a = 0.0f;
    for (int e = lane; e < 1024; e += 64) a += bf2f(q[e]) * bf2f(kj[e]);
    s[j] = wave_sum(a) * (1.0f / 32.0f);
  }
  float m = fmaxf(fmaxf(s[0], s[1]), fmaxf(s[2], s[3]));
  float e0 = __expf(s[0] - m), e1 = __expf(s[1] - m);
  float e2 = __expf(s[2] - m), e3 = __expf(s[3] - m);
  float inv = 1.0f / (e0 + e1 + e2 + e3);
  float a0 = e0 * inv, a1 = e1 * inv, a2 = e2 * inv, a3 = e3 * inv;
  unsigned short* c = C + (long)(bp * 4 + w) * 1024;
  const unsigned short* v0 = QKV + (long)(bp * 4 + 0) * 3072 + 2048;
  const unsigned short* v1 = QKV + (long)(bp * 4 + 1) * 3072 + 2048;
  const unsigned short* v2 = QKV + (long)(bp * 4 + 2) * 3072 + 2048;
  const unsigned short* v3 = QKV + (long)(bp * 4 + 3) * 3072 + 2048;
  for (int e = lane; e < 1024; e += 64) {
    float v = a0 * bf2f(v0[e]) + a1 * bf2f(v1[e]) + a2 * bf2f(v2[e]) + a3 * bf2f(v3[e]);
    c[e] = f2bf(v);
  }
}

// ---------------- bf16 batched transpose with strides ----------------
__global__ __launch_bounds__(256) void k_transpose(const unsigned short* __restrict__ in,
    unsigned short* __restrict__ out, int rows, int cols, int ld_in, int ld_out,
    long inB, long outB) {
  __shared__ unsigned short tile[32][33];
  long ibase = (long)blockIdx.z * inB;
  long obase = (long)blockIdx.z * outB;
  int r0 = blockIdx.y * 32, c0 = blockIdx.x * 32;
  int tx = threadIdx.x, ty = threadIdx.y;
  for (int i = ty; i < 32; i += 8)
    tile[i][tx] = in[ibase + (long)(r0 + i) * ld_in + c0 + tx];
  __syncthreads();
  for (int i = ty; i < 32; i += 8)
    out[obase + (long)(c0 + i) * ld_out + r0 + tx] = tile[tx][i];
}

// ---------------- log-softmax: bf16 logits in, f32 out ----------------
__global__ __launch_bounds__(320) void k_logsoftmax_b(
    const unsigned short* __restrict__ Lb, float* __restrict__ out) {
  __shared__ float sm[5];
  int row = blockIdx.x, t = threadIdx.x;
  const unsigned long long* xr =
      (const unsigned long long*)(Lb + (long)row * VOCAB);
  float* yr = out + (long)row * VOCAB;
  float4 v[25];
  float m = -1e30f;
#pragma unroll
  for (int i = 0; i < 25; ++i) {
    unsigned long long u = __builtin_nontemporal_load(&xr[t + i * 320]);
    v[i].x = bf2f((unsigned short)(u & 0xffffu));
    v[i].y = bf2f((unsigned short)((u >> 16) & 0xffffu));
    v[i].z = bf2f((unsigned short)((u >> 32) & 0xffffu));
    v[i].w = bf2f((unsigned short)(u >> 48));
    m = fmaxf(m, fmaxf(fmaxf(v[i].x, v[i].y), fmaxf(v[i].z, v[i].w)));
  }
  m = wave_max(m);
  if ((t & 63) == 0) sm[t >> 6] = m;
  __syncthreads();
  m = fmaxf(fmaxf(fmaxf(sm[0], sm[1]), fmaxf(sm[2], sm[3])), sm[4]);
  __syncthreads();
  float s = 0.0f;
#pragma unroll
  for (int i = 0; i < 25; ++i)
    s += __expf(v[i].x - m) + __expf(v[i].y - m) + __expf(v[i].z - m) + __expf(v[i].w - m);
  s = wave_sum(s);
  if ((t & 63) == 0) sm[t >> 6] = s;
  __syncthreads();
  float l = m + __logf(sm[0] + sm[1] + sm[2] + sm[3] + sm[4]);
#pragma unroll
  for (int i = 0; i < 25; ++i) {
    float4 o = v[i];
    o.x -= l; o.y -= l; o.z -= l; o.w -= l;
    ((float4*)yr)[t + i * 320] = o;
  }
}

// ---------------- log-softmax fallback: in-place f32 ----------------
__global__ __launch_bounds__(320) void k_logsoftmax(float* __restrict__ L) {
  __shared__ float sm[5];
  int row = blockIdx.x, t = threadIdx.x;
  float* x = L + (long)row * VOCAB;
  float4 v[25];
  float m = -1e30f;
#pragma unroll
  for (int i = 0; i < 25; ++i) {
    v[i] = ((const float4*)x)[t + i * 320];
    m = fmaxf(m, fmaxf(fmaxf(v[i].x, v[i].y), fmaxf(v[i].z, v[i].w)));
  }
  m = wave_max(m);
  if ((t & 63) == 0) sm[t >> 6] = m;
  __syncthreads();
  m = fmaxf(fmaxf(fmaxf(sm[0], sm[1]), fmaxf(sm[2], sm[3])), sm[4]);
  __syncthreads();
  float s = 0.0f;
#pragma unroll
  for (int i = 0; i < 25; ++i)
    s += __expf(v[i].x - m) + __expf(v[i].y - m) + __expf(v[i].z - m) + __expf(v[i].w - m);
  s = wave_sum(s);
  if ((t & 63) == 0) sm[t >> 6] = s;
  __syncthreads();
  float l = m + __logf(sm[0] + sm[1] + sm[2] + sm[3] + sm[4]);
#pragma unroll
  for (int i = 0; i < 25; ++i) {
    float4 o = v[i];
    o.x -= l; o.y -= l; o.z -= l; o.w -= l;
    ((float4*)x)[t + i * 320] = o;
  }
}

__global__ __launch_bounds__(256) void k_addbias(const float* __restrict__ a,
    const float* __restrict__ b, float* __restrict__ o, int n) {
  int i = blockIdx.x * 256 + threadIdx.x;
  if (i < n) o[i] = a[i] + b[i];
}

// ---------------- host ----------------
extern "C" void kernel_launch(void* const* d_in, const int* in_sizes, int n_in,
                              void* d_out, int out_size, void* d_ws, size_t ws_size,
                              hipStream_t stream) {
  const int* x = (const int*)d_in[0];
  const float* wemb = (const float*)d_in[1];
  const float* pemb = (const float*)d_in[2];
  const float* wq = (const float*)d_in[3];
  const float* wk = (const float*)d_in[4];
  const float* wv = (const float*)d_in[5];
  const float* wc = (const float*)d_in[6];
  const float* ln1g = (const float*)d_in[7];
  const float* ln1b = (const float*)d_in[8];
  const float* w1 = (const float*)d_in[9];
  const float* b1 = (const float*)d_in[10];
  const float* w2 = (const float*)d_in[11];
  const float* b2 = (const float*)d_in[12];
  const float* ln2g = (const float*)d_in[13];
  const float* ln2b = (const float*)d_in[14];
  const float* decw = (const float*)d_in[15];
  const float* decb = (const float*)d_in[16];
  const float* obias = (const float*)d_in[17];
  float* out = (float*)d_out;

  char* ws = (char*)d_ws;
  size_t off = 0;
  auto alloc = [&](size_t bytes) -> char* {
    char* p = ws + off;
    off += (bytes + 255) & ~(size_t)255;
    return p;
  };
  float* z = (float*)alloc((size_t)NROW * DMODEL * 4);
  unsigned short* xb = (unsigned short*)alloc((size_t)NROW * DMODEL * 2);
  unsigned short* qkv = (unsigned short*)alloc((size_t)NROW * 3072 * 2);
  unsigned short* vt = (unsigned short*)alloc((size_t)NROW * HKDIM * 2);
  unsigned short* wbuf = (unsigned short*)alloc((size_t)MDIM * DMODEL * 2);
  float* tmp16 = (float*)alloc((size_t)NROW * 1024 * 4);
  unsigned short* am = (unsigned short*)alloc((size_t)NROW * 1024 * 2);
  unsigned short* ctx = (unsigned short*)alloc((size_t)NROW * HKDIM * 2);
  unsigned short* hb = (unsigned short*)alloc((size_t)NROW * DMODEL * 2);
  unsigned short* f = (unsigned short*)alloc((size_t)NROW * MDIM * 2);
  unsigned short* dwb = (unsigned short*)alloc((size_t)VOCAB * DMODEL * 2);
  unsigned short* zb = (unsigned short*)alloc((size_t)NROW * DMODEL * 2);
  float* biasD = (float*)alloc((size_t)VOCAB * 4);
  unsigned short* logits = (unsigned short*)alloc((size_t)NROW * VOCAB * 2);
  const bool bfLogits = (off <= ws_size);  // deterministic: ws_size fixed per deploy
  (void)in_sizes; (void)n_in; (void)out_size;

  auto gemm = [&](const unsigned short* A, const unsigned short* B, float* Cf,
                  unsigned short* Cb, const float* bias, const unsigned short* resb,
                  int M, int N, int K, int lda, int ldb, int ldc, int batch,
                  long aB, long bB, long cB, float scale) {
    dim3 g(N / 128, M / 128, batch);
    k_gemm_bt<<<g, dim3(256), 0, stream>>>(A, B, Cf, Cb, bias, resb, M, N, K,
                                           lda, ldb, ldc, aB, bB, cB, scale);
  };
  auto gemm64 = [&](const unsigned short* A, const unsigned short* B, float* Cf,
                    unsigned short* Cb, const float* bias, const unsigned short* resb,
                    int M, int N, int K, int lda, int ldb, int ldc, int batch,
                    long aB, long bB, long cB, float scale) {
    dim3 g(N / 128, M / 64, batch);
    k_gemm64<<<g, dim3(256), 0, stream>>>(A, B, Cf, Cb, bias, resb, M, N, K,
                                          lda, ldb, ldc, aB, bB, cB, scale);
  };
  auto gemm8 = [&](const unsigned short* A, const unsigned short* B, float* Cf,
                   unsigned short* Cb, const float* bias, int M, int N, int K,
                   int lda, int ldb, int ldc) {
    k_gemm8<<<dim3(N / 256, M / 256, 1), dim3(512), 0, stream>>>(
        A, B, Cf, Cb, bias, M, N, K, lda, ldb, ldc);
  };
  auto cvt = [&](const float* in, unsigned short* o, long n) {
    int n4 = (int)(n / 4);
    int grid = (n4 + 255) / 256;
    if (grid > 2048) grid = 2048;
    k_cvt<<<dim3(grid), dim3(256), 0, stream>>>(in, o, n4);
  };

  k_embed<<<NROW, 256, 0, stream>>>(x, wemb, pemb, z);
  // layer 0 permute (A0=1024, A1=4)
  k_permute<<<NROW, 256, 0, stream>>>(z, xb, 1024, 4);

  for (int i = 0; i < NLAYER; ++i) {
    int A0 = (i % 2 == 0) ? 1024 : 4;

    // merged QKV: weights stacked [3072,1024] (768 blocks, 3/CU)
    cvt(wq + (long)i * HKDIM * DMODEL, wbuf, (long)HKDIM * DMODEL);
    cvt(wk + (long)i * HKDIM * DMODEL, wbuf + (size_t)1024 * DMODEL, (long)HKDIM * DMODEL);
    cvt(wv + (long)i * HKDIM * DMODEL, wbuf + (size_t)2048 * DMODEL, (long)HKDIM * DMODEL);
    gemm(xb, wbuf, nullptr, qkv, nullptr, nullptr, NROW, 3072, DMODEL,
         DMODEL, DMODEL, 3072, 1, 0, 0, 0, 1.0f);

    if (A0 == 1024) {  // even: full attention over S=1024, 4 batches
      gemm64(qkv, qkv + 1024, tmp16, nullptr, nullptr, nullptr, 1024, 1024, 1024,
             3072, 3072, 1024, 4, (long)1024 * 3072, (long)1024 * 3072, 1 << 20,
             1.0f / 32.0f);
      k_softmax<<<NROW, 256, 0, stream>>>(tmp16, am);
      k_transpose<<<dim3(32, 32, 4), dim3(32, 8), 0, stream>>>(
          qkv + 2048, vt, 1024, 1024, 3072, 1024, (long)1024 * 3072, 1 << 20);
      gemm64(am, vt, nullptr, ctx, nullptr, nullptr, 1024, 1024, 1024,
             1024, 1024, 1024, 4, 1 << 20, 1 << 20, 1 << 20, 1.0f);
    } else {  // odd: seq length 4
      k_attn4<<<1024, 256, 0, stream>>>(qkv, ctx);
    }

    // proj + bf16 residual  (N=1024: 64-row tiles -> 512 blocks, 2/CU)
    cvt(wc + (long)i * DMODEL * HKDIM, wbuf, (long)DMODEL * HKDIM);
    gemm64(ctx, wbuf, tmp16, nullptr, nullptr, xb, NROW, DMODEL, HKDIM,
           HKDIM, HKDIM, DMODEL, 1, 0, 0, 0, 1.0f);
    k_ln<<<NROW, 256, 0, stream>>>(tmp16, nullptr, ln1g + (long)i * DMODEL,
                                   ln1b + (long)i * DMODEL, nullptr, hb, 0, 0);
    cvt(w1 + (long)i * MDIM * DMODEL, wbuf, (long)MDIM * DMODEL);
    gemm(hb, wbuf, nullptr, f, b1 + (long)i * MDIM, nullptr, NROW, MDIM, DMODEL,
         DMODEL, DMODEL, MDIM, 1, 0, 0, 0, 1.0f);
    cvt(w2 + (long)i * DMODEL * MDIM, wbuf, (long)DMODEL * MDIM);
    gemm64(f, wbuf, tmp16, nullptr, b2 + (long)i * DMODEL, nullptr, NROW, DMODEL, MDIM,
           MDIM, MDIM, DMODEL, 1, 0, 0, 0, 1.0f);
    // LN2: fused permuted write into next layer's xb (i<5), linear zb for i=5
    if (i == NLAYER - 1) {
      k_ln<<<NROW, 256, 0, stream>>>(tmp16, hb, ln2g + (long)i * DMODEL,
                                     ln2b + (long)i * DMODEL, nullptr, zb, 0, 0);
    } else {
      int A0n = ((i + 1) % 2 == 0) ? 1024 : 4;
      int A1n = 4096 / A0n;
      k_ln<<<NROW, 256, 0, stream>>>(tmp16, hb, ln2g + (long)i * DMODEL,
                                     ln2b + (long)i * DMODEL, nullptr, xb, A0n, A1n);
    }
  }

  // decoder: double-buffered 256^2 2-phase (r9 best), bf16 logits when ws allows
  cvt(decw, dwb, (long)VOCAB * DMODEL);
  k_addbias<<<(VOCAB + 255) / 256, 256, 0, stream>>>(decb, obias, biasD, VOCAB);
  if (bfLogits) {
    gemm8(zb, dwb, nullptr, logits, biasD, NROW, VOCAB, DMODEL, DMODEL, DMODEL, VOCAB);
    k_logsoftmax_b<<<NROW, 320, 0, stream>>>(logits, out);
  } else {
    gemm8(zb, dwb, out, nullptr, biasD, NROW, VOCAB, DMODEL, DMODEL, DMODEL, VOCAB);
    k_logsoftmax<<<NROW, 320, 0, stream>>>(out);
  }
}

// Round 13
// 2193.006 us; speedup vs baseline: 1.9665x; 1.0018x over previous
//
#include <hip/hip_runtime.h>

// ---------------- types / constants ----------------
typedef short short8 __attribute__((ext_vector_type(8)));
typedef float f32x4 __attribute__((ext_vector_type(4)));

#define DMODEL 1024
#define HKDIM 1024
#define MDIM 4096
#define NROW 4096   // S*B = 1024*4
#define VOCAB 32000
#define NLAYER 6

#define GLOAD_LDS16(g, l)                                                      \
  __builtin_amdgcn_global_load_lds(                                            \
      (const __attribute__((address_space(1))) void*)(g),                      \
      (__attribute__((address_space(3))) void*)(l), 16, 0, 0)

__device__ __forceinline__ unsigned short f2bf(float f) {
  unsigned u = __float_as_uint(f);
  u += 0x7fffu + ((u >> 16) & 1u);
  return (unsigned short)(u >> 16);
}
__device__ __forceinline__ float bf2f(unsigned short h) {
  return __uint_as_float(((unsigned)h) << 16);
}
__device__ __forceinline__ float wave_sum(float v) {
  for (int o = 32; o; o >>= 1) v += __shfl_xor(v, o);
  return v;
}
__device__ __forceinline__ float wave_max(float v) {
  for (int o = 32; o; o >>= 1) v = fmaxf(v, __shfl_xor(v, o));
  return v;
}

// ---------------- embedding ----------------
__global__ __launch_bounds__(256) void k_embed(const int* __restrict__ x,
    const float* __restrict__ wemb, const float* __restrict__ pemb,
    float* __restrict__ z) {
  int r = blockIdx.x;           // r = s*4 + b
  int s = r >> 2;
  int tok = x[r];
  float4 a = ((const float4*)(wemb + (long)tok * DMODEL))[threadIdx.x];
  float4 p = ((const float4*)(pemb + (long)s * DMODEL))[threadIdx.x];
  float4 o;
  o.x = fmaxf(a.x * 32.0f + p.x, 0.0f);
  o.y = fmaxf(a.y * 32.0f + p.y, 0.0f);
  o.z = fmaxf(a.z * 32.0f + p.z, 0.0f);
  o.w = fmaxf(a.w * 32.0f + p.w, 0.0f);
  ((float4*)(z + (long)r * DMODEL))[threadIdx.x] = o;
}

// ---------------- permute rows: x = swapaxes(z,0,1), bf16 out only ----------------
__global__ __launch_bounds__(256) void k_permute(const float* __restrict__ zin,
    unsigned short* __restrict__ xb, int A0, int A1) {
  int r = blockIdx.x;
  int a1 = r / A0, a0 = r - a1 * A0;
  float4 v = ((const float4*)(zin + (long)(a0 * A1 + a1) * DMODEL))[threadIdx.x];
  ushort4 o = make_ushort4(f2bf(v.x), f2bf(v.y), f2bf(v.z), f2bf(v.w));
  ((ushort4*)(xb + (long)r * DMODEL))[threadIdx.x] = o;
}

// ---------------- f32 -> bf16 ----------------
__global__ __launch_bounds__(256) void k_cvt(const float* __restrict__ in,
    unsigned short* __restrict__ out, int n4) {
  int i = blockIdx.x * 256 + threadIdx.x;
  int stride = gridDim.x * 256;
  for (; i < n4; i += stride) {
    float4 v = ((const float4*)in)[i];
    ((ushort4*)out)[i] = make_ushort4(f2bf(v.x), f2bf(v.y), f2bf(v.z), f2bf(v.w));
  }
}

// ---------------- 128x128 bf16 GEMM (m97 structure + T2 + XCD swizzle) ------------
__global__ __launch_bounds__(256) void k_gemm_bt(
    const unsigned short* __restrict__ A, const unsigned short* __restrict__ B,
    float* __restrict__ Cf, unsigned short* __restrict__ Cb,
    const float* __restrict__ bias, const unsigned short* __restrict__ resb,
    int M, int N, int K, int lda, int ldb, int ldc,
    long aB, long bB, long cB, float scale) {
  __shared__ unsigned short As[128 * 64];
  __shared__ unsigned short Bs[128 * 64];
  const int tid = threadIdx.x;
  const int gx = gridDim.x, gy = gridDim.y;

  int nwg = gx * gy * gridDim.z;
  int flat = blockIdx.x + gx * (blockIdx.y + gy * blockIdx.z);
  int q8 = nwg >> 3, r8 = nwg & 7;
  int xcd = flat & 7, inner = flat >> 3;
  int wg = (xcd < r8 ? xcd * (q8 + 1) : r8 * (q8 + 1) + (xcd - r8) * q8) + inner;
  int ty = wg % gy;         // y-fastest: co-XCD consecutive blocks share B-panel
  int rest = wg / gy;
  int tx = rest % gx;
  int tz = rest / gx;

  const unsigned short* Ab = A + (long)tz * aB;
  const unsigned short* Bb = B + (long)tz * bB;
  const int row0 = ty * 128, col0 = tx * 128;
  const int lane = tid & 63, w = tid >> 6;
  const int wm = w >> 1, wn = w & 1;
  const int fr = lane & 15, fg = lane >> 4, fr7 = fr & 7;
  const int lrow = lane >> 3;
  const int lcol = ((lane & 7) ^ lrow) * 8;  // T2: pre-swizzled global source chunk

  const unsigned short* aSrc = Ab + (long)(row0 + w * 32 + lrow) * lda + lcol;
  const unsigned short* bSrc = Bb + (long)(col0 + w * 32 + lrow) * ldb + lcol;
  unsigned short* aDst = As + w * 32 * 64;  // linear wave-uniform LDS dest
  unsigned short* bDst = Bs + w * 32 * 64;

  f32x4 acc[4][4];
#pragma unroll
  for (int i = 0; i < 4; ++i)
#pragma unroll
    for (int j = 0; j < 4; ++j)
#pragma unroll
      for (int qq = 0; qq < 4; ++qq) acc[i][j][qq] = 0.0f;

  for (int k0 = 0; k0 < K; k0 += 64) {
#pragma unroll
    for (int i = 0; i < 4; ++i) {
      GLOAD_LDS16(aSrc + (long)i * 8 * lda + k0, aDst + i * 512);
      GLOAD_LDS16(bSrc + (long)i * 8 * ldb + k0, bDst + i * 512);
    }
    __syncthreads();
#pragma unroll
    for (int kk = 0; kk < 64; kk += 32) {
      short8 af[4], bfr[4];
#pragma unroll
      for (int i = 0; i < 4; ++i) {
        af[i] = *(const short8*)(As + (wm * 64 + i * 16 + fr) * 64 +
                                 (((kk >> 3) + fg) ^ fr7) * 8);
        bfr[i] = *(const short8*)(Bs + (wn * 64 + i * 16 + fr) * 64 +
                                  (((kk >> 3) + fg) ^ fr7) * 8);
      }
#pragma unroll
      for (int i = 0; i < 4; ++i)
#pragma unroll
        for (int j = 0; j < 4; ++j)
          acc[i][j] = __builtin_amdgcn_mfma_f32_16x16x32_bf16(af[i], bfr[j], acc[i][j], 0, 0, 0);
    }
    __syncthreads();
  }

#pragma unroll
  for (int i = 0; i < 4; ++i) {
#pragma unroll
    for (int qq = 0; qq < 4; ++qq) {
      int row = row0 + wm * 64 + i * 16 + fg * 4 + qq;
#pragma unroll
      for (int j = 0; j < 4; ++j) {
        int col = col0 + wn * 64 + j * 16 + fr;
        long off = cB * tz + (long)row * ldc + col;
        float v = acc[i][j][qq] * scale + (bias ? bias[col] : 0.0f);
        if (resb) v += bf2f(resb[off]);
        if (Cf) Cf[off] = v;
        if (Cb) Cb[off] = f2bf(v);
      }
    }
  }
}

// ---------------- 64x128 bf16 GEMM variant for N=1024 shapes ----------------
__global__ __launch_bounds__(256) void k_gemm64(
    const unsigned short* __restrict__ A, const unsigned short* __restrict__ B,
    float* __restrict__ Cf, unsigned short* __restrict__ Cb,
    const float* __restrict__ bias, const unsigned short* __restrict__ resb,
    int M, int N, int K, int lda, int ldb, int ldc,
    long aB, long bB, long cB, float scale) {
  __shared__ unsigned short As[64 * 64];
  __shared__ unsigned short Bs[128 * 64];
  const int tid = threadIdx.x;
  const int gx = gridDim.x, gy = gridDim.y;

  int nwg = gx * gy * gridDim.z;
  int flat = blockIdx.x + gx * (blockIdx.y + gy * blockIdx.z);
  int q8 = nwg >> 3, r8 = nwg & 7;
  int xcd = flat & 7, inner = flat >> 3;
  int wg = (xcd < r8 ? xcd * (q8 + 1) : r8 * (q8 + 1) + (xcd - r8) * q8) + inner;
  int ty = wg % gy;
  int rest = wg / gy;
  int tx = rest % gx;
  int tz = rest / gx;

  const unsigned short* Ab = A + (long)tz * aB;
  const unsigned short* Bb = B + (long)tz * bB;
  const int row0 = ty * 64, col0 = tx * 128;
  const int lane = tid & 63, w = tid >> 6;
  const int wm = w >> 1, wn = w & 1;
  const int fr = lane & 15, fg = lane >> 4, fr7 = fr & 7;
  const int lrow = lane >> 3;
  const int lcol = ((lane & 7) ^ lrow) * 8;

  const unsigned short* aSrc = Ab + (long)(row0 + w * 16 + lrow) * lda + lcol;
  const unsigned short* bSrc = Bb + (long)(col0 + w * 32 + lrow) * ldb + lcol;
  unsigned short* aDst = As + w * 16 * 64;
  unsigned short* bDst = Bs + w * 32 * 64;

  f32x4 acc[2][4];
#pragma unroll
  for (int i = 0; i < 2; ++i)
#pragma unroll
    for (int j = 0; j < 4; ++j)
#pragma unroll
      for (int qq = 0; qq < 4; ++qq) acc[i][j][qq] = 0.0f;

  for (int k0 = 0; k0 < K; k0 += 64) {
#pragma unroll
    for (int i = 0; i < 2; ++i)
      GLOAD_LDS16(aSrc + (long)i * 8 * lda + k0, aDst + i * 512);
#pragma unroll
    for (int i = 0; i < 4; ++i)
      GLOAD_LDS16(bSrc + (long)i * 8 * ldb + k0, bDst + i * 512);
    __syncthreads();
#pragma unroll
    for (int kk = 0; kk < 64; kk += 32) {
      short8 af[2], bfr[4];
#pragma unroll
      for (int i = 0; i < 2; ++i)
        af[i] = *(const short8*)(As + (wm * 32 + i * 16 + fr) * 64 +
                                 (((kk >> 3) + fg) ^ fr7) * 8);
#pragma unroll
      for (int j = 0; j < 4; ++j)
        bfr[j] = *(const short8*)(Bs + (wn * 64 + j * 16 + fr) * 64 +
                                  (((kk >> 3) + fg) ^ fr7) * 8);
#pragma unroll
      for (int i = 0; i < 2; ++i)
#pragma unroll
        for (int j = 0; j < 4; ++j)
          acc[i][j] = __builtin_amdgcn_mfma_f32_16x16x32_bf16(af[i], bfr[j], acc[i][j], 0, 0, 0);
    }
    __syncthreads();
  }

#pragma unroll
  for (int i = 0; i < 2; ++i) {
#pragma unroll
    for (int qq = 0; qq < 4; ++qq) {
      int row = row0 + wm * 32 + i * 16 + fg * 4 + qq;
#pragma unroll
      for (int j = 0; j < 4; ++j) {
        int col = col0 + wn * 64 + j * 16 + fr;
        long off = cB * tz + (long)row * ldc + col;
        float v = acc[i][j][qq] * scale + (bias ? bias[col] : 0.0f);
        if (resb) v += bf2f(resb[off]);
        if (Cf) Cf[off] = v;
        if (Cb) Cb[off] = f2bf(v);
      }
    }
  }
}

// ---------------- 256x256 8-phase bf16 GEMM (m201 template, no sched_barriers) -----
// 512 thr = 8 waves (2M x 4N), per-wave C 128x64 = acc[8][4]. BK=64, 128KB LDS dbuf.
// Half-tiles (wave-aligned): A-lo = rows {0-63,128-191}, A-hi = {64-127,192-255};
// B01 = N-rows {w*64..w*64+31}, B23 = complement. Phase reads 12/4/8/0; B held in
// regs. Stages: p0->A-hi(t+1), p1->A-lo(t+2), p2->B01(t+2), p3->B23(t+2); each
// target region's last LDS read completed >=1 phase earlier. One vmcnt(6) gate per
// K-tile (3 half-tiles in flight). NO sched_barrier (m141 lesson). K mult 64, NT>=2.
__global__ __launch_bounds__(512, 2) void k_gemm8p(
    const unsigned short* __restrict__ A, const unsigned short* __restrict__ B,
    float* __restrict__ Cf, unsigned short* __restrict__ Cb,
    const float* __restrict__ bias, int M, int N, int K,
    int lda, int ldb, int ldc) {
  __shared__ unsigned short As[2][256 * 64];
  __shared__ unsigned short Bs[2][256 * 64];
  const int tid = threadIdx.x;
  const int gx = gridDim.x, gy = gridDim.y;
  int nwg = gx * gy;
  int flat = blockIdx.x + gx * blockIdx.y;
  int q8 = nwg >> 3, r8 = nwg & 7;
  int xcd = flat & 7, inner = flat >> 3;
  int wg = (xcd < r8 ? xcd * (q8 + 1) : r8 * (q8 + 1) + (xcd - r8) * q8) + inner;
  int ty = wg % gy, tx = wg / gy;

  const int row0 = ty * 256, col0 = tx * 256;
  const int lane = tid & 63, w = tid >> 6;
  const int wm = w >> 2, wn = w & 3;
  const int fr = lane & 15, fg = lane >> 4, fr7 = fr & 7;
  const int srow = lane >> 3;
  const int scol = ((lane & 7) ^ srow) * 8;     // T2 pre-swizzled source chunk
  const int bq = (w >> 1) * 64 + (w & 1) * 16;  // B-quadrant row base per wave

  const unsigned short* pA = A + (size_t)(row0 + srow) * lda + scol;
  const unsigned short* pB = B + (size_t)(col0 + srow) * ldb + scol;

  auto stg = [&](const unsigned short* base, int ld, int tk,
                 unsigned short* lds, int r0) {
    GLOAD_LDS16(base + (size_t)r0 * ld + (size_t)tk * 64, lds + r0 * 64);
  };
#define STALO(bf, tk) { stg(pA, lda, tk, &As[bf][0], w * 8); stg(pA, lda, tk, &As[bf][0], 128 + w * 8); }
#define STAHI(bf, tk) { stg(pA, lda, tk, &As[bf][0], 64 + w * 8); stg(pA, lda, tk, &As[bf][0], 192 + w * 8); }
#define STB01(bf, tk) { stg(pB, ldb, tk, &Bs[bf][0], bq); stg(pB, ldb, tk, &Bs[bf][0], bq + 8); }
#define STB23(bf, tk) { stg(pB, ldb, tk, &Bs[bf][0], bq + 32); stg(pB, ldb, tk, &Bs[bf][0], bq + 40); }

  auto rdA = [&](const unsigned short* lds, int i, int kq) -> short8 {
    return *(const short8*)(lds + (wm * 128 + i * 16 + fr) * 64 +
                            (((kq << 2) + fg) ^ fr7) * 8);
  };
  auto rdB = [&](const unsigned short* lds, int j, int kq) -> short8 {
    return *(const short8*)(lds + (wn * 64 + j * 16 + fr) * 64 +
                            (((kq << 2) + fg) ^ fr7) * 8);
  };

  f32x4 acc[8][4];
#pragma unroll
  for (int i = 0; i < 8; ++i)
#pragma unroll
    for (int j = 0; j < 4; ++j)
#pragma unroll
      for (int qq = 0; qq < 4; ++qq) acc[i][j][qq] = 0.0f;

  short8 a8[8], b01[4], b23[4];

#define MFMA16(I0, BR, J0)                                                   \
  {                                                                          \
    __builtin_amdgcn_s_setprio(1);                                           \
    _Pragma("unroll") for (int kq = 0; kq < 2; ++kq)                         \
      _Pragma("unroll") for (int i = 0; i < 4; ++i)                          \
        _Pragma("unroll") for (int j = 0; j < 2; ++j)                        \
          acc[(I0) + i][(J0) + j] = __builtin_amdgcn_mfma_f32_16x16x32_bf16( \
              a8[i * 2 + kq], BR[j * 2 + kq], acc[(I0) + i][(J0) + j], 0, 0, 0); \
    __builtin_amdgcn_s_setprio(0);                                           \
  }

  const int NT = K >> 6;

  // prologue: tile0 (4 halves) + tile1's {A-lo, B01, B23}; confirm tile0
  STALO(0, 0) STAHI(0, 0) STB01(0, 0) STB23(0, 0)
  STALO(1, 1) STB01(1, 1) STB23(1, 1)
  asm volatile("s_waitcnt vmcnt(6)" ::: "memory");
  __builtin_amdgcn_s_barrier();

  for (int t = 0; t < NT; ++t) {
    const int b = t & 1;
    const unsigned short* aL = &As[b][0];
    const unsigned short* bL = &Bs[b][0];
    const int tp1 = (t + 1 < NT) ? t + 1 : NT - 1;
    const int tp2 = (t + 2 < NT) ? t + 2 : NT - 1;
    // ---- p0: (i0-3 x j0-1); 12 ds_reads; stage A-hi(t+1) -> other buf ----
#pragma unroll
    for (int i = 0; i < 4; ++i) {
      a8[i * 2] = rdA(aL, i, 0);
      a8[i * 2 + 1] = rdA(aL, i, 1);
    }
#pragma unroll
    for (int j = 0; j < 2; ++j) {
      b01[j * 2] = rdB(bL, j, 0);
      b01[j * 2 + 1] = rdB(bL, j, 1);
    }
    STAHI(1 - b, tp1)
    asm volatile("s_waitcnt lgkmcnt(8)" ::: "memory");
    __builtin_amdgcn_s_barrier();
    asm volatile("s_waitcnt lgkmcnt(0)" ::: "memory");
    MFMA16(0, b01, 0)
    __builtin_amdgcn_s_barrier();
    // ---- p1: (i0-3 x j2-3); 4 ds_reads; stage A-lo(t+2) ----
#pragma unroll
    for (int j = 0; j < 2; ++j) {
      b23[j * 2] = rdB(bL, j + 2, 0);
      b23[j * 2 + 1] = rdB(bL, j + 2, 1);
    }
    STALO(b, tp2)
    __builtin_amdgcn_s_barrier();
    asm volatile("s_waitcnt lgkmcnt(0)" ::: "memory");
    MFMA16(0, b23, 2)
    __builtin_amdgcn_s_barrier();
    // ---- p2: (i4-7 x j2-3); 8 ds_reads; stage B01(t+2) ----
#pragma unroll
    for (int i = 0; i < 4; ++i) {
      a8[i * 2] = rdA(aL, i + 4, 0);
      a8[i * 2 + 1] = rdA(aL, i + 4, 1);
    }
    STB01(b, tp2)
    __builtin_amdgcn_s_barrier();
    asm volatile("s_waitcnt lgkmcnt(0)" ::: "memory");
    MFMA16(4, b23, 2)
    __builtin_amdgcn_s_barrier();
    // ---- p3: (i4-7 x j0-1); regs only; stage B23(t+2); K-tile gate vmcnt(6) ----
    STB23(b, tp2)
    __builtin_amdgcn_s_barrier();
    MFMA16(4, b01, 0)
    asm volatile("s_waitcnt vmcnt(6)" ::: "memory");
    __builtin_amdgcn_s_barrier();
  }
  asm volatile("s_waitcnt vmcnt(0)" ::: "memory");

  // epilogue: j innermost for write-combining
#pragma unroll
  for (int i = 0; i < 8; ++i) {
#pragma unroll
    for (int qq = 0; qq < 4; ++qq) {
      int row = row0 + wm * 128 + i * 16 + fg * 4 + qq;
#pragma unroll
      for (int j = 0; j < 4; ++j) {
        int col = col0 + wn * 64 + j * 16 + fr;
        size_t off = (size_t)row * ldc + col;
        float v = acc[i][j][qq] + (bias ? bias[col] : 0.0f);
        if (Cf) Cf[off] = v;
        if (Cb) Cb[off] = f2bf(v);
      }
    }
  }
#undef STALO
#undef STAHI
#undef STB01
#undef STB23
#undef MFMA16
}

// ---------------- layernorm (optional fused permuted bf16 write) ----------------
__global__ __launch_bounds__(256) void k_ln(const float* __restrict__ X,
    const unsigned short* __restrict__ X2b, const float* __restrict__ g,
    const float* __restrict__ b, float* __restrict__ outF,
    unsigned short* __restrict__ outB, int pA0, int pA1) {
  __shared__ float sm[4];
  int row = blockIdx.x, t = threadIdx.x;
  float4 v = ((const float4*)(X + (long)row * DMODEL))[t];
  if (X2b) {
    ushort4 u = ((const ushort4*)(X2b + (long)row * DMODEL))[t];
    v.x += bf2f(u.x); v.y += bf2f(u.y); v.z += bf2f(u.z); v.w += bf2f(u.w);
  }
  float s = wave_sum(v.x + v.y + v.z + v.w);
  if ((t & 63) == 0) sm[t >> 6] = s;
  __syncthreads();
  float mean = (sm[0] + sm[1] + sm[2] + sm[3]) * (1.0f / DMODEL);
  __syncthreads();
  float4 c;
  c.x = v.x - mean; c.y = v.y - mean; c.z = v.z - mean; c.w = v.w - mean;
  float ss = wave_sum(c.x * c.x + c.y * c.y + c.z * c.z + c.w * c.w);
  if ((t & 63) == 0) sm[t >> 6] = ss;
  __syncthreads();
  float var = (sm[0] + sm[1] + sm[2] + sm[3]) * (1.0f / DMODEL);
  float rs = rsqrtf(var + 1e-5f);
  float4 gv = ((const float4*)g)[t], bv = ((const float4*)b)[t];
  float4 o;
  o.x = c.x * rs * gv.x + bv.x;
  o.y = c.y * rs * gv.y + bv.y;
  o.z = c.z * rs * gv.z + bv.z;
  o.w = c.w * rs * gv.w + bv.w;
  if (outF) ((float4*)(outF + (long)row * DMODEL))[t] = o;
  if (outB) {
    int d = row;
    if (pA1 > 0) d = (row % pA1) * pA0 + row / pA1;
    ((ushort4*)(outB + (long)d * DMODEL))[t] =
        make_ushort4(f2bf(o.x), f2bf(o.y), f2bf(o.z), f2bf(o.w));
  }
}

// ---------------- softmax (rows of 1024) ----------------
__global__ __launch_bounds__(256) void k_softmax(const float* __restrict__ S,
    unsigned short* __restrict__ A) {
  __shared__ float sm[4];
  int row = blockIdx.x, t = threadIdx.x;
  float4 v = ((const float4*)(S + (long)row * 1024))[t];
  float m = wave_max(fmaxf(fmaxf(v.x, v.y), fmaxf(v.z, v.w)));
  if ((t & 63) == 0) sm[t >> 6] = m;
  __syncthreads();
  m = fmaxf(fmaxf(sm[0], sm[1]), fmaxf(sm[2], sm[3]));
  __syncthreads();
  float4 e;
  e.x = __expf(v.x - m); e.y = __expf(v.y - m);
  e.z = __expf(v.z - m); e.w = __expf(v.w - m);
  float s = wave_sum(e.x + e.y + e.z + e.w);
  if ((t & 63) == 0) sm[t >> 6] = s;
  __syncthreads();
  float inv = 1.0f / (sm[0] + sm[1] + sm[2] + sm[3]);
  ((ushort4*)(A + (long)row * 1024))[t] =
      make_ushort4(f2bf(e.x * inv), f2bf(e.y * inv), f2bf(e.z * inv), f2bf(e.w * inv));
}

// ---------------- odd layers: seq-4 attention (QKV packed, stride 3072) -------------
__global__ __launch_bounds__(256) void k_attn4(const unsigned short* __restrict__ QKV,
    unsigned short* __restrict__ C) {
  int bp = blockIdx.x;
  int w = threadIdx.x >> 6, lane = threadIdx.x & 63;
  const unsigned short* q = QKV + (long)(bp * 4 + w) * 3072;
  float s[4];
  for (int j = 0; j < 4; ++j) {
    const unsigned short* kj = QKV + (long)(bp * 4 + j) * 3072 + 1024;
    float a = 0.0f;
    for (int e = lane; e < 1024; e += 64) a += bf2f(q[e]) * bf2f(kj[e]);
    s[j] = wave_sum(a) * (1.0f / 32.0f);
  }
  float m = fmaxf(fmaxf(s[0], s[1]), fmaxf(s[2], s[3]));
  float e0 = __expf(s[0] - m), e1 = __expf(s[1] - m);
  float e2 = __expf(s[2] - m), e3 = __expf(s[3] - m);
  float inv = 1.0f / (e0 + e1 + e2 + e3);
  float a0 = e0 * inv, a1 = e1 * inv, a2 = e2 * inv, a3 = e3 * inv;
  unsigned short* c = C + (long)(bp * 4 + w) * 1024;
  const unsigned short* v0 = QKV + (long)(bp * 4 + 0) * 3072 + 2048;
  const unsigned short* v1 = QKV + (long)(bp * 4 + 1) * 3072 + 2048;
  const unsigned short* v2 = QKV + (long)(bp * 4 + 2) * 3072 + 2048;
  const unsigned short* v3 = QKV + (long)(bp * 4 + 3) * 3072 + 2048;
  for (int e = lane; e < 1024; e += 64) {
    float v = a0 * bf2f(v0[e]) + a1 * bf2f(v1[e]) + a2 * bf2f(v2[e]) + a3 * bf2f(v3[e]);
    c[e] = f2bf(v);
  }
}

// ---------------- bf16 batched transpose with strides ----------------
__global__ __launch_bounds__(256) void k_transpose(const unsigned short* __restrict__ in,
    unsigned short* __restrict__ out, int rows, int cols, int ld_in, int ld_out,
    long inB, long outB) {
  __shared__ unsigned short tile[32][33];
  long ibase = (long)blockIdx.z * inB;
  long obase = (long)blockIdx.z * outB;
  int r0 = blockIdx.y * 32, c0 = blockIdx.x * 32;
  int tx = threadIdx.x, ty = threadIdx.y;
  for (int i = ty; i < 32; i += 8)
    tile[i][tx] = in[ibase + (long)(r0 + i) * ld_in + c0 + tx];
  __syncthreads();
  for (int i = ty; i < 32; i += 8)
    out[obase + (long)(c0 + i) * ld_out + r0 + tx] = tile[tx][i];
}

// ---------------- log-softmax: bf16 logits in, f32 out ----------------
__global__ __launch_bounds__(320) void k_logsoftmax_b(
    const unsigned short* __restrict__ Lb, float* __restrict__ out) {
  __shared__ float sm[5];
  int row = blockIdx.x, t = threadIdx.x;
  const unsigned long long* xr =
      (const unsigned long long*)(Lb + (long)row * VOCAB);
  float* yr = out + (long)row * VOCAB;
  float4 v[25];
  float m = -1e30f;
#pragma unroll
  for (int i = 0; i < 25; ++i) {
    unsigned long long u = __builtin_nontemporal_load(&xr[t + i * 320]);
    v[i].x = bf2f((unsigned short)(u & 0xffffu));
    v[i].y = bf2f((unsigned short)((u >> 16) & 0xffffu));
    v[i].z = bf2f((unsigned short)((u >> 32) & 0xffffu));
    v[i].w = bf2f((unsigned short)(u >> 48));
    m = fmaxf(m, fmaxf(fmaxf(v[i].x, v[i].y), fmaxf(v[i].z, v[i].w)));
  }
  m = wave_max(m);
  if ((t & 63) == 0) sm[t >> 6] = m;
  __syncthreads();
  m = fmaxf(fmaxf(fmaxf(sm[0], sm[1]), fmaxf(sm[2], sm[3])), sm[4]);
  __syncthreads();
  float s = 0.0f;
#pragma unroll
  for (int i = 0; i < 25; ++i)
    s += __expf(v[i].x - m) + __expf(v[i].y - m) + __expf(v[i].z - m) + __expf(v[i].w - m);
  s = wave_sum(s);
  if ((t & 63) == 0) sm[t >> 6] = s;
  __syncthreads();
  float l = m + __logf(sm[0] + sm[1] + sm[2] + sm[3] + sm[4]);
#pragma unroll
  for (int i = 0; i < 25; ++i) {
    float4 o = v[i];
    o.x -= l; o.y -= l; o.z -= l; o.w -= l;
    ((float4*)yr)[t + i * 320] = o;
  }
}

// ---------------- log-softmax fallback: in-place f32 ----------------
__global__ __launch_bounds__(320) void k_logsoftmax(float* __restrict__ L) {
  __shared__ float sm[5];
  int row = blockIdx.x, t = threadIdx.x;
  float* x = L + (long)row * VOCAB;
  float4 v[25];
  float m = -1e30f;
#pragma unroll
  for (int i = 0; i < 25; ++i) {
    v[i] = ((const float4*)x)[t + i * 320];
    m = fmaxf(m, fmaxf(fmaxf(v[i].x, v[i].y), fmaxf(v[i].z, v[i].w)));
  }
  m = wave_max(m);
  if ((t & 63) == 0) sm[t >> 6] = m;
  __syncthreads();
  m = fmaxf(fmaxf(fmaxf(sm[0], sm[1]), fmaxf(sm[2], sm[3])), sm[4]);
  __syncthreads();
  float s = 0.0f;
#pragma unroll
  for (int i = 0; i < 25; ++i)
    s += __expf(v[i].x - m) + __expf(v[i].y - m) + __expf(v[i].z - m) + __expf(v[i].w - m);
  s = wave_sum(s);
  if ((t & 63) == 0) sm[t >> 6] = s;
  __syncthreads();
  float l = m + __logf(sm[0] + sm[1] + sm[2] + sm[3] + sm[4]);
#pragma unroll
  for (int i = 0; i < 25; ++i) {
    float4 o = v[i];
    o.x -= l; o.y -= l; o.z -= l; o.w -= l;
    ((float4*)x)[t + i * 320] = o;
  }
}

__global__ __launch_bounds__(256) void k_addbias(const float* __restrict__ a,
    const float* __restrict__ b, float* __restrict__ o, int n) {
  int i = blockIdx.x * 256 + threadIdx.x;
  if (i < n) o[i] = a[i] + b[i];
}

// ---------------- host ----------------
extern "C" void kernel_launch(void* const* d_in, const int* in_sizes, int n_in,
                              void* d_out, int out_size, void* d_ws, size_t ws_size,
                              hipStream_t stream) {
  const int* x = (const int*)d_in[0];
  const float* wemb = (const float*)d_in[1];
  const float* pemb = (const float*)d_in[2];
  const float* wq = (const float*)d_in[3];
  const float* wk = (const float*)d_in[4];
  const float* wv = (const float*)d_in[5];
  const float* wc = (const float*)d_in[6];
  const float* ln1g = (const float*)d_in[7];
  const float* ln1b = (const float*)d_in[8];
  const float* w1 = (const float*)d_in[9];
  const float* b1 = (const float*)d_in[10];
  const float* w2 = (const float*)d_in[11];
  const float* b2 = (const float*)d_in[12];
  const float* ln2g = (const float*)d_in[13];
  const float* ln2b = (const float*)d_in[14];
  const float* decw = (const float*)d_in[15];
  const float* decb = (const float*)d_in[16];
  const float* obias = (const float*)d_in[17];
  float* out = (float*)d_out;

  char* ws = (char*)d_ws;
  size_t off = 0;
  auto alloc = [&](size_t bytes) -> char* {
    char* p = ws + off;
    off += (bytes + 255) & ~(size_t)255;
    return p;
  };
  float* z = (float*)alloc((size_t)NROW * DMODEL * 4);
  unsigned short* xb = (unsigned short*)alloc((size_t)NROW * DMODEL * 2);
  unsigned short* qkv = (unsigned short*)alloc((size_t)NROW * 3072 * 2);
  unsigned short* vt = (unsigned short*)alloc((size_t)NROW * HKDIM * 2);
  unsigned short* wbuf = (unsigned short*)alloc((size_t)MDIM * DMODEL * 2);
  float* tmp16 = (float*)alloc((size_t)NROW * 1024 * 4);
  unsigned short* am = (unsigned short*)alloc((size_t)NROW * 1024 * 2);
  unsigned short* ctx = (unsigned short*)alloc((size_t)NROW * HKDIM * 2);
  unsigned short* hb = (unsigned short*)alloc((size_t)NROW * DMODEL * 2);
  unsigned short* f = (unsigned short*)alloc((size_t)NROW * MDIM * 2);
  unsigned short* dwb = (unsigned short*)alloc((size_t)VOCAB * DMODEL * 2);
  unsigned short* zb = (unsigned short*)alloc((size_t)NROW * DMODEL * 2);
  float* biasD = (float*)alloc((size_t)VOCAB * 4);
  unsigned short* logits = (unsigned short*)alloc((size_t)NROW * VOCAB * 2);
  const bool bfLogits = (off <= ws_size);  // deterministic: ws_size fixed per deploy
  (void)in_sizes; (void)n_in; (void)out_size;

  auto gemm = [&](const unsigned short* A, const unsigned short* B, float* Cf,
                  unsigned short* Cb, const float* bias, const unsigned short* resb,
                  int M, int N, int K, int lda, int ldb, int ldc, int batch,
                  long aB, long bB, long cB, float scale) {
    dim3 g(N / 128, M / 128, batch);
    k_gemm_bt<<<g, dim3(256), 0, stream>>>(A, B, Cf, Cb, bias, resb, M, N, K,
                                           lda, ldb, ldc, aB, bB, cB, scale);
  };
  auto gemm64 = [&](const unsigned short* A, const unsigned short* B, float* Cf,
                    unsigned short* Cb, const float* bias, const unsigned short* resb,
                    int M, int N, int K, int lda, int ldb, int ldc, int batch,
                    long aB, long bB, long cB, float scale) {
    dim3 g(N / 128, M / 64, batch);
    k_gemm64<<<g, dim3(256), 0, stream>>>(A, B, Cf, Cb, bias, resb, M, N, K,
                                          lda, ldb, ldc, aB, bB, cB, scale);
  };
  auto gemm8p = [&](const unsigned short* A, const unsigned short* B, float* Cf,
                    unsigned short* Cb, const float* bias, int M, int N, int K,
                    int lda, int ldb, int ldc) {
    k_gemm8p<<<dim3(N / 256, M / 256, 1), dim3(512), 0, stream>>>(
        A, B, Cf, Cb, bias, M, N, K, lda, ldb, ldc);
  };
  auto cvt = [&](const float* in, unsigned short* o, long n) {
    int n4 = (int)(n / 4);
    int grid = (n4 + 255) / 256;
    if (grid > 2048) grid = 2048;
    k_cvt<<<dim3(grid), dim3(256), 0, stream>>>(in, o, n4);
  };

  k_embed<<<NROW, 256, 0, stream>>>(x, wemb, pemb, z);
  // layer 0 permute (A0=1024, A1=4)
  k_permute<<<NROW, 256, 0, stream>>>(z, xb, 1024, 4);

  for (int i = 0; i < NLAYER; ++i) {
    int A0 = (i % 2 == 0) ? 1024 : 4;

    // merged QKV: weights stacked [3072,1024] (768 blocks, 3/CU)
    cvt(wq + (long)i * HKDIM * DMODEL, wbuf, (long)HKDIM * DMODEL);
    cvt(wk + (long)i * HKDIM * DMODEL, wbuf + (size_t)1024 * DMODEL, (long)HKDIM * DMODEL);
    cvt(wv + (long)i * HKDIM * DMODEL, wbuf + (size_t)2048 * DMODEL, (long)HKDIM * DMODEL);
    gemm(xb, wbuf, nullptr, qkv, nullptr, nullptr, NROW, 3072, DMODEL,
         DMODEL, DMODEL, 3072, 1, 0, 0, 0, 1.0f);

    if (A0 == 1024) {  // even: full attention over S=1024, 4 batches
      gemm64(qkv, qkv + 1024, tmp16, nullptr, nullptr, nullptr, 1024, 1024, 1024,
             3072, 3072, 1024, 4, (long)1024 * 3072, (long)1024 * 3072, 1 << 20,
             1.0f / 32.0f);
      k_softmax<<<NROW, 256, 0, stream>>>(tmp16, am);
      k_transpose<<<dim3(32, 32, 4), dim3(32, 8), 0, stream>>>(
          qkv + 2048, vt, 1024, 1024, 3072, 1024, (long)1024 * 3072, 1 << 20);
      gemm64(am, vt, nullptr, ctx, nullptr, nullptr, 1024, 1024, 1024,
             1024, 1024, 1024, 4, 1 << 20, 1 << 20, 1 << 20, 1.0f);
    } else {  // odd: seq length 4
      k_attn4<<<1024, 256, 0, stream>>>(qkv, ctx);
    }

    // proj + bf16 residual  (N=1024: 64-row tiles -> 512 blocks, 2/CU)
    cvt(wc + (long)i * DMODEL * HKDIM, wbuf, (long)DMODEL * HKDIM);
    gemm64(ctx, wbuf, tmp16, nullptr, nullptr, xb, NROW, DMODEL, HKDIM,
           HKDIM, HKDIM, DMODEL, 1, 0, 0, 0, 1.0f);
    k_ln<<<NROW, 256, 0, stream>>>(tmp16, nullptr, ln1g + (long)i * DMODEL,
                                   ln1b + (long)i * DMODEL, nullptr, hb, 0, 0);
    // FFN1 on the 8-phase 256^2 kernel (256 blocks, 1/CU by design)
    cvt(w1 + (long)i * MDIM * DMODEL, wbuf, (long)MDIM * DMODEL);
    gemm8p(hb, wbuf, nullptr, f, b1 + (long)i * MDIM, NROW, MDIM, DMODEL,
           DMODEL, DMODEL, MDIM);
    cvt(w2 + (long)i * DMODEL * MDIM, wbuf, (long)DMODEL * MDIM);
    gemm64(f, wbuf, tmp16, nullptr, b2 + (long)i * DMODEL, nullptr, NROW, DMODEL, MDIM,
           MDIM, MDIM, DMODEL, 1, 0, 0, 0, 1.0f);
    // LN2: fused permuted write into next layer's xb (i<5), linear zb for i=5
    if (i == NLAYER - 1) {
      k_ln<<<NROW, 256, 0, stream>>>(tmp16, hb, ln2g + (long)i * DMODEL,
                                     ln2b + (long)i * DMODEL, nullptr, zb, 0, 0);
    } else {
      int A0n = ((i + 1) % 2 == 0) ? 1024 : 4;
      int A1n = 4096 / A0n;
      k_ln<<<NROW, 256, 0, stream>>>(tmp16, hb, ln2g + (long)i * DMODEL,
                                     ln2b + (long)i * DMODEL, nullptr, xb, A0n, A1n);
    }
  }

  // decoder: 8-phase 256^2 (m201 template), bf16 logits when ws allows
  cvt(decw, dwb, (long)VOCAB * DMODEL);
  k_addbias<<<(VOCAB + 255) / 256, 256, 0, stream>>>(decb, obias, biasD, VOCAB);
  if (bfLogits) {
    gemm8p(zb, dwb, nullptr, logits, biasD, NROW, VOCAB, DMODEL, DMODEL, DMODEL, VOCAB);
    k_logsoftmax_b<<<NROW, 320, 0, stream>>>(logits, out);
  } else {
    gemm8p(zb, dwb, out, nullptr, biasD, NROW, VOCAB, DMODEL, DMODEL, DMODEL, VOCAB);
    k_logsoftmax<<<NROW, 320, 0, stream>>>(out);
  }
}

// Round 14
// 2089.708 us; speedup vs baseline: 2.0637x; 1.0494x over previous
//
#include <hip/hip_runtime.h>

// ---------------- types / constants ----------------
typedef short short8 __attribute__((ext_vector_type(8)));
typedef float f32x4 __attribute__((ext_vector_type(4)));

#define DMODEL 1024
#define HKDIM 1024
#define MDIM 4096
#define NROW 4096   // S*B = 1024*4
#define VOCAB 32000
#define NLAYER 6

#define GLOAD_LDS16(g, l)                                                      \
  __builtin_amdgcn_global_load_lds(                                            \
      (const __attribute__((address_space(1))) void*)(g),                      \
      (__attribute__((address_space(3))) void*)(l), 16, 0, 0)

__device__ __forceinline__ unsigned short f2bf(float f) {
  unsigned u = __float_as_uint(f);
  u += 0x7fffu + ((u >> 16) & 1u);
  return (unsigned short)(u >> 16);
}
__device__ __forceinline__ float bf2f(unsigned short h) {
  return __uint_as_float(((unsigned)h) << 16);
}
__device__ __forceinline__ float wave_sum(float v) {
  for (int o = 32; o; o >>= 1) v += __shfl_xor(v, o);
  return v;
}
__device__ __forceinline__ float wave_max(float v) {
  for (int o = 32; o; o >>= 1) v = fmaxf(v, __shfl_xor(v, o));
  return v;
}

// ---------------- embedding ----------------
__global__ __launch_bounds__(256) void k_embed(const int* __restrict__ x,
    const float* __restrict__ wemb, const float* __restrict__ pemb,
    float* __restrict__ z) {
  int r = blockIdx.x;           // r = s*4 + b
  int s = r >> 2;
  int tok = x[r];
  float4 a = ((const float4*)(wemb + (long)tok * DMODEL))[threadIdx.x];
  float4 p = ((const float4*)(pemb + (long)s * DMODEL))[threadIdx.x];
  float4 o;
  o.x = fmaxf(a.x * 32.0f + p.x, 0.0f);
  o.y = fmaxf(a.y * 32.0f + p.y, 0.0f);
  o.z = fmaxf(a.z * 32.0f + p.z, 0.0f);
  o.w = fmaxf(a.w * 32.0f + p.w, 0.0f);
  ((float4*)(z + (long)r * DMODEL))[threadIdx.x] = o;
}

// ---------------- permute rows: x = swapaxes(z,0,1), bf16 out only ----------------
__global__ __launch_bounds__(256) void k_permute(const float* __restrict__ zin,
    unsigned short* __restrict__ xb, int A0, int A1) {
  int r = blockIdx.x;
  int a1 = r / A0, a0 = r - a1 * A0;
  float4 v = ((const float4*)(zin + (long)(a0 * A1 + a1) * DMODEL))[threadIdx.x];
  ushort4 o = make_ushort4(f2bf(v.x), f2bf(v.y), f2bf(v.z), f2bf(v.w));
  ((ushort4*)(xb + (long)r * DMODEL))[threadIdx.x] = o;
}

// ---------------- f32 -> bf16 ----------------
__global__ __launch_bounds__(256) void k_cvt(const float* __restrict__ in,
    unsigned short* __restrict__ out, int n4) {
  int i = blockIdx.x * 256 + threadIdx.x;
  int stride = gridDim.x * 256;
  for (; i < n4; i += stride) {
    float4 v = ((const float4*)in)[i];
    ((ushort4*)out)[i] = make_ushort4(f2bf(v.x), f2bf(v.y), f2bf(v.z), f2bf(v.w));
  }
}

// ---------------- 128x128 bf16 GEMM (m97 structure + T2 + XCD swizzle) ------------
__global__ __launch_bounds__(256) void k_gemm_bt(
    const unsigned short* __restrict__ A, const unsigned short* __restrict__ B,
    float* __restrict__ Cf, unsigned short* __restrict__ Cb,
    const float* __restrict__ bias, const unsigned short* __restrict__ resb,
    int M, int N, int K, int lda, int ldb, int ldc,
    long aB, long bB, long cB, float scale) {
  __shared__ unsigned short As[128 * 64];
  __shared__ unsigned short Bs[128 * 64];
  const int tid = threadIdx.x;
  const int gx = gridDim.x, gy = gridDim.y;

  int nwg = gx * gy * gridDim.z;
  int flat = blockIdx.x + gx * (blockIdx.y + gy * blockIdx.z);
  int q8 = nwg >> 3, r8 = nwg & 7;
  int xcd = flat & 7, inner = flat >> 3;
  int wg = (xcd < r8 ? xcd * (q8 + 1) : r8 * (q8 + 1) + (xcd - r8) * q8) + inner;
  int ty = wg % gy;         // y-fastest: co-XCD consecutive blocks share B-panel
  int rest = wg / gy;
  int tx = rest % gx;
  int tz = rest / gx;

  const unsigned short* Ab = A + (long)tz * aB;
  const unsigned short* Bb = B + (long)tz * bB;
  const int row0 = ty * 128, col0 = tx * 128;
  const int lane = tid & 63, w = tid >> 6;
  const int wm = w >> 1, wn = w & 1;
  const int fr = lane & 15, fg = lane >> 4, fr7 = fr & 7;
  const int lrow = lane >> 3;
  const int lcol = ((lane & 7) ^ lrow) * 8;  // T2: pre-swizzled global source chunk

  const unsigned short* aSrc = Ab + (long)(row0 + w * 32 + lrow) * lda + lcol;
  const unsigned short* bSrc = Bb + (long)(col0 + w * 32 + lrow) * ldb + lcol;
  unsigned short* aDst = As + w * 32 * 64;  // linear wave-uniform LDS dest
  unsigned short* bDst = Bs + w * 32 * 64;

  f32x4 acc[4][4];
#pragma unroll
  for (int i = 0; i < 4; ++i)
#pragma unroll
    for (int j = 0; j < 4; ++j)
#pragma unroll
      for (int qq = 0; qq < 4; ++qq) acc[i][j][qq] = 0.0f;

  for (int k0 = 0; k0 < K; k0 += 64) {
#pragma unroll
    for (int i = 0; i < 4; ++i) {
      GLOAD_LDS16(aSrc + (long)i * 8 * lda + k0, aDst + i * 512);
      GLOAD_LDS16(bSrc + (long)i * 8 * ldb + k0, bDst + i * 512);
    }
    __syncthreads();
#pragma unroll
    for (int kk = 0; kk < 64; kk += 32) {
      short8 af[4], bfr[4];
#pragma unroll
      for (int i = 0; i < 4; ++i) {
        af[i] = *(const short8*)(As + (wm * 64 + i * 16 + fr) * 64 +
                                 (((kk >> 3) + fg) ^ fr7) * 8);
        bfr[i] = *(const short8*)(Bs + (wn * 64 + i * 16 + fr) * 64 +
                                  (((kk >> 3) + fg) ^ fr7) * 8);
      }
#pragma unroll
      for (int i = 0; i < 4; ++i)
#pragma unroll
        for (int j = 0; j < 4; ++j)
          acc[i][j] = __builtin_amdgcn_mfma_f32_16x16x32_bf16(af[i], bfr[j], acc[i][j], 0, 0, 0);
    }
    __syncthreads();
  }

#pragma unroll
  for (int i = 0; i < 4; ++i) {
#pragma unroll
    for (int qq = 0; qq < 4; ++qq) {
      int row = row0 + wm * 64 + i * 16 + fg * 4 + qq;
#pragma unroll
      for (int j = 0; j < 4; ++j) {
        int col = col0 + wn * 64 + j * 16 + fr;
        long off = cB * tz + (long)row * ldc + col;
        float v = acc[i][j][qq] * scale + (bias ? bias[col] : 0.0f);
        if (resb) v += bf2f(resb[off]);
        if (Cf) Cf[off] = v;
        if (Cb) Cb[off] = f2bf(v);
      }
    }
  }
}

// ---------------- 64x128 bf16 GEMM variant for N=1024 shapes ----------------
__global__ __launch_bounds__(256) void k_gemm64(
    const unsigned short* __restrict__ A, const unsigned short* __restrict__ B,
    float* __restrict__ Cf, unsigned short* __restrict__ Cb,
    const float* __restrict__ bias, const unsigned short* __restrict__ resb,
    int M, int N, int K, int lda, int ldb, int ldc,
    long aB, long bB, long cB, float scale) {
  __shared__ unsigned short As[64 * 64];
  __shared__ unsigned short Bs[128 * 64];
  const int tid = threadIdx.x;
  const int gx = gridDim.x, gy = gridDim.y;

  int nwg = gx * gy * gridDim.z;
  int flat = blockIdx.x + gx * (blockIdx.y + gy * blockIdx.z);
  int q8 = nwg >> 3, r8 = nwg & 7;
  int xcd = flat & 7, inner = flat >> 3;
  int wg = (xcd < r8 ? xcd * (q8 + 1) : r8 * (q8 + 1) + (xcd - r8) * q8) + inner;
  int ty = wg % gy;
  int rest = wg / gy;
  int tx = rest % gx;
  int tz = rest / gx;

  const unsigned short* Ab = A + (long)tz * aB;
  const unsigned short* Bb = B + (long)tz * bB;
  const int row0 = ty * 64, col0 = tx * 128;
  const int lane = tid & 63, w = tid >> 6;
  const int wm = w >> 1, wn = w & 1;
  const int fr = lane & 15, fg = lane >> 4, fr7 = fr & 7;
  const int lrow = lane >> 3;
  const int lcol = ((lane & 7) ^ lrow) * 8;

  const unsigned short* aSrc = Ab + (long)(row0 + w * 16 + lrow) * lda + lcol;
  const unsigned short* bSrc = Bb + (long)(col0 + w * 32 + lrow) * ldb + lcol;
  unsigned short* aDst = As + w * 16 * 64;
  unsigned short* bDst = Bs + w * 32 * 64;

  f32x4 acc[2][4];
#pragma unroll
  for (int i = 0; i < 2; ++i)
#pragma unroll
    for (int j = 0; j < 4; ++j)
#pragma unroll
      for (int qq = 0; qq < 4; ++qq) acc[i][j][qq] = 0.0f;

  for (int k0 = 0; k0 < K; k0 += 64) {
#pragma unroll
    for (int i = 0; i < 2; ++i)
      GLOAD_LDS16(aSrc + (long)i * 8 * lda + k0, aDst + i * 512);
#pragma unroll
    for (int i = 0; i < 4; ++i)
      GLOAD_LDS16(bSrc + (long)i * 8 * ldb + k0, bDst + i * 512);
    __syncthreads();
#pragma unroll
    for (int kk = 0; kk < 64; kk += 32) {
      short8 af[2], bfr[4];
#pragma unroll
      for (int i = 0; i < 2; ++i)
        af[i] = *(const short8*)(As + (wm * 32 + i * 16 + fr) * 64 +
                                 (((kk >> 3) + fg) ^ fr7) * 8);
#pragma unroll
      for (int j = 0; j < 4; ++j)
        bfr[j] = *(const short8*)(Bs + (wn * 64 + j * 16 + fr) * 64 +
                                  (((kk >> 3) + fg) ^ fr7) * 8);
#pragma unroll
      for (int i = 0; i < 2; ++i)
#pragma unroll
        for (int j = 0; j < 4; ++j)
          acc[i][j] = __builtin_amdgcn_mfma_f32_16x16x32_bf16(af[i], bfr[j], acc[i][j], 0, 0, 0);
    }
    __syncthreads();
  }

#pragma unroll
  for (int i = 0; i < 2; ++i) {
#pragma unroll
    for (int qq = 0; qq < 4; ++qq) {
      int row = row0 + wm * 32 + i * 16 + fg * 4 + qq;
#pragma unroll
      for (int j = 0; j < 4; ++j) {
        int col = col0 + wn * 64 + j * 16 + fr;
        long off = cB * tz + (long)row * ldc + col;
        float v = acc[i][j][qq] * scale + (bias ? bias[col] : 0.0f);
        if (resb) v += bf2f(resb[off]);
        if (Cf) Cf[off] = v;
        if (Cb) Cb[off] = f2bf(v);
      }
    }
  }
}

// ---------------- 256x256 2-phase bf16 GEMM (decoder + FFN1; proven ~670 TF) -------
// 512 threads = 8 waves (2M x 4N); BK=64, double-buffered LDS. Issue next tile's
// DMA first, then compute, then ONE __syncthreads() per K-tile.
__global__ __launch_bounds__(512, 2) void k_gemm8(
    const unsigned short* __restrict__ A, const unsigned short* __restrict__ B,
    float* __restrict__ Cf, unsigned short* __restrict__ Cb,
    const float* __restrict__ bias, int M, int N, int K,
    int lda, int ldb, int ldc) {
  __shared__ unsigned short As[2][256 * 64];
  __shared__ unsigned short Bs[2][256 * 64];
  const int tid = threadIdx.x;
  const int gx = gridDim.x, gy = gridDim.y;
  int nwg = gx * gy;
  int flat = blockIdx.x + gx * blockIdx.y;
  int q8 = nwg >> 3, r8 = nwg & 7;
  int xcd = flat & 7, inner = flat >> 3;
  int wg = (xcd < r8 ? xcd * (q8 + 1) : r8 * (q8 + 1) + (xcd - r8) * q8) + inner;
  int ty = wg % gy, tx = wg / gy;

  const int row0 = ty * 256, col0 = tx * 256;
  const int lane = tid & 63, w = tid >> 6;
  const int wm = w >> 2, wn = w & 3;
  const int fr = lane & 15, fg = lane >> 4, fr7 = fr & 7;
  const int srow = lane >> 3;
  const int scol = ((lane & 7) ^ srow) * 8;   // T2 pre-swizzled source chunk

  const unsigned short* pA = A + (size_t)(row0 + w * 32 + srow) * lda + scol;
  const unsigned short* pB = B + (size_t)(col0 + w * 32 + srow) * ldb + scol;
  unsigned short* aD0 = &As[0][w * 32 * 64];
  unsigned short* bD0 = &Bs[0][w * 32 * 64];
  unsigned short* aD1 = &As[1][w * 32 * 64];
  unsigned short* bD1 = &Bs[1][w * 32 * 64];

  auto stage = [&](int bf, int tk) {
    unsigned short* aD = bf ? aD1 : aD0;
    unsigned short* bD = bf ? bD1 : bD0;
#pragma unroll
    for (int i = 0; i < 4; ++i) {
      GLOAD_LDS16(pA + (size_t)i * 8 * lda + (size_t)tk * 64, aD + i * 512);
      GLOAD_LDS16(pB + (size_t)i * 8 * ldb + (size_t)tk * 64, bD + i * 512);
    }
  };
  auto rdA = [&](const unsigned short* lds, int i, int kq) -> short8 {
    return *(const short8*)(lds + (wm * 128 + i * 16 + fr) * 64 +
                            (((kq << 2) + fg) ^ fr7) * 8);
  };
  auto rdB = [&](const unsigned short* lds, int j, int kq) -> short8 {
    return *(const short8*)(lds + (wn * 64 + j * 16 + fr) * 64 +
                            (((kq << 2) + fg) ^ fr7) * 8);
  };

  f32x4 acc[8][4];
#pragma unroll
  for (int i = 0; i < 8; ++i)
#pragma unroll
    for (int j = 0; j < 4; ++j)
#pragma unroll
      for (int qq = 0; qq < 4; ++qq) acc[i][j][qq] = 0.0f;

  const int NT = K >> 6;

  stage(0, 0);
  __syncthreads();

  for (int t = 0; t < NT; ++t) {
    const unsigned short* aL = (t & 1) ? &As[1][0] : &As[0][0];
    const unsigned short* bL = (t & 1) ? &Bs[1][0] : &Bs[0][0];
    if (t + 1 < NT) stage((t & 1) ^ 1, t + 1);  // issue next-tile DMA first
#pragma unroll
    for (int kq = 0; kq < 2; ++kq) {
      short8 a8[8], b8[4];
#pragma unroll
      for (int i = 0; i < 8; ++i) a8[i] = rdA(aL, i, kq);
#pragma unroll
      for (int j = 0; j < 4; ++j) b8[j] = rdB(bL, j, kq);
#pragma unroll
      for (int i = 0; i < 8; ++i)
#pragma unroll
        for (int j = 0; j < 4; ++j)
          acc[i][j] = __builtin_amdgcn_mfma_f32_16x16x32_bf16(a8[i], b8[j], acc[i][j], 0, 0, 0);
    }
    __syncthreads();
  }

  // epilogue: j innermost so each row's 128B span is written by adjacent stores
#pragma unroll
  for (int i = 0; i < 8; ++i) {
#pragma unroll
    for (int qq = 0; qq < 4; ++qq) {
      int row = row0 + wm * 128 + i * 16 + fg * 4 + qq;
#pragma unroll
      for (int j = 0; j < 4; ++j) {
        int col = col0 + wn * 64 + j * 16 + fr;
        size_t off = (size_t)row * ldc + col;
        float v = acc[i][j][qq] + (bias ? bias[col] : 0.0f);
        if (Cf) Cf[off] = v;
        if (Cb) Cb[off] = f2bf(v);
      }
    }
  }
}

// ---------------- layernorm (optional fused permuted bf16 write) ----------------
__global__ __launch_bounds__(256) void k_ln(const float* __restrict__ X,
    const unsigned short* __restrict__ X2b, const float* __restrict__ g,
    const float* __restrict__ b, float* __restrict__ outF,
    unsigned short* __restrict__ outB, int pA0, int pA1) {
  __shared__ float sm[4];
  int row = blockIdx.x, t = threadIdx.x;
  float4 v = ((const float4*)(X + (long)row * DMODEL))[t];
  if (X2b) {
    ushort4 u = ((const ushort4*)(X2b + (long)row * DMODEL))[t];
    v.x += bf2f(u.x); v.y += bf2f(u.y); v.z += bf2f(u.z); v.w += bf2f(u.w);
  }
  float s = wave_sum(v.x + v.y + v.z + v.w);
  if ((t & 63) == 0) sm[t >> 6] = s;
  __syncthreads();
  float mean = (sm[0] + sm[1] + sm[2] + sm[3]) * (1.0f / DMODEL);
  __syncthreads();
  float4 c;
  c.x = v.x - mean; c.y = v.y - mean; c.z = v.z - mean; c.w = v.w - mean;
  float ss = wave_sum(c.x * c.x + c.y * c.y + c.z * c.z + c.w * c.w);
  if ((t & 63) == 0) sm[t >> 6] = ss;
  __syncthreads();
  float var = (sm[0] + sm[1] + sm[2] + sm[3]) * (1.0f / DMODEL);
  float rs = rsqrtf(var + 1e-5f);
  float4 gv = ((const float4*)g)[t], bv = ((const float4*)b)[t];
  float4 o;
  o.x = c.x * rs * gv.x + bv.x;
  o.y = c.y * rs * gv.y + bv.y;
  o.z = c.z * rs * gv.z + bv.z;
  o.w = c.w * rs * gv.w + bv.w;
  if (outF) ((float4*)(outF + (long)row * DMODEL))[t] = o;
  if (outB) {
    int d = row;
    if (pA1 > 0) d = (row % pA1) * pA0 + row / pA1;
    ((ushort4*)(outB + (long)d * DMODEL))[t] =
        make_ushort4(f2bf(o.x), f2bf(o.y), f2bf(o.z), f2bf(o.w));
  }
}

// ---------------- softmax (rows of 1024) ----------------
__global__ __launch_bounds__(256) void k_softmax(const float* __restrict__ S,
    unsigned short* __restrict__ A) {
  __shared__ float sm[4];
  int row = blockIdx.x, t = threadIdx.x;
  float4 v = ((const float4*)(S + (long)row * 1024))[t];
  float m = wave_max(fmaxf(fmaxf(v.x, v.y), fmaxf(v.z, v.w)));
  if ((t & 63) == 0) sm[t >> 6] = m;
  __syncthreads();
  m = fmaxf(fmaxf(sm[0], sm[1]), fmaxf(sm[2], sm[3]));
  __syncthreads();
  float4 e;
  e.x = __expf(v.x - m); e.y = __expf(v.y - m);
  e.z = __expf(v.z - m); e.w = __expf(v.w - m);
  float s = wave_sum(e.x + e.y + e.z + e.w);
  if ((t & 63) == 0) sm[t >> 6] = s;
  __syncthreads();
  float inv = 1.0f / (sm[0] + sm[1] + sm[2] + sm[3]);
  ((ushort4*)(A + (long)row * 1024))[t] =
      make_ushort4(f2bf(e.x * inv), f2bf(e.y * inv), f2bf(e.z * inv), f2bf(e.w * inv));
}

// ---------------- odd layers: seq-4 attention (QKV packed, stride 3072) -------------
__global__ __launch_bounds__(256) void k_attn4(const unsigned short* __restrict__ QKV,
    unsigned short* __restrict__ C) {
  int bp = blockIdx.x;
  int w = threadIdx.x >> 6, lane = threadIdx.x & 63;
  const unsigned short* q = QKV + (long)(bp * 4 + w) * 3072;
  float s[4];
  for (int j = 0; j < 4; ++j) {
    const unsigned short* kj = QKV + (long)(bp * 4 + j) * 3072 + 1024;
    float a = 0.0f;
    for (int e = lane; e < 1024; e += 64) a += bf2f(q[e]) * bf2f(kj[e]);
    s[j] = wave_sum(a) * (1.0f / 32.0f);
  }
  float m = fmaxf(fmaxf(s[0], s[1]), fmaxf(s[2], s[3]));
  float e0 = __expf(s[0] - m), e1 = __expf(s[1] - m);
  float e2 = __expf(s[2] - m), e3 = __expf(s[3] - m);
  float inv = 1.0f / (e0 + e1 + e2 + e3);
  float a0 = e0 * inv, a1 = e1 * inv, a2 = e2 * inv, a3 = e3 * inv;
  unsigned short* c = C + (long)(bp * 4 + w) * 1024;
  const unsigned short* v0 = QKV + (long)(bp * 4 + 0) * 3072 + 2048;
  const unsigned short* v1 = QKV + (long)(bp * 4 + 1) * 3072 + 2048;
  const unsigned short* v2 = QKV + (long)(bp * 4 + 2) * 3072 + 2048;
  const unsigned short* v3 = QKV + (long)(bp * 4 + 3) * 3072 + 2048;
  for (int e = lane; e < 1024; e += 64) {
    float v = a0 * bf2f(v0[e]) + a1 * bf2f(v1[e]) + a2 * bf2f(v2[e]) + a3 * bf2f(v3[e]);
    c[e] = f2bf(v);
  }
}

// ---------------- bf16 batched transpose with strides ----------------
__global__ __launch_bounds__(256) void k_transpose(const unsigned short* __restrict__ in,
    unsigned short* __restrict__ out, int rows, int cols, int ld_in, int ld_out,
    long inB, long outB) {
  __shared__ unsigned short tile[32][33];
  long ibase = (long)blockIdx.z * inB;
  long obase = (long)blockIdx.z * outB;
  int r0 = blockIdx.y * 32, c0 = blockIdx.x * 32;
  int tx = threadIdx.x, ty = threadIdx.y;
  for (int i = ty; i < 32; i += 8)
    tile[i][tx] = in[ibase + (long)(r0 + i) * ld_in + c0 + tx];
  __syncthreads();
  for (int i = ty; i < 32; i += 8)
    out[obase + (long)(c0 + i) * ld_out + r0 + tx] = tile[tx][i];
}

// ---------------- log-softmax: bf16 logits in, f32 out ----------------
__global__ __launch_bounds__(320) void k_logsoftmax_b(
    const unsigned short* __restrict__ Lb, float* __restrict__ out) {
  __shared__ float sm[5];
  int row = blockIdx.x, t = threadIdx.x;
  const unsigned long long* xr =
      (const unsigned long long*)(Lb + (long)row * VOCAB);
  float* yr = out + (long)row * VOCAB;
  float4 v[25];
  float m = -1e30f;
#pragma unroll
  for (int i = 0; i < 25; ++i) {
    unsigned long long u = __builtin_nontemporal_load(&xr[t + i * 320]);
    v[i].x = bf2f((unsigned short)(u & 0xffffu));
    v[i].y = bf2f((unsigned short)((u >> 16) & 0xffffu));
    v[i].z = bf2f((unsigned short)((u >> 32) & 0xffffu));
    v[i].w = bf2f((unsigned short)(u >> 48));
    m = fmaxf(m, fmaxf(fmaxf(v[i].x, v[i].y), fmaxf(v[i].z, v[i].w)));
  }
  m = wave_max(m);
  if ((t & 63) == 0) sm[t >> 6] = m;
  __syncthreads();
  m = fmaxf(fmaxf(fmaxf(sm[0], sm[1]), fmaxf(sm[2], sm[3])), sm[4]);
  __syncthreads();
  float s = 0.0f;
#pragma unroll
  for (int i = 0; i < 25; ++i)
    s += __expf(v[i].x - m) + __expf(v[i].y - m) + __expf(v[i].z - m) + __expf(v[i].w - m);
  s = wave_sum(s);
  if ((t & 63) == 0) sm[t >> 6] = s;
  __syncthreads();
  float l = m + __logf(sm[0] + sm[1] + sm[2] + sm[3] + sm[4]);
#pragma unroll
  for (int i = 0; i < 25; ++i) {
    float4 o = v[i];
    o.x -= l; o.y -= l; o.z -= l; o.w -= l;
    ((float4*)yr)[t + i * 320] = o;
  }
}

// ---------------- log-softmax fallback: in-place f32 ----------------
__global__ __launch_bounds__(320) void k_logsoftmax(float* __restrict__ L) {
  __shared__ float sm[5];
  int row = blockIdx.x, t = threadIdx.x;
  float* x = L + (long)row * VOCAB;
  float4 v[25];
  float m = -1e30f;
#pragma unroll
  for (int i = 0; i < 25; ++i) {
    v[i] = ((const float4*)x)[t + i * 320];
    m = fmaxf(m, fmaxf(fmaxf(v[i].x, v[i].y), fmaxf(v[i].z, v[i].w)));
  }
  m = wave_max(m);
  if ((t & 63) == 0) sm[t >> 6] = m;
  __syncthreads();
  m = fmaxf(fmaxf(fmaxf(sm[0], sm[1]), fmaxf(sm[2], sm[3])), sm[4]);
  __syncthreads();
  float s = 0.0f;
#pragma unroll
  for (int i = 0; i < 25; ++i)
    s += __expf(v[i].x - m) + __expf(v[i].y - m) + __expf(v[i].z - m) + __expf(v[i].w - m);
  s = wave_sum(s);
  if ((t & 63) == 0) sm[t >> 6] = s;
  __syncthreads();
  float l = m + __logf(sm[0] + sm[1] + sm[2] + sm[3] + sm[4]);
#pragma unroll
  for (int i = 0; i < 25; ++i) {
    float4 o = v[i];
    o.x -= l; o.y -= l; o.z -= l; o.w -= l;
    ((float4*)x)[t + i * 320] = o;
  }
}

__global__ __launch_bounds__(256) void k_addbias(const float* __restrict__ a,
    const float* __restrict__ b, float* __restrict__ o, int n) {
  int i = blockIdx.x * 256 + threadIdx.x;
  if (i < n) o[i] = a[i] + b[i];
}

// ---------------- host ----------------
extern "C" void kernel_launch(void* const* d_in, const int* in_sizes, int n_in,
                              void* d_out, int out_size, void* d_ws, size_t ws_size,
                              hipStream_t stream) {
  const int* x = (const int*)d_in[0];
  const float* wemb = (const float*)d_in[1];
  const float* pemb = (const float*)d_in[2];
  const float* wq = (const float*)d_in[3];
  const float* wk = (const float*)d_in[4];
  const float* wv = (const float*)d_in[5];
  const float* wc = (const float*)d_in[6];
  const float* ln1g = (const float*)d_in[7];
  const float* ln1b = (const float*)d_in[8];
  const float* w1 = (const float*)d_in[9];
  const float* b1 = (const float*)d_in[10];
  const float* w2 = (const float*)d_in[11];
  const float* b2 = (const float*)d_in[12];
  const float* ln2g = (const float*)d_in[13];
  const float* ln2b = (const float*)d_in[14];
  const float* decw = (const float*)d_in[15];
  const float* decb = (const float*)d_in[16];
  const float* obias = (const float*)d_in[17];
  float* out = (float*)d_out;

  char* ws = (char*)d_ws;
  size_t off = 0;
  auto alloc = [&](size_t bytes) -> char* {
    char* p = ws + off;
    off += (bytes + 255) & ~(size_t)255;
    return p;
  };
  float* z = (float*)alloc((size_t)NROW * DMODEL * 4);
  unsigned short* xb = (unsigned short*)alloc((size_t)NROW * DMODEL * 2);
  unsigned short* qkv = (unsigned short*)alloc((size_t)NROW * 3072 * 2);
  unsigned short* vt = (unsigned short*)alloc((size_t)NROW * HKDIM * 2);
  unsigned short* wbuf = (unsigned short*)alloc((size_t)MDIM * DMODEL * 2);
  float* tmp16 = (float*)alloc((size_t)NROW * 1024 * 4);
  unsigned short* am = (unsigned short*)alloc((size_t)NROW * 1024 * 2);
  unsigned short* ctx = (unsigned short*)alloc((size_t)NROW * HKDIM * 2);
  unsigned short* hb = (unsigned short*)alloc((size_t)NROW * DMODEL * 2);
  unsigned short* f = (unsigned short*)alloc((size_t)NROW * MDIM * 2);
  unsigned short* dwb = (unsigned short*)alloc((size_t)VOCAB * DMODEL * 2);
  unsigned short* zb = (unsigned short*)alloc((size_t)NROW * DMODEL * 2);
  float* biasD = (float*)alloc((size_t)VOCAB * 4);
  unsigned short* logits = (unsigned short*)alloc((size_t)NROW * VOCAB * 2);
  const bool bfLogits = (off <= ws_size);  // deterministic: ws_size fixed per deploy
  (void)in_sizes; (void)n_in; (void)out_size;

  auto gemm = [&](const unsigned short* A, const unsigned short* B, float* Cf,
                  unsigned short* Cb, const float* bias, const unsigned short* resb,
                  int M, int N, int K, int lda, int ldb, int ldc, int batch,
                  long aB, long bB, long cB, float scale) {
    dim3 g(N / 128, M / 128, batch);
    k_gemm_bt<<<g, dim3(256), 0, stream>>>(A, B, Cf, Cb, bias, resb, M, N, K,
                                           lda, ldb, ldc, aB, bB, cB, scale);
  };
  auto gemm64 = [&](const unsigned short* A, const unsigned short* B, float* Cf,
                    unsigned short* Cb, const float* bias, const unsigned short* resb,
                    int M, int N, int K, int lda, int ldb, int ldc, int batch,
                    long aB, long bB, long cB, float scale) {
    dim3 g(N / 128, M / 64, batch);
    k_gemm64<<<g, dim3(256), 0, stream>>>(A, B, Cf, Cb, bias, resb, M, N, K,
                                          lda, ldb, ldc, aB, bB, cB, scale);
  };
  auto gemm8 = [&](const unsigned short* A, const unsigned short* B, float* Cf,
                   unsigned short* Cb, const float* bias, int M, int N, int K,
                   int lda, int ldb, int ldc) {
    k_gemm8<<<dim3(N / 256, M / 256, 1), dim3(512), 0, stream>>>(
        A, B, Cf, Cb, bias, M, N, K, lda, ldb, ldc);
  };
  auto cvt = [&](const float* in, unsigned short* o, long n) {
    int n4 = (int)(n / 4);
    int grid = (n4 + 255) / 256;
    if (grid > 2048) grid = 2048;
    k_cvt<<<dim3(grid), dim3(256), 0, stream>>>(in, o, n4);
  };

  k_embed<<<NROW, 256, 0, stream>>>(x, wemb, pemb, z);
  // layer 0 permute (A0=1024, A1=4)
  k_permute<<<NROW, 256, 0, stream>>>(z, xb, 1024, 4);

  for (int i = 0; i < NLAYER; ++i) {
    int A0 = (i % 2 == 0) ? 1024 : 4;

    // merged QKV: weights stacked [3072,1024] (768 blocks, 3/CU)
    cvt(wq + (long)i * HKDIM * DMODEL, wbuf, (long)HKDIM * DMODEL);
    cvt(wk + (long)i * HKDIM * DMODEL, wbuf + (size_t)1024 * DMODEL, (long)HKDIM * DMODEL);
    cvt(wv + (long)i * HKDIM * DMODEL, wbuf + (size_t)2048 * DMODEL, (long)HKDIM * DMODEL);
    gemm(xb, wbuf, nullptr, qkv, nullptr, nullptr, NROW, 3072, DMODEL,
         DMODEL, DMODEL, 3072, 1, 0, 0, 0, 1.0f);

    if (A0 == 1024) {  // even: full attention over S=1024, 4 batches
      gemm64(qkv, qkv + 1024, tmp16, nullptr, nullptr, nullptr, 1024, 1024, 1024,
             3072, 3072, 1024, 4, (long)1024 * 3072, (long)1024 * 3072, 1 << 20,
             1.0f / 32.0f);
      k_softmax<<<NROW, 256, 0, stream>>>(tmp16, am);
      k_transpose<<<dim3(32, 32, 4), dim3(32, 8), 0, stream>>>(
          qkv + 2048, vt, 1024, 1024, 3072, 1024, (long)1024 * 3072, 1 << 20);
      gemm64(am, vt, nullptr, ctx, nullptr, nullptr, 1024, 1024, 1024,
             1024, 1024, 1024, 4, 1 << 20, 1 << 20, 1 << 20, 1.0f);
    } else {  // odd: seq length 4
      k_attn4<<<1024, 256, 0, stream>>>(qkv, ctx);
    }

    // proj + bf16 residual  (N=1024: 64-row tiles -> 512 blocks, 2/CU)
    cvt(wc + (long)i * DMODEL * HKDIM, wbuf, (long)DMODEL * HKDIM);
    gemm64(ctx, wbuf, tmp16, nullptr, nullptr, xb, NROW, DMODEL, HKDIM,
           HKDIM, HKDIM, DMODEL, 1, 0, 0, 0, 1.0f);
    k_ln<<<NROW, 256, 0, stream>>>(tmp16, nullptr, ln1g + (long)i * DMODEL,
                                   ln1b + (long)i * DMODEL, nullptr, hb, 0, 0);
    // FFN1 on the 2-phase 256^2 kernel (256 blocks; best traffic + schedule)
    cvt(w1 + (long)i * MDIM * DMODEL, wbuf, (long)MDIM * DMODEL);
    gemm8(hb, wbuf, nullptr, f, b1 + (long)i * MDIM, NROW, MDIM, DMODEL,
          DMODEL, DMODEL, MDIM);
    cvt(w2 + (long)i * DMODEL * MDIM, wbuf, (long)DMODEL * MDIM);
    gemm64(f, wbuf, tmp16, nullptr, b2 + (long)i * DMODEL, nullptr, NROW, DMODEL, MDIM,
           MDIM, MDIM, DMODEL, 1, 0, 0, 0, 1.0f);
    // LN2: fused permuted write into next layer's xb (i<5), linear zb for i=5
    if (i == NLAYER - 1) {
      k_ln<<<NROW, 256, 0, stream>>>(tmp16, hb, ln2g + (long)i * DMODEL,
                                     ln2b + (long)i * DMODEL, nullptr, zb, 0, 0);
    } else {
      int A0n = ((i + 1) % 2 == 0) ? 1024 : 4;
      int A1n = 4096 / A0n;
      k_ln<<<NROW, 256, 0, stream>>>(tmp16, hb, ln2g + (long)i * DMODEL,
                                     ln2b + (long)i * DMODEL, nullptr, xb, A0n, A1n);
    }
  }

  // decoder: double-buffered 2-phase 256^2 (proven best), bf16 logits
  cvt(decw, dwb, (long)VOCAB * DMODEL);
  k_addbias<<<(VOCAB + 255) / 256, 256, 0, stream>>>(decb, obias, biasD, VOCAB);
  if (bfLogits) {
    gemm8(zb, dwb, nullptr, logits, biasD, NROW, VOCAB, DMODEL, DMODEL, DMODEL, VOCAB);
    k_logsoftmax_b<<<NROW, 320, 0, stream>>>(logits, out);
  } else {
    gemm8(zb, dwb, out, nullptr, biasD, NROW, VOCAB, DMODEL, DMODEL, DMODEL, VOCAB);
    k_logsoftmax<<<NROW, 320, 0, stream>>>(out);
  }
}

// Round 15
// 2067.144 us; speedup vs baseline: 2.0862x; 1.0109x over previous
//
#include <hip/hip_runtime.h>

// ---------------- types / constants ----------------
typedef short short8 __attribute__((ext_vector_type(8)));
typedef float f32x4 __attribute__((ext_vector_type(4)));

#define DMODEL 1024
#define HKDIM 1024
#define MDIM 4096
#define NROW 4096   // S*B = 1024*4
#define VOCAB 32000
#define NLAYER 6

#define GLOAD_LDS16(g, l)                                                      \
  __builtin_amdgcn_global_load_lds(                                            \
      (const __attribute__((address_space(1))) void*)(g),                      \
      (__attribute__((address_space(3))) void*)(l), 16, 0, 0)

__device__ __forceinline__ unsigned short f2bf(float f) {
  unsigned u = __float_as_uint(f);
  u += 0x7fffu + ((u >> 16) & 1u);
  return (unsigned short)(u >> 16);
}
__device__ __forceinline__ float bf2f(unsigned short h) {
  return __uint_as_float(((unsigned)h) << 16);
}
__device__ __forceinline__ float wave_sum(float v) {
  for (int o = 32; o; o >>= 1) v += __shfl_xor(v, o);
  return v;
}
__device__ __forceinline__ float wave_max(float v) {
  for (int o = 32; o; o >>= 1) v = fmaxf(v, __shfl_xor(v, o));
  return v;
}

// ---------------- embedding ----------------
__global__ __launch_bounds__(256) void k_embed(const int* __restrict__ x,
    const float* __restrict__ wemb, const float* __restrict__ pemb,
    float* __restrict__ z) {
  int r = blockIdx.x;           // r = s*4 + b
  int s = r >> 2;
  int tok = x[r];
  float4 a = ((const float4*)(wemb + (long)tok * DMODEL))[threadIdx.x];
  float4 p = ((const float4*)(pemb + (long)s * DMODEL))[threadIdx.x];
  float4 o;
  o.x = fmaxf(a.x * 32.0f + p.x, 0.0f);
  o.y = fmaxf(a.y * 32.0f + p.y, 0.0f);
  o.z = fmaxf(a.z * 32.0f + p.z, 0.0f);
  o.w = fmaxf(a.w * 32.0f + p.w, 0.0f);
  ((float4*)(z + (long)r * DMODEL))[threadIdx.x] = o;
}

// ---------------- permute rows: x = swapaxes(z,0,1), bf16 out only ----------------
__global__ __launch_bounds__(256) void k_permute(const float* __restrict__ zin,
    unsigned short* __restrict__ xb, int A0, int A1) {
  int r = blockIdx.x;
  int a1 = r / A0, a0 = r - a1 * A0;
  float4 v = ((const float4*)(zin + (long)(a0 * A1 + a1) * DMODEL))[threadIdx.x];
  ushort4 o = make_ushort4(f2bf(v.x), f2bf(v.y), f2bf(v.z), f2bf(v.w));
  ((ushort4*)(xb + (long)r * DMODEL))[threadIdx.x] = o;
}

// ---------------- f32 -> bf16 (NT source reads: streamed once) ----------------
__global__ __launch_bounds__(256) void k_cvt(const float* __restrict__ in,
    unsigned short* __restrict__ out, int n4) {
  int i = blockIdx.x * 256 + threadIdx.x;
  int stride = gridDim.x * 256;
  for (; i < n4; i += stride) {
    float4 v;
    v.x = __builtin_nontemporal_load(in + (size_t)i * 4);
    v.y = __builtin_nontemporal_load(in + (size_t)i * 4 + 1);
    v.z = __builtin_nontemporal_load(in + (size_t)i * 4 + 2);
    v.w = __builtin_nontemporal_load(in + (size_t)i * 4 + 3);
    ((ushort4*)out)[i] = make_ushort4(f2bf(v.x), f2bf(v.y), f2bf(v.z), f2bf(v.w));
  }
}

// ---------------- 3-way f32 -> bf16 into stacked dst (QKV weights) ----------------
__global__ __launch_bounds__(256) void k_cvt3(const float* __restrict__ s0,
    const float* __restrict__ s1, const float* __restrict__ s2,
    unsigned short* __restrict__ out, int n4each) {
  int i = blockIdx.x * 256 + threadIdx.x;
  int stride = gridDim.x * 256;
  int total = n4each * 3;
  for (; i < total; i += stride) {
    int sel = i / n4each, r = i - sel * n4each;
    const float* src = (sel == 0) ? s0 : (sel == 1) ? s1 : s2;
    float4 v;
    v.x = __builtin_nontemporal_load(src + (size_t)r * 4);
    v.y = __builtin_nontemporal_load(src + (size_t)r * 4 + 1);
    v.z = __builtin_nontemporal_load(src + (size_t)r * 4 + 2);
    v.w = __builtin_nontemporal_load(src + (size_t)r * 4 + 3);
    ((ushort4*)out)[i] = make_ushort4(f2bf(v.x), f2bf(v.y), f2bf(v.z), f2bf(v.w));
  }
}

// ---------------- 128x128 bf16 GEMM (m97 structure + T2 + XCD swizzle) ------------
__global__ __launch_bounds__(256) void k_gemm_bt(
    const unsigned short* __restrict__ A, const unsigned short* __restrict__ B,
    float* __restrict__ Cf, unsigned short* __restrict__ Cb,
    const float* __restrict__ bias, const unsigned short* __restrict__ resb,
    int M, int N, int K, int lda, int ldb, int ldc,
    long aB, long bB, long cB, float scale) {
  __shared__ unsigned short As[128 * 64];
  __shared__ unsigned short Bs[128 * 64];
  const int tid = threadIdx.x;
  const int gx = gridDim.x, gy = gridDim.y;

  int nwg = gx * gy * gridDim.z;
  int flat = blockIdx.x + gx * (blockIdx.y + gy * blockIdx.z);
  int q8 = nwg >> 3, r8 = nwg & 7;
  int xcd = flat & 7, inner = flat >> 3;
  int wg = (xcd < r8 ? xcd * (q8 + 1) : r8 * (q8 + 1) + (xcd - r8) * q8) + inner;
  int ty = wg % gy;         // y-fastest: co-XCD consecutive blocks share B-panel
  int rest = wg / gy;
  int tx = rest % gx;
  int tz = rest / gx;

  const unsigned short* Ab = A + (long)tz * aB;
  const unsigned short* Bb = B + (long)tz * bB;
  const int row0 = ty * 128, col0 = tx * 128;
  const int lane = tid & 63, w = tid >> 6;
  const int wm = w >> 1, wn = w & 1;
  const int fr = lane & 15, fg = lane >> 4, fr7 = fr & 7;
  const int lrow = lane >> 3;
  const int lcol = ((lane & 7) ^ lrow) * 8;  // T2: pre-swizzled global source chunk

  const unsigned short* aSrc = Ab + (long)(row0 + w * 32 + lrow) * lda + lcol;
  const unsigned short* bSrc = Bb + (long)(col0 + w * 32 + lrow) * ldb + lcol;
  unsigned short* aDst = As + w * 32 * 64;  // linear wave-uniform LDS dest
  unsigned short* bDst = Bs + w * 32 * 64;

  f32x4 acc[4][4];
#pragma unroll
  for (int i = 0; i < 4; ++i)
#pragma unroll
    for (int j = 0; j < 4; ++j)
#pragma unroll
      for (int qq = 0; qq < 4; ++qq) acc[i][j][qq] = 0.0f;

  for (int k0 = 0; k0 < K; k0 += 64) {
#pragma unroll
    for (int i = 0; i < 4; ++i) {
      GLOAD_LDS16(aSrc + (long)i * 8 * lda + k0, aDst + i * 512);
      GLOAD_LDS16(bSrc + (long)i * 8 * ldb + k0, bDst + i * 512);
    }
    __syncthreads();
#pragma unroll
    for (int kk = 0; kk < 64; kk += 32) {
      short8 af[4], bfr[4];
#pragma unroll
      for (int i = 0; i < 4; ++i) {
        af[i] = *(const short8*)(As + (wm * 64 + i * 16 + fr) * 64 +
                                 (((kk >> 3) + fg) ^ fr7) * 8);
        bfr[i] = *(const short8*)(Bs + (wn * 64 + i * 16 + fr) * 64 +
                                  (((kk >> 3) + fg) ^ fr7) * 8);
      }
#pragma unroll
      for (int i = 0; i < 4; ++i)
#pragma unroll
        for (int j = 0; j < 4; ++j)
          acc[i][j] = __builtin_amdgcn_mfma_f32_16x16x32_bf16(af[i], bfr[j], acc[i][j], 0, 0, 0);
    }
    __syncthreads();
  }

#pragma unroll
  for (int i = 0; i < 4; ++i) {
#pragma unroll
    for (int qq = 0; qq < 4; ++qq) {
      int row = row0 + wm * 64 + i * 16 + fg * 4 + qq;
#pragma unroll
      for (int j = 0; j < 4; ++j) {
        int col = col0 + wn * 64 + j * 16 + fr;
        long off = cB * tz + (long)row * ldc + col;
        float v = acc[i][j][qq] * scale + (bias ? bias[col] : 0.0f);
        if (resb) v += bf2f(resb[off]);
        if (Cf) Cf[off] = v;
        if (Cb) Cb[off] = f2bf(v);
      }
    }
  }
}

// ---------------- 64x128 bf16 GEMM variant for N=1024 shapes ----------------
__global__ __launch_bounds__(256) void k_gemm64(
    const unsigned short* __restrict__ A, const unsigned short* __restrict__ B,
    float* __restrict__ Cf, unsigned short* __restrict__ Cb,
    const float* __restrict__ bias, const unsigned short* __restrict__ resb,
    int M, int N, int K, int lda, int ldb, int ldc,
    long aB, long bB, long cB, float scale) {
  __shared__ unsigned short As[64 * 64];
  __shared__ unsigned short Bs[128 * 64];
  const int tid = threadIdx.x;
  const int gx = gridDim.x, gy = gridDim.y;

  int nwg = gx * gy * gridDim.z;
  int flat = blockIdx.x + gx * (blockIdx.y + gy * blockIdx.z);
  int q8 = nwg >> 3, r8 = nwg & 7;
  int xcd = flat & 7, inner = flat >> 3;
  int wg = (xcd < r8 ? xcd * (q8 + 1) : r8 * (q8 + 1) + (xcd - r8) * q8) + inner;
  int ty = wg % gy;
  int rest = wg / gy;
  int tx = rest % gx;
  int tz = rest / gx;

  const unsigned short* Ab = A + (long)tz * aB;
  const unsigned short* Bb = B + (long)tz * bB;
  const int row0 = ty * 64, col0 = tx * 128;
  const int lane = tid & 63, w = tid >> 6;
  const int wm = w >> 1, wn = w & 1;
  const int fr = lane & 15, fg = lane >> 4, fr7 = fr & 7;
  const int lrow = lane >> 3;
  const int lcol = ((lane & 7) ^ lrow) * 8;

  const unsigned short* aSrc = Ab + (long)(row0 + w * 16 + lrow) * lda + lcol;
  const unsigned short* bSrc = Bb + (long)(col0 + w * 32 + lrow) * ldb + lcol;
  unsigned short* aDst = As + w * 16 * 64;
  unsigned short* bDst = Bs + w * 32 * 64;

  f32x4 acc[2][4];
#pragma unroll
  for (int i = 0; i < 2; ++i)
#pragma unroll
    for (int j = 0; j < 4; ++j)
#pragma unroll
      for (int qq = 0; qq < 4; ++qq) acc[i][j][qq] = 0.0f;

  for (int k0 = 0; k0 < K; k0 += 64) {
#pragma unroll
    for (int i = 0; i < 2; ++i)
      GLOAD_LDS16(aSrc + (long)i * 8 * lda + k0, aDst + i * 512);
#pragma unroll
    for (int i = 0; i < 4; ++i)
      GLOAD_LDS16(bSrc + (long)i * 8 * ldb + k0, bDst + i * 512);
    __syncthreads();
#pragma unroll
    for (int kk = 0; kk < 64; kk += 32) {
      short8 af[2], bfr[4];
#pragma unroll
      for (int i = 0; i < 2; ++i)
        af[i] = *(const short8*)(As + (wm * 32 + i * 16 + fr) * 64 +
                                 (((kk >> 3) + fg) ^ fr7) * 8);
#pragma unroll
      for (int j = 0; j < 4; ++j)
        bfr[j] = *(const short8*)(Bs + (wn * 64 + j * 16 + fr) * 64 +
                                  (((kk >> 3) + fg) ^ fr7) * 8);
#pragma unroll
      for (int i = 0; i < 2; ++i)
#pragma unroll
        for (int j = 0; j < 4; ++j)
          acc[i][j] = __builtin_amdgcn_mfma_f32_16x16x32_bf16(af[i], bfr[j], acc[i][j], 0, 0, 0);
    }
    __syncthreads();
  }

#pragma unroll
  for (int i = 0; i < 2; ++i) {
#pragma unroll
    for (int qq = 0; qq < 4; ++qq) {
      int row = row0 + wm * 32 + i * 16 + fg * 4 + qq;
#pragma unroll
      for (int j = 0; j < 4; ++j) {
        int col = col0 + wn * 64 + j * 16 + fr;
        long off = cB * tz + (long)row * ldc + col;
        float v = acc[i][j][qq] * scale + (bias ? bias[col] : 0.0f);
        if (resb) v += bf2f(resb[off]);
        if (Cf) Cf[off] = v;
        if (Cb) Cb[off] = f2bf(v);
      }
    }
  }
}

// ---------------- 256x256 2-phase bf16 GEMM (decoder + FFN1; ~670 TF) ----------
__global__ __launch_bounds__(512, 2) void k_gemm8(
    const unsigned short* __restrict__ A, const unsigned short* __restrict__ B,
    float* __restrict__ Cf, unsigned short* __restrict__ Cb,
    const float* __restrict__ bias, int M, int N, int K,
    int lda, int ldb, int ldc) {
  __shared__ unsigned short As[2][256 * 64];
  __shared__ unsigned short Bs[2][256 * 64];
  const int tid = threadIdx.x;
  const int gx = gridDim.x, gy = gridDim.y;
  int nwg = gx * gy;
  int flat = blockIdx.x + gx * blockIdx.y;
  int q8 = nwg >> 3, r8 = nwg & 7;
  int xcd = flat & 7, inner = flat >> 3;
  int wg = (xcd < r8 ? xcd * (q8 + 1) : r8 * (q8 + 1) + (xcd - r8) * q8) + inner;
  int ty = wg % gy, tx = wg / gy;

  const int row0 = ty * 256, col0 = tx * 256;
  const int lane = tid & 63, w = tid >> 6;
  const int wm = w >> 2, wn = w & 3;
  const int fr = lane & 15, fg = lane >> 4, fr7 = fr & 7;
  const int srow = lane >> 3;
  const int scol = ((lane & 7) ^ srow) * 8;   // T2 pre-swizzled source chunk

  const unsigned short* pA = A + (size_t)(row0 + w * 32 + srow) * lda + scol;
  const unsigned short* pB = B + (size_t)(col0 + w * 32 + srow) * ldb + scol;
  unsigned short* aD0 = &As[0][w * 32 * 64];
  unsigned short* bD0 = &Bs[0][w * 32 * 64];
  unsigned short* aD1 = &As[1][w * 32 * 64];
  unsigned short* bD1 = &Bs[1][w * 32 * 64];

  auto stage = [&](int bf, int tk) {
    unsigned short* aD = bf ? aD1 : aD0;
    unsigned short* bD = bf ? bD1 : bD0;
#pragma unroll
    for (int i = 0; i < 4; ++i) {
      GLOAD_LDS16(pA + (size_t)i * 8 * lda + (size_t)tk * 64, aD + i * 512);
      GLOAD_LDS16(pB + (size_t)i * 8 * ldb + (size_t)tk * 64, bD + i * 512);
    }
  };
  auto rdA = [&](const unsigned short* lds, int i, int kq) -> short8 {
    return *(const short8*)(lds + (wm * 128 + i * 16 + fr) * 64 +
                            (((kq << 2) + fg) ^ fr7) * 8);
  };
  auto rdB = [&](const unsigned short* lds, int j, int kq) -> short8 {
    return *(const short8*)(lds + (wn * 64 + j * 16 + fr) * 64 +
                            (((kq << 2) + fg) ^ fr7) * 8);
  };

  f32x4 acc[8][4];
#pragma unroll
  for (int i = 0; i < 8; ++i)
#pragma unroll
    for (int j = 0; j < 4; ++j)
#pragma unroll
      for (int qq = 0; qq < 4; ++qq) acc[i][j][qq] = 0.0f;

  const int NT = K >> 6;

  stage(0, 0);
  __syncthreads();

  for (int t = 0; t < NT; ++t) {
    const unsigned short* aL = (t & 1) ? &As[1][0] : &As[0][0];
    const unsigned short* bL = (t & 1) ? &Bs[1][0] : &Bs[0][0];
    if (t + 1 < NT) stage((t & 1) ^ 1, t + 1);  // issue next-tile DMA first
#pragma unroll
    for (int kq = 0; kq < 2; ++kq) {
      short8 a8[8], b8[4];
#pragma unroll
      for (int i = 0; i < 8; ++i) a8[i] = rdA(aL, i, kq);
#pragma unroll
      for (int j = 0; j < 4; ++j) b8[j] = rdB(bL, j, kq);
#pragma unroll
      for (int i = 0; i < 8; ++i)
#pragma unroll
        for (int j = 0; j < 4; ++j)
          acc[i][j] = __builtin_amdgcn_mfma_f32_16x16x32_bf16(a8[i], b8[j], acc[i][j], 0, 0, 0);
    }
    __syncthreads();
  }

  // epilogue: j innermost so each row's 128B span is written by adjacent stores
#pragma unroll
  for (int i = 0; i < 8; ++i) {
#pragma unroll
    for (int qq = 0; qq < 4; ++qq) {
      int row = row0 + wm * 128 + i * 16 + fg * 4 + qq;
#pragma unroll
      for (int j = 0; j < 4; ++j) {
        int col = col0 + wn * 64 + j * 16 + fr;
        size_t off = (size_t)row * ldc + col;
        float v = acc[i][j][qq] + (bias ? bias[col] : 0.0f);
        if (Cf) Cf[off] = v;
        if (Cb) Cb[off] = f2bf(v);
      }
    }
  }
}

// ---------------- layernorm (optional fused permuted bf16 write) ----------------
__global__ __launch_bounds__(256) void k_ln(const float* __restrict__ X,
    const unsigned short* __restrict__ X2b, const float* __restrict__ g,
    const float* __restrict__ b, float* __restrict__ outF,
    unsigned short* __restrict__ outB, int pA0, int pA1) {
  __shared__ float sm[4];
  int row = blockIdx.x, t = threadIdx.x;
  float4 v = ((const float4*)(X + (long)row * DMODEL))[t];
  if (X2b) {
    ushort4 u = ((const ushort4*)(X2b + (long)row * DMODEL))[t];
    v.x += bf2f(u.x); v.y += bf2f(u.y); v.z += bf2f(u.z); v.w += bf2f(u.w);
  }
  float s = wave_sum(v.x + v.y + v.z + v.w);
  if ((t & 63) == 0) sm[t >> 6] = s;
  __syncthreads();
  float mean = (sm[0] + sm[1] + sm[2] + sm[3]) * (1.0f / DMODEL);
  __syncthreads();
  float4 c;
  c.x = v.x - mean; c.y = v.y - mean; c.z = v.z - mean; c.w = v.w - mean;
  float ss = wave_sum(c.x * c.x + c.y * c.y + c.z * c.z + c.w * c.w);
  if ((t & 63) == 0) sm[t >> 6] = ss;
  __syncthreads();
  float var = (sm[0] + sm[1] + sm[2] + sm[3]) * (1.0f / DMODEL);
  float rs = rsqrtf(var + 1e-5f);
  float4 gv = ((const float4*)g)[t], bv = ((const float4*)b)[t];
  float4 o;
  o.x = c.x * rs * gv.x + bv.x;
  o.y = c.y * rs * gv.y + bv.y;
  o.z = c.z * rs * gv.z + bv.z;
  o.w = c.w * rs * gv.w + bv.w;
  if (outF) ((float4*)(outF + (long)row * DMODEL))[t] = o;
  if (outB) {
    int d = row;
    if (pA1 > 0) d = (row % pA1) * pA0 + row / pA1;
    ((ushort4*)(outB + (long)d * DMODEL))[t] =
        make_ushort4(f2bf(o.x), f2bf(o.y), f2bf(o.z), f2bf(o.w));
  }
}

// ---------------- softmax (rows of 1024) ----------------
__global__ __launch_bounds__(256) void k_softmax(const float* __restrict__ S,
    unsigned short* __restrict__ A) {
  __shared__ float sm[4];
  int row = blockIdx.x, t = threadIdx.x;
  float4 v = ((const float4*)(S + (long)row * 1024))[t];
  float m = wave_max(fmaxf(fmaxf(v.x, v.y), fmaxf(v.z, v.w)));
  if ((t & 63) == 0) sm[t >> 6] = m;
  __syncthreads();
  m = fmaxf(fmaxf(sm[0], sm[1]), fmaxf(sm[2], sm[3]));
  __syncthreads();
  float4 e;
  e.x = __expf(v.x - m); e.y = __expf(v.y - m);
  e.z = __expf(v.z - m); e.w = __expf(v.w - m);
  float s = wave_sum(e.x + e.y + e.z + e.w);
  if ((t & 63) == 0) sm[t >> 6] = s;
  __syncthreads();
  float inv = 1.0f / (sm[0] + sm[1] + sm[2] + sm[3]);
  ((ushort4*)(A + (long)row * 1024))[t] =
      make_ushort4(f2bf(e.x * inv), f2bf(e.y * inv), f2bf(e.z * inv), f2bf(e.w * inv));
}

// ---------------- odd layers: seq-4 attention (QKV packed, stride 3072) -------------
__global__ __launch_bounds__(256) void k_attn4(const unsigned short* __restrict__ QKV,
    unsigned short* __restrict__ C) {
  int bp = blockIdx.x;
  int w = threadIdx.x >> 6, lane = threadIdx.x & 63;
  const unsigned short* q = QKV + (long)(bp * 4 + w) * 3072;
  float s[4];
  for (int j = 0; j < 4; ++j) {
    const unsigned short* kj = QKV + (long)(bp * 4 + j) * 3072 + 1024;
    float a = 0.0f;
    for (int e = lane; e < 1024; e += 64) a += bf2f(q[e]) * bf2f(kj[e]);
    s[j] = wave_sum(a) * (1.0f / 32.0f);
  }
  float m = fmaxf(fmaxf(s[0], s[1]), fmaxf(s[2], s[3]));
  float e0 = __expf(s[0] - m), e1 = __expf(s[1] - m);
  float e2 = __expf(s[2] - m), e3 = __expf(s[3] - m);
  float inv = 1.0f / (e0 + e1 + e2 + e3);
  float a0 = e0 * inv, a1 = e1 * inv, a2 = e2 * inv, a3 = e3 * inv;
  unsigned short* c = C + (long)(bp * 4 + w) * 1024;
  const unsigned short* v0 = QKV + (long)(bp * 4 + 0) * 3072 + 2048;
  const unsigned short* v1 = QKV + (long)(bp * 4 + 1) * 3072 + 2048;
  const unsigned short* v2 = QKV + (long)(bp * 4 + 2) * 3072 + 2048;
  const unsigned short* v3 = QKV + (long)(bp * 4 + 3) * 3072 + 2048;
  for (int e = lane; e < 1024; e += 64) {
    float v = a0 * bf2f(v0[e]) + a1 * bf2f(v1[e]) + a2 * bf2f(v2[e]) + a3 * bf2f(v3[e]);
    c[e] = f2bf(v);
  }
}

// ---------------- bf16 batched transpose with strides ----------------
__global__ __launch_bounds__(256) void k_transpose(const unsigned short* __restrict__ in,
    unsigned short* __restrict__ out, int rows, int cols, int ld_in, int ld_out,
    long inB, long outB) {
  __shared__ unsigned short tile[32][33];
  long ibase = (long)blockIdx.z * inB;
  long obase = (long)blockIdx.z * outB;
  int r0 = blockIdx.y * 32, c0 = blockIdx.x * 32;
  int tx = threadIdx.x, ty = threadIdx.y;
  for (int i = ty; i < 32; i += 8)
    tile[i][tx] = in[ibase + (long)(r0 + i) * ld_in + c0 + tx];
  __syncthreads();
  for (int i = ty; i < 32; i += 8)
    out[obase + (long)(c0 + i) * ld_out + r0 + tx] = tile[tx][i];
}

// ---------------- log-softmax: bf16 logits in, f32 out ----------------
__global__ __launch_bounds__(320) void k_logsoftmax_b(
    const unsigned short* __restrict__ Lb, float* __restrict__ out) {
  __shared__ float sm[5];
  int row = blockIdx.x, t = threadIdx.x;
  const unsigned long long* xr =
      (const unsigned long long*)(Lb + (long)row * VOCAB);
  float* yr = out + (long)row * VOCAB;
  float4 v[25];
  float m = -1e30f;
#pragma unroll
  for (int i = 0; i < 25; ++i) {
    unsigned long long u = __builtin_nontemporal_load(&xr[t + i * 320]);
    v[i].x = bf2f((unsigned short)(u & 0xffffu));
    v[i].y = bf2f((unsigned short)((u >> 16) & 0xffffu));
    v[i].z = bf2f((unsigned short)((u >> 32) & 0xffffu));
    v[i].w = bf2f((unsigned short)(u >> 48));
    m = fmaxf(m, fmaxf(fmaxf(v[i].x, v[i].y), fmaxf(v[i].z, v[i].w)));
  }
  m = wave_max(m);
  if ((t & 63) == 0) sm[t >> 6] = m;
  __syncthreads();
  m = fmaxf(fmaxf(fmaxf(sm[0], sm[1]), fmaxf(sm[2], sm[3])), sm[4]);
  __syncthreads();
  float s = 0.0f;
#pragma unroll
  for (int i = 0; i < 25; ++i)
    s += __expf(v[i].x - m) + __expf(v[i].y - m) + __expf(v[i].z - m) + __expf(v[i].w - m);
  s = wave_sum(s);
  if ((t & 63) == 0) sm[t >> 6] = s;
  __syncthreads();
  float l = m + __logf(sm[0] + sm[1] + sm[2] + sm[3] + sm[4]);
#pragma unroll
  for (int i = 0; i < 25; ++i) {
    float4 o = v[i];
    o.x -= l; o.y -= l; o.z -= l; o.w -= l;
    ((float4*)yr)[t + i * 320] = o;
  }
}

// ---------------- log-softmax fallback: in-place f32 ----------------
__global__ __launch_bounds__(320) void k_logsoftmax(float* __restrict__ L) {
  __shared__ float sm[5];
  int row = blockIdx.x, t = threadIdx.x;
  float* x = L + (long)row * VOCAB;
  float4 v[25];
  float m = -1e30f;
#pragma unroll
  for (int i = 0; i < 25; ++i) {
    v[i] = ((const float4*)x)[t + i * 320];
    m = fmaxf(m, fmaxf(fmaxf(v[i].x, v[i].y), fmaxf(v[i].z, v[i].w)));
  }
  m = wave_max(m);
  if ((t & 63) == 0) sm[t >> 6] = m;
  __syncthreads();
  m = fmaxf(fmaxf(fmaxf(sm[0], sm[1]), fmaxf(sm[2], sm[3])), sm[4]);
  __syncthreads();
  float s = 0.0f;
#pragma unroll
  for (int i = 0; i < 25; ++i)
    s += __expf(v[i].x - m) + __expf(v[i].y - m) + __expf(v[i].z - m) + __expf(v[i].w - m);
  s = wave_sum(s);
  if ((t & 63) == 0) sm[t >> 6] = s;
  __syncthreads();
  float l = m + __logf(sm[0] + sm[1] + sm[2] + sm[3] + sm[4]);
#pragma unroll
  for (int i = 0; i < 25; ++i) {
    float4 o = v[i];
    o.x -= l; o.y -= l; o.z -= l; o.w -= l;
    ((float4*)x)[t + i * 320] = o;
  }
}

__global__ __launch_bounds__(256) void k_addbias(const float* __restrict__ a,
    const float* __restrict__ b, float* __restrict__ o, int n) {
  int i = blockIdx.x * 256 + threadIdx.x;
  if (i < n) o[i] = a[i] + b[i];
}

// ---------------- host ----------------
extern "C" void kernel_launch(void* const* d_in, const int* in_sizes, int n_in,
                              void* d_out, int out_size, void* d_ws, size_t ws_size,
                              hipStream_t stream) {
  const int* x = (const int*)d_in[0];
  const float* wemb = (const float*)d_in[1];
  const float* pemb = (const float*)d_in[2];
  const float* wq = (const float*)d_in[3];
  const float* wk = (const float*)d_in[4];
  const float* wv = (const float*)d_in[5];
  const float* wc = (const float*)d_in[6];
  const float* ln1g = (const float*)d_in[7];
  const float* ln1b = (const float*)d_in[8];
  const float* w1 = (const float*)d_in[9];
  const float* b1 = (const float*)d_in[10];
  const float* w2 = (const float*)d_in[11];
  const float* b2 = (const float*)d_in[12];
  const float* ln2g = (const float*)d_in[13];
  const float* ln2b = (const float*)d_in[14];
  const float* decw = (const float*)d_in[15];
  const float* decb = (const float*)d_in[16];
  const float* obias = (const float*)d_in[17];
  float* out = (float*)d_out;

  char* ws = (char*)d_ws;
  size_t off = 0;
  auto alloc = [&](size_t bytes) -> char* {
    char* p = ws + off;
    off += (bytes + 255) & ~(size_t)255;
    return p;
  };
  float* z = (float*)alloc((size_t)NROW * DMODEL * 4);
  unsigned short* xb = (unsigned short*)alloc((size_t)NROW * DMODEL * 2);
  unsigned short* qkv = (unsigned short*)alloc((size_t)NROW * 3072 * 2);
  unsigned short* vt = (unsigned short*)alloc((size_t)NROW * HKDIM * 2);
  unsigned short* wbuf = (unsigned short*)alloc((size_t)MDIM * DMODEL * 2);
  float* tmp16 = (float*)alloc((size_t)NROW * 1024 * 4);
  unsigned short* am = (unsigned short*)alloc((size_t)NROW * 1024 * 2);
  unsigned short* ctx = (unsigned short*)alloc((size_t)NROW * HKDIM * 2);
  unsigned short* hb = (unsigned short*)alloc((size_t)NROW * DMODEL * 2);
  unsigned short* f = (unsigned short*)alloc((size_t)NROW * MDIM * 2);
  unsigned short* dwb = (unsigned short*)alloc((size_t)VOCAB * DMODEL * 2);
  unsigned short* zb = (unsigned short*)alloc((size_t)NROW * DMODEL * 2);
  float* biasD = (float*)alloc((size_t)VOCAB * 4);
  unsigned short* logits = (unsigned short*)alloc((size_t)NROW * VOCAB * 2);
  const bool bfLogits = (off <= ws_size);  // deterministic: ws_size fixed per deploy
  (void)in_sizes; (void)n_in; (void)out_size;

  auto gemm = [&](const unsigned short* A, const unsigned short* B, float* Cf,
                  unsigned short* Cb, const float* bias, const unsigned short* resb,
                  int M, int N, int K, int lda, int ldb, int ldc, int batch,
                  long aB, long bB, long cB, float scale) {
    dim3 g(N / 128, M / 128, batch);
    k_gemm_bt<<<g, dim3(256), 0, stream>>>(A, B, Cf, Cb, bias, resb, M, N, K,
                                           lda, ldb, ldc, aB, bB, cB, scale);
  };
  auto gemm64 = [&](const unsigned short* A, const unsigned short* B, float* Cf,
                    unsigned short* Cb, const float* bias, const unsigned short* resb,
                    int M, int N, int K, int lda, int ldb, int ldc, int batch,
                    long aB, long bB, long cB, float scale) {
    dim3 g(N / 128, M / 64, batch);
    k_gemm64<<<g, dim3(256), 0, stream>>>(A, B, Cf, Cb, bias, resb, M, N, K,
                                          lda, ldb, ldc, aB, bB, cB, scale);
  };
  auto gemm8 = [&](const unsigned short* A, const unsigned short* B, float* Cf,
                   unsigned short* Cb, const float* bias, int M, int N, int K,
                   int lda, int ldb, int ldc) {
    k_gemm8<<<dim3(N / 256, M / 256, 1), dim3(512), 0, stream>>>(
        A, B, Cf, Cb, bias, M, N, K, lda, ldb, ldc);
  };
  auto cvt = [&](const float* in, unsigned short* o, long n) {
    int n4 = (int)(n / 4);
    int grid = (n4 + 255) / 256;
    if (grid > 2048) grid = 2048;
    k_cvt<<<dim3(grid), dim3(256), 0, stream>>>(in, o, n4);
  };

  k_embed<<<NROW, 256, 0, stream>>>(x, wemb, pemb, z);
  // layer 0 permute (A0=1024, A1=4)
  k_permute<<<NROW, 256, 0, stream>>>(z, xb, 1024, 4);

  for (int i = 0; i < NLAYER; ++i) {
    int A0 = (i % 2 == 0) ? 1024 : 4;

    // merged QKV weight cvt: one launch, stacked [3072,1024]
    k_cvt3<<<dim3(2048), dim3(256), 0, stream>>>(
        wq + (long)i * HKDIM * DMODEL, wk + (long)i * HKDIM * DMODEL,
        wv + (long)i * HKDIM * DMODEL, wbuf, (int)((long)HKDIM * DMODEL / 4));
    gemm(xb, wbuf, nullptr, qkv, nullptr, nullptr, NROW, 3072, DMODEL,
         DMODEL, DMODEL, 3072, 1, 0, 0, 0, 1.0f);

    if (A0 == 1024) {  // even: full attention over S=1024, 4 batches
      gemm64(qkv, qkv + 1024, tmp16, nullptr, nullptr, nullptr, 1024, 1024, 1024,
             3072, 3072, 1024, 4, (long)1024 * 3072, (long)1024 * 3072, 1 << 20,
             1.0f / 32.0f);
      k_softmax<<<NROW, 256, 0, stream>>>(tmp16, am);
      k_transpose<<<dim3(32, 32, 4), dim3(32, 8), 0, stream>>>(
          qkv + 2048, vt, 1024, 1024, 3072, 1024, (long)1024 * 3072, 1 << 20);
      gemm64(am, vt, nullptr, ctx, nullptr, nullptr, 1024, 1024, 1024,
             1024, 1024, 1024, 4, 1 << 20, 1 << 20, 1 << 20, 1.0f);
    } else {  // odd: seq length 4
      k_attn4<<<1024, 256, 0, stream>>>(qkv, ctx);
    }

    // proj + bf16 residual  (N=1024: 64-row tiles -> 512 blocks, 2/CU)
    cvt(wc + (long)i * DMODEL * HKDIM, wbuf, (long)DMODEL * HKDIM);
    gemm64(ctx, wbuf, tmp16, nullptr, nullptr, xb, NROW, DMODEL, HKDIM,
           HKDIM, HKDIM, DMODEL, 1, 0, 0, 0, 1.0f);
    k_ln<<<NROW, 256, 0, stream>>>(tmp16, nullptr, ln1g + (long)i * DMODEL,
                                   ln1b + (long)i * DMODEL, nullptr, hb, 0, 0);
    // FFN1 on the 2-phase 256^2 kernel (256 blocks; best traffic + schedule)
    cvt(w1 + (long)i * MDIM * DMODEL, wbuf, (long)MDIM * DMODEL);
    gemm8(hb, wbuf, nullptr, f, b1 + (long)i * MDIM, NROW, MDIM, DMODEL,
          DMODEL, DMODEL, MDIM);
    cvt(w2 + (long)i * DMODEL * MDIM, wbuf, (long)DMODEL * MDIM);
    gemm64(f, wbuf, tmp16, nullptr, b2 + (long)i * DMODEL, nullptr, NROW, DMODEL, MDIM,
           MDIM, MDIM, DMODEL, 1, 0, 0, 0, 1.0f);
    // LN2: fused permuted write into next layer's xb (i<5), linear zb for i=5
    if (i == NLAYER - 1) {
      k_ln<<<NROW, 256, 0, stream>>>(tmp16, hb, ln2g + (long)i * DMODEL,
                                     ln2b + (long)i * DMODEL, nullptr, zb, 0, 0);
    } else {
      int A0n = ((i + 1) % 2 == 0) ? 1024 : 4;
      int A1n = 4096 / A0n;
      k_ln<<<NROW, 256, 0, stream>>>(tmp16, hb, ln2g + (long)i * DMODEL,
                                     ln2b + (long)i * DMODEL, nullptr, xb, A0n, A1n);
    }
  }

  // decoder: double-buffered 2-phase 256^2 (proven best), bf16 logits
  cvt(decw, dwb, (long)VOCAB * DMODEL);
  k_addbias<<<(VOCAB + 255) / 256, 256, 0, stream>>>(decb, obias, biasD, VOCAB);
  if (bfLogits) {
    gemm8(zb, dwb, nullptr, logits, biasD, NROW, VOCAB, DMODEL, DMODEL, DMODEL, VOCAB);
    k_logsoftmax_b<<<NROW, 320, 0, stream>>>(logits, out);
  } else {
    gemm8(zb, dwb, out, nullptr, biasD, NROW, VOCAB, DMODEL, DMODEL, DMODEL, VOCAB);
    k_logsoftmax<<<NROW, 320, 0, stream>>>(out);
  }
}